// Round 1
// baseline (1839.111 us; speedup 1.0000x reference)
//
#include <hip/hip_runtime.h>
#include <math.h>

#define BB_ 8
#define LL_ 720
#define NF 321
#define DM 512
#define HH_ 8
#define DH 64
#define DFF 128
#define PRED 336
#define UK 35
#define NLAY 2
#define EPSF 1e-5f
#define BL (BB_*LL_)

// ---------------- reduction helpers ----------------
__device__ __forceinline__ float wredsum(float v){
#pragma unroll
  for(int o=32;o>0;o>>=1) v += __shfl_xor(v,o,64);
  return v;
}
__device__ __forceinline__ float wredmax(float v){
#pragma unroll
  for(int o=32;o>0;o>>=1) v = fmaxf(v,__shfl_xor(v,o,64));
  return v;
}
// block reduce across 256 threads (4 waves). red must be float[4] shared.
__device__ __forceinline__ float bredsum(float v, float* red){
  int lane = threadIdx.x & 63, wid = threadIdx.x >> 6;
  v = wredsum(v);
  __syncthreads();
  if (lane==0) red[wid]=v;
  __syncthreads();
  return red[0]+red[1]+red[2]+red[3];
}
__device__ __forceinline__ float bredmax(float v, float* red){
  int lane = threadIdx.x & 63, wid = threadIdx.x >> 6;
  v = wredmax(v);
  __syncthreads();
  if (lane==0) red[wid]=v;
  __syncthreads();
  return fmaxf(fmaxf(red[0],red[1]),fmaxf(red[2],red[3]));
}

// ---------------- stats: mean/std over L for x^T (B,N,L) ----------------
__global__ __launch_bounds__(256) void stats_k(const float* __restrict__ x,
                                               float* __restrict__ mean,
                                               float* __restrict__ stdv,
                                               float* __restrict__ rstd){
  __shared__ float red[4];
  int bn = blockIdx.x;              // b*NF + n
  int b = bn / NF; int n = bn % NF;
  const float* xp = x + (size_t)b*LL_*NF + n;
  int t = threadIdx.x;
  float s = 0.f;
  for (int l=t;l<LL_;l+=256) s += xp[(size_t)l*NF];
  s = bredsum(s, red);
  float mu = s * (1.f/LL_);
  float s2 = 0.f;
  for (int l=t;l<LL_;l+=256){ float d = xp[(size_t)l*NF]-mu; s2 += d*d; }
  s2 = bredsum(s2, red);
  if (t==0){
    mean[bn]=mu;
    float sd = sqrtf(s2*(1.f/(LL_-1))) + EPSF;
    stdv[bn]=sd;
    rstd[bn]=1.f/sd;
  }
}

// ---------------- generic tiled fp32 GEMM ----------------
// C[M,N] = A[M,K] @ B[K,N] + bias[N];  flags: bit0 relu, bit1 normalize-A (embed)
__global__ __launch_bounds__(256) void gemm_k(
    const float* __restrict__ A, const float* __restrict__ Bw,
    const float* __restrict__ bias, float* __restrict__ C,
    int M, int N, int K, int flags,
    const float* __restrict__ nm, const float* __restrict__ nr)
{
  __shared__ float As[16][64];
  __shared__ float Bs[16][64];
  int bm = blockIdx.y * 64;
  int bn = blockIdx.x * 64;
  int t = threadIdx.x;
  int tx = t & 15, ty = t >> 4;
  int tx4 = tx*4, ty4 = ty*4;
  float acc[4][4] = {{0.f}};

  int arow = t >> 2;          // 0..63
  int akq  = (t & 3) * 4;     // 0,4,8,12
  int bkr  = t >> 4;          // 0..15
  int bcq  = (t & 15) * 4;    // 0..60

  for (int k0 = 0; k0 < K; k0 += 16){
    // --- A tile (64x16) ---
    {
      int gr = bm + arow;
      float a0=0.f,a1=0.f,a2=0.f,a3=0.f;
      if (gr < M){
        const float* ap = A + (size_t)gr * K + (k0 + akq);
        int gk = k0 + akq;
        if (gk+0<K) a0 = ap[0];
        if (gk+1<K) a1 = ap[1];
        if (gk+2<K) a2 = ap[2];
        if (gk+3<K) a3 = ap[3];
        if (flags & 2){
          int b = gr / LL_;
          const float* mp = nm + b*NF;
          const float* rp = nr + b*NF;
          if (gk+0<K) a0 = (a0 - mp[gk+0]) * rp[gk+0];
          if (gk+1<K) a1 = (a1 - mp[gk+1]) * rp[gk+1];
          if (gk+2<K) a2 = (a2 - mp[gk+2]) * rp[gk+2];
          if (gk+3<K) a3 = (a3 - mp[gk+3]) * rp[gk+3];
        }
      }
      As[akq+0][arow]=a0; As[akq+1][arow]=a1; As[akq+2][arow]=a2; As[akq+3][arow]=a3;
    }
    // --- B tile (16x64) ---
    {
      int gk = k0 + bkr;
      int gc = bn + bcq;
      float b0=0.f,b1=0.f,b2=0.f,b3=0.f;
      if (gk < K){
        const float* bp = Bw + (size_t)gk * N + gc;
        if (gc+0<N) b0 = bp[0];
        if (gc+1<N) b1 = bp[1];
        if (gc+2<N) b2 = bp[2];
        if (gc+3<N) b3 = bp[3];
      }
      Bs[bkr][bcq+0]=b0; Bs[bkr][bcq+1]=b1; Bs[bkr][bcq+2]=b2; Bs[bkr][bcq+3]=b3;
    }
    __syncthreads();
#pragma unroll
    for (int kk=0; kk<16; ++kk){
      float a0=As[kk][ty4+0],a1=As[kk][ty4+1],a2=As[kk][ty4+2],a3=As[kk][ty4+3];
      float b0=Bs[kk][tx4+0],b1=Bs[kk][tx4+1],b2=Bs[kk][tx4+2],b3=Bs[kk][tx4+3];
      acc[0][0]=fmaf(a0,b0,acc[0][0]); acc[0][1]=fmaf(a0,b1,acc[0][1]);
      acc[0][2]=fmaf(a0,b2,acc[0][2]); acc[0][3]=fmaf(a0,b3,acc[0][3]);
      acc[1][0]=fmaf(a1,b0,acc[1][0]); acc[1][1]=fmaf(a1,b1,acc[1][1]);
      acc[1][2]=fmaf(a1,b2,acc[1][2]); acc[1][3]=fmaf(a1,b3,acc[1][3]);
      acc[2][0]=fmaf(a2,b0,acc[2][0]); acc[2][1]=fmaf(a2,b1,acc[2][1]);
      acc[2][2]=fmaf(a2,b2,acc[2][2]); acc[2][3]=fmaf(a2,b3,acc[2][3]);
      acc[3][0]=fmaf(a3,b0,acc[3][0]); acc[3][1]=fmaf(a3,b1,acc[3][1]);
      acc[3][2]=fmaf(a3,b2,acc[3][2]); acc[3][3]=fmaf(a3,b3,acc[3][3]);
    }
    __syncthreads();
  }
#pragma unroll
  for (int i=0;i<4;i++){
    int row = bm + ty4 + i;
    if (row >= M) continue;
#pragma unroll
    for (int j=0;j<4;j++){
      int col = bn + tx4 + j;
      if (col >= N) continue;
      float v = acc[i][j] + bias[col];
      if (flags & 1) v = fmaxf(v, 0.f);
      C[(size_t)row*N + col] = v;
    }
  }
}

// ---------------- sampled QK dots ----------------
__global__ __launch_bounds__(256) void qksamp_k(const float* __restrict__ q,
                                                const float* __restrict__ k,
                                                const int* __restrict__ samp,
                                                float* __restrict__ qks){
  long long i = (long long)blockIdx.x*256 + threadIdx.x;
  if (i >= (long long)BB_*HH_*LL_*UK) return;
  int s = (int)(i % UK);
  long long r = i / UK;
  int l = (int)(r % LL_);
  int bh = (int)(r / LL_);
  int h = bh % HH_; int b = bh / HH_;
  int j = samp[l*UK + s];
  const float* qp = q + ((size_t)b*LL_ + l)*DM + h*DH;
  const float* kp = k + ((size_t)b*LL_ + j)*DM + h*DH;
  float acc = 0.f;
#pragma unroll
  for (int d=0; d<DH; ++d) acc = fmaf(qp[d], kp[d], acc);
  qks[i] = acc;
}

// M = max_s(qks) - sum_s(qks)/L
__global__ __launch_bounds__(256) void mscore_k(const float* __restrict__ qks,
                                                float* __restrict__ Mb){
  int i = blockIdx.x*256 + threadIdx.x;
  if (i >= BB_*HH_*LL_) return;
  const float* p = qks + (size_t)i*UK;
  float mx = -INFINITY, sm = 0.f;
#pragma unroll
  for (int s=0;s<UK;++s){ float v=p[s]; mx=fmaxf(mx,v); sm+=v; }
  Mb[i] = mx - sm*(1.f/LL_);
}

// ---------------- top-U per (b,h) ----------------
__global__ __launch_bounds__(256) void topk_k(const float* __restrict__ Mb,
                                              int* __restrict__ mtop){
  __shared__ float sv[LL_];
  __shared__ float bv[4]; __shared__ int bi[4];
  int bh = blockIdx.x;
  const float* mp = Mb + (size_t)bh*LL_;
  int t = threadIdx.x;
  for (int j=t;j<LL_;j+=256) sv[j]=mp[j];
  __syncthreads();
  for (int it=0; it<UK; ++it){
    float best=-INFINITY; int bidx=LL_;
    for (int j=t;j<LL_;j+=256){
      float v=sv[j];
      if (v>best){best=v;bidx=j;}
    }
#pragma unroll
    for(int o=32;o>0;o>>=1){
      float ov=__shfl_xor(best,o,64); int oi=__shfl_xor(bidx,o,64);
      if (ov>best || (ov==best && oi<bidx)){best=ov;bidx=oi;}
    }
    int lane=t&63, wid=t>>6;
    if(lane==0){bv[wid]=best;bi[wid]=bidx;}
    __syncthreads();
    if(t==0){
      float bb=bv[0]; int ii=bi[0];
      for(int w=1;w<4;w++){ if(bv[w]>bb || (bv[w]==bb && bi[w]<ii)){bb=bv[w];ii=bi[w];} }
      mtop[(size_t)bh*UK+it]=ii;
      sv[ii]=-INFINITY;
    }
    __syncthreads();
  }
}

// ---------------- v mean over L ----------------
__global__ __launch_bounds__(256) void vmean_k(const float* __restrict__ v,
                                               float* __restrict__ vmn){
  int i = blockIdx.x*256 + threadIdx.x;
  if (i >= BB_*HH_*DH) return;
  int d = i & 63; int h = (i>>6) % HH_; int b = i/(64*HH_);
  const float* vp = v + (size_t)b*LL_*DM + h*DH + d;
  float s=0.f;
  for (int l=0;l<LL_;++l) s += vp[(size_t)l*DM];
  vmn[i] = s*(1.f/LL_);
}

// ---------------- dense attention for the U selected queries ----------------
__global__ __launch_bounds__(256) void attn_k(const float* __restrict__ q,
                                              const float* __restrict__ k,
                                              const float* __restrict__ v,
                                              const int* __restrict__ mtop,
                                              float* __restrict__ upd){
  __shared__ float qrow[DH];
  __shared__ float sc[LL_];
  __shared__ float red[4];
  __shared__ float pv[4][DH];
  int idx = blockIdx.x;               // (b*H+h)*UK+u
  int bh = idx / UK;
  int h = bh % HH_; int b = bh / HH_;
  int lrow = mtop[idx];
  int t = threadIdx.x;
  if (t < DH) qrow[t] = q[((size_t)b*LL_ + lrow)*DM + h*DH + t];
  __syncthreads();
  float lmax = -INFINITY;
  for (int j=t;j<LL_;j+=256){
    const float* kp = k + ((size_t)b*LL_ + j)*DM + h*DH;
    float a=0.f;
#pragma unroll
    for(int d=0;d<DH;++d) a = fmaf(qrow[d],kp[d],a);
    a *= 0.125f;
    sc[j]=a;
    lmax = fmaxf(lmax,a);
  }
  float mx = bredmax(lmax, red);
  float lsum = 0.f;
  for (int j=t;j<LL_;j+=256){ float e = expf(sc[j]-mx); sc[j]=e; lsum+=e; }
  float se = bredsum(lsum, red);
  float inv = 1.f/se;
  int d = t & 63, g = t >> 6;
  float acc=0.f;
  for (int j=g;j<LL_;j+=4) acc = fmaf(sc[j], v[((size_t)b*LL_+j)*DM + h*DH + d], acc);
  pv[g][d]=acc;
  __syncthreads();
  if (t < DH){
    upd[(size_t)idx*DH + t] = (pv[0][t]+pv[1][t]+pv[2][t]+pv[3][t])*inv;
  }
}

// ---------------- ctx = broadcast v_mean ----------------
__global__ __launch_bounds__(256) void ctxfill_k(const float* __restrict__ vmn,
                                                 float* __restrict__ cx){
  long long i = (long long)blockIdx.x*256 + threadIdx.x;
  if (i >= (long long)BL*DM) return;
  int c = (int)(i % DM);
  int bl = (int)(i / DM);
  int b = bl / LL_;
  cx[i] = vmn[(b*HH_ + (c>>6))*DH + (c&63)];
}

__global__ __launch_bounds__(64) void scatter_k(const float* __restrict__ upd,
                                                const int* __restrict__ mtop,
                                                float* __restrict__ cx){
  int idx = blockIdx.x;
  int bh = idx / UK;
  int h = bh % HH_; int b = bh / HH_;
  int lrow = mtop[idx];
  cx[((size_t)b*LL_ + lrow)*DM + h*DH + threadIdx.x] = upd[(size_t)idx*DH + threadIdx.x];
}

// ---------------- out = LayerNorm(a - s) ----------------
__global__ __launch_bounds__(256) void subln_k(const float* __restrict__ a,
                                               const float* __restrict__ s,
                                               const float* __restrict__ g,
                                               const float* __restrict__ be,
                                               float* __restrict__ outp){
  __shared__ float red[4];
  int row = blockIdx.x;
  size_t base = (size_t)row * DM;
  int t = threadIdx.x;
  float e0 = a[base+t]     - s[base+t];
  float e1 = a[base+t+256] - s[base+t+256];
  float sum = bredsum(e0+e1, red);
  float mu = sum * (1.f/DM);
  float d0 = e0-mu, d1 = e1-mu;
  float var = bredsum(d0*d0+d1*d1, red);
  float rs = rsqrtf(var*(1.f/DM) + EPSF);
  outp[base+t]     = d0*rs*g[t]     + be[t];
  outp[base+t+256] = d1*rs*g[t+256] + be[t+256];
}

// ---------------- y (+)= t1 * sigmoid(t2) ----------------
__global__ __launch_bounds__(256) void yupd_k(const float* __restrict__ t1,
                                              const float* __restrict__ t2,
                                              float* __restrict__ y,
                                              int accum){
  long long i = (long long)blockIdx.x*256 + threadIdx.x;
  if (i >= (long long)BL*PRED) return;
  float a = t1[i];
  float gg = t2[i];
  float sg = 1.f/(1.f+expf(-gg));
  float val = a*sg;
  y[i] = accum ? (y[i] + val) : val;
}

// ---------------- final: out[b,p,n] = y[b,n,p]*std + mean ----------------
__global__ __launch_bounds__(256) void final_k(const float* __restrict__ y,
                                               const float* __restrict__ stdv,
                                               const float* __restrict__ mean,
                                               float* __restrict__ out){
  long long i = (long long)blockIdx.x*256 + threadIdx.x;
  if (i >= (long long)BB_*PRED*NF) return;
  int n = (int)(i % NF);
  long long r = i / NF;
  int p = (int)(r % PRED);
  int b = (int)(r / PRED);
  out[i] = y[((size_t)b*LL_ + n)*PRED + p] * stdv[b*NF+n] + mean[b*NF+n];
}

// ---------------- host launch ----------------
static inline void gemm_launch(const float* A, const float* Bw, const float* bias,
                               float* C, int M, int N, int K, int flags,
                               const float* nm, const float* nr, hipStream_t st){
  dim3 grid((N+63)/64, (M+63)/64);
  gemm_k<<<grid, 256, 0, st>>>(A, Bw, bias, C, M, N, K, flags, nm, nr);
}

extern "C" void kernel_launch(void* const* d_in, const int* in_sizes, int n_in,
                              void* d_out, int out_size, void* d_ws, size_t ws_size,
                              hipStream_t stream){
  const float* x_enc  = (const float*)d_in[0];
  const int*   samp   = (const int*)  d_in[1];
  const float* embw   = (const float*)d_in[2];
  const float* embb   = (const float*)d_in[3];
  const float* wq     = (const float*)d_in[4];
  const float* bq     = (const float*)d_in[5];
  const float* wk     = (const float*)d_in[6];
  const float* bk     = (const float*)d_in[7];
  const float* wv     = (const float*)d_in[8];
  const float* bv     = (const float*)d_in[9];
  const float* wo     = (const float*)d_in[10];
  const float* bo     = (const float*)d_in[11];
  const float* ln1g   = (const float*)d_in[12];
  const float* ln1b   = (const float*)d_in[13];
  const float* w1     = (const float*)d_in[14];
  const float* b1     = (const float*)d_in[15];
  const float* w2     = (const float*)d_in[16];
  const float* b2     = (const float*)d_in[17];
  const float* ln2g   = (const float*)d_in[18];
  const float* ln2b   = (const float*)d_in[19];
  const float* wout   = (const float*)d_in[20];
  const float* boutp  = (const float*)d_in[21];
  const float* wg     = (const float*)d_in[22];
  const float* bg     = (const float*)d_in[23];
  float* out = (float*)d_out;

  float* ws = (float*)d_ws;
  size_t o = 0;
  auto alloc = [&](size_t n)->float*{ float* p = ws + o; o += (n + 255) & ~(size_t)255; return p; };
  float* mean = alloc(BB_*NF);
  float* stdv = alloc(BB_*NF);
  float* rstd = alloc(BB_*NF);
  float* h    = alloc((size_t)BL*DM);
  float* q    = alloc((size_t)BL*DM);
  float* k    = alloc((size_t)BL*DM);
  float* v    = alloc((size_t)BL*DM);
  float* Mb   = alloc((size_t)BB_*HH_*LL_);
  int*   mtop = (int*)alloc(BB_*HH_*UK);
  float* vmn  = alloc(BB_*HH_*DH);
  float* upd  = alloc((size_t)BB_*HH_*UK*DH);
  float* qks  = alloc((size_t)BB_*HH_*LL_*UK);
  float* cx   = alloc((size_t)BL*DM);   // ctx, then hx
  float* aout = alloc((size_t)BL*DM);
  float* ff1  = alloc((size_t)BL*DFF);
  float* y    = alloc((size_t)BL*PRED);
  if (o * sizeof(float) > ws_size) return;  // workspace too small: bail

  // 1. stats over x^T rows
  stats_k<<<BB_*NF, 256, 0, stream>>>(x_enc, mean, stdv, rstd);
  // 2. embed GEMM with fused normalization of A
  gemm_launch(x_enc, embw, embb, h, BL, DM, NF, 2, mean, rstd, stream);

  for (int l=0; l<NLAY; ++l){
    const float* wq_l = wq + (size_t)l*DM*DM; const float* bq_l = bq + (size_t)l*DM;
    const float* wk_l = wk + (size_t)l*DM*DM; const float* bk_l = bk + (size_t)l*DM;
    const float* wv_l = wv + (size_t)l*DM*DM; const float* bv_l = bv + (size_t)l*DM;
    const float* wo_l = wo + (size_t)l*DM*DM; const float* bo_l = bo + (size_t)l*DM;
    const float* w1_l = w1 + (size_t)l*DM*DFF; const float* b1_l = b1 + (size_t)l*DFF;
    const float* w2_l = w2 + (size_t)l*DFF*DM; const float* b2_l = b2 + (size_t)l*DM;
    const float* wo_t = wout + (size_t)l*DM*PRED; const float* bo_t = boutp + (size_t)l*PRED;
    const float* wg_l = wg + (size_t)l*DM*PRED; const float* bg_l = bg + (size_t)l*PRED;

    gemm_launch(h, wq_l, bq_l, q, BL, DM, DM, 0, nullptr, nullptr, stream);
    gemm_launch(h, wk_l, bk_l, k, BL, DM, DM, 0, nullptr, nullptr, stream);
    gemm_launch(h, wv_l, bv_l, v, BL, DM, DM, 0, nullptr, nullptr, stream);

    {
      long long tot = (long long)BB_*HH_*LL_*UK;
      qksamp_k<<<(int)((tot+255)/256), 256, 0, stream>>>(q, k, samp, qks);
    }
    mscore_k<<<(BB_*HH_*LL_+255)/256, 256, 0, stream>>>(qks, Mb);
    topk_k<<<BB_*HH_, 256, 0, stream>>>(Mb, mtop);
    vmean_k<<<(BB_*HH_*DH+255)/256, 256, 0, stream>>>(v, vmn);
    attn_k<<<BB_*HH_*UK, 256, 0, stream>>>(q, k, v, mtop, upd);
    {
      long long tot = (long long)BL*DM;
      ctxfill_k<<<(int)((tot+255)/256), 256, 0, stream>>>(vmn, cx);
    }
    scatter_k<<<BB_*HH_*UK, 64, 0, stream>>>(upd, mtop, cx);

    gemm_launch(cx, wo_l, bo_l, aout, BL, DM, DM, 0, nullptr, nullptr, stream);
    subln_k<<<BL, 256, 0, stream>>>(h, aout, ln1g + (size_t)l*DM, ln1b + (size_t)l*DM, cx); // cx = hx
    gemm_launch(cx, w1_l, b1_l, ff1, BL, DFF, DM, 1, nullptr, nullptr, stream);
    gemm_launch(ff1, w2_l, b2_l, q, BL, DM, DFF, 0, nullptr, nullptr, stream);  // q = ff2
    subln_k<<<BL, 256, 0, stream>>>(cx, q, ln2g + (size_t)l*DM, ln2b + (size_t)l*DM, h);

    gemm_launch(h, wo_t, bo_t, k, BL, PRED, DM, 0, nullptr, nullptr, stream);   // k = t1
    gemm_launch(h, wg_l, bg_l, v, BL, PRED, DM, 0, nullptr, nullptr, stream);   // v = t2
    {
      long long tot = (long long)BL*PRED;
      yupd_k<<<(int)((tot+255)/256), 256, 0, stream>>>(k, v, y, l==0?0:1);
    }
  }
  {
    long long tot = (long long)BB_*PRED*NF;
    final_k<<<(int)((tot+255)/256), 256, 0, stream>>>(y, stdv, mean, out);
  }
}

// Round 3
// 1150.371 us; speedup vs baseline: 1.5987x; 1.5987x over previous
//
#include <hip/hip_runtime.h>
#include <math.h>

#define BB_ 8
#define LL_ 720
#define NF 321
#define DM 512
#define HH_ 8
#define DH 64
#define DFF 128
#define PRED 336
#define UK 35
#define NLAY 2
#define EPSF 1e-5f
#define BL (BB_*LL_)

typedef unsigned short ushort;
typedef __attribute__((ext_vector_type(4))) float f32x4;
typedef __attribute__((ext_vector_type(8))) ushort ushort8;

// ---------- bf16 <-> f32 (raw ushort bits) ----------
__device__ __forceinline__ float b2f(ushort u){
  unsigned int x = ((unsigned int)u) << 16;
  return __builtin_bit_cast(float, x);
}
__device__ __forceinline__ ushort f2b(float f){
  unsigned int x = __builtin_bit_cast(unsigned int, f);
  unsigned int r = x + 0x7fff + ((x >> 16) & 1);   // RNE
  return (ushort)(r >> 16);
}

// ---------- reductions ----------
__device__ __forceinline__ float wredsum(float v){
#pragma unroll
  for (int o=32;o>0;o>>=1) v += __shfl_xor(v,o,64);
  return v;
}
__device__ __forceinline__ float wredmax(float v){
#pragma unroll
  for (int o=32;o>0;o>>=1) v = fmaxf(v,__shfl_xor(v,o,64));
  return v;
}
__device__ __forceinline__ float bredsum(float v, float* red){
  int lane = threadIdx.x & 63, wid = threadIdx.x >> 6;
  v = wredsum(v);
  __syncthreads();
  if (lane==0) red[wid]=v;
  __syncthreads();
  return red[0]+red[1]+red[2]+red[3];
}

// ---------- stats over L for x^T (B,N,L) ----------
__global__ __launch_bounds__(256) void stats_k(const float* __restrict__ x,
                                               float* __restrict__ mean,
                                               float* __restrict__ stdv,
                                               float* __restrict__ rstd){
  __shared__ float red[4];
  int bn = blockIdx.x;
  int b = bn / NF; int n = bn % NF;
  const float* xp = x + (size_t)b*LL_*NF + n;
  int t = threadIdx.x;
  float s = 0.f;
  for (int l=t;l<LL_;l+=256) s += xp[(size_t)l*NF];
  s = bredsum(s, red);
  float mu = s * (1.f/LL_);
  float s2 = 0.f;
  for (int l=t;l<LL_;l+=256){ float d = xp[(size_t)l*NF]-mu; s2 += d*d; }
  s2 = bredsum(s2, red);
  if (t==0){
    mean[bn]=mu;
    float sd = sqrtf(s2*(1.f/(LL_-1))) + EPSF;
    stdv[bn]=sd;
    rstd[bn]=1.f/sd;
  }
}

// ---------- normalized input -> bf16, K padded to 352 ----------
#define KPE 352
__global__ __launch_bounds__(256) void xnorm_k(const float* __restrict__ x,
                                               const float* __restrict__ mean,
                                               const float* __restrict__ rstd,
                                               ushort* __restrict__ xn){
  int idx = blockIdx.x*256 + threadIdx.x;
  if (idx >= BL*KPE) return;
  int c = idx % KPE; int bl = idx / KPE; int b = bl / LL_;
  float v = 0.f;
  if (c < NF) v = (x[(size_t)bl*NF + c] - mean[b*NF+c]) * rstd[b*NF+c];
  xn[idx] = f2b(v);
}

// ---------- weight transpose+convert mega-kernel ----------
struct TDesc { const float* in; ushort* out; int N, K, Npad, Kpad, nbx, blk0; };
struct TPack { TDesc d[17]; int n; };
__global__ __launch_bounds__(256) void transpose_k(TPack p){
  __shared__ float tile[32][33];
  int blk = blockIdx.x;
  int di = 0;
  while (di+1 < p.n && p.d[di+1].blk0 <= blk) ++di;
  TDesc D = p.d[di];
  int rel = blk - D.blk0;
  int bx = rel % D.nbx, by = rel / D.nbx;
  int k0 = bx*32, n0 = by*32;
  int t = threadIdx.x; int tx = t & 31, ty = t >> 5;
#pragma unroll
  for (int i=0;i<4;++i){
    int k = k0+ty+8*i, n = n0+tx;
    float v = (k < D.K && n < D.N) ? D.in[(size_t)k*D.N + n] : 0.f;
    tile[ty+8*i][tx] = v;
  }
  __syncthreads();
#pragma unroll
  for (int i=0;i<4;++i){
    int n = n0+ty+8*i, k = k0+tx;
    if (n < D.Npad && k < D.Kpad) D.out[(size_t)n*D.Kpad + k] = f2b(tile[tx][ty+8*i]);
  }
}

// ---------- fused bias packing (qkv + out/gate) ----------
__global__ __launch_bounds__(256) void pack_bias_k(const float* __restrict__ bq,
                                                   const float* __restrict__ bk,
                                                   const float* __restrict__ bv,
                                                   const float* __restrict__ bo2,
                                                   const float* __restrict__ bg,
                                                   float* __restrict__ bqkv,
                                                   float* __restrict__ bog){
  int t = blockIdx.x*256 + threadIdx.x;
  if (t < 2*1536){
    int l = t/1536, c = t%1536;
    float v = c<512 ? bq[l*512+c] : (c<1024 ? bk[l*512+c-512] : bv[l*512+c-1024]);
    bqkv[t] = v;
  }
  if (t < 2*672){
    int l = t/672, c = t%672;
    bog[t] = c<336 ? bo2[l*336+c] : bg[l*336+c-336];
  }
}

// ---------- bf16 MFMA GEMM: C[M,N] = A[M,K] @ Bt[N,K]^T + bias ----------
// flags: 1 = relu, 2 = bf16-only out (Cout is ushort*), 4 = dual store (Cout fp32 + Cbf bf16)
__global__ __launch_bounds__(256) void gemm_k(
    const ushort* __restrict__ A, const ushort* __restrict__ Bt,
    const float* __restrict__ bias, void* __restrict__ Cout,
    ushort* __restrict__ Cbf,
    int N, int K, int flags)
{
  __shared__ ushort As[128*32];
  __shared__ ushort Bs[128*32];
  const int t = threadIdx.x;
  const int bm = blockIdx.y << 7, bn = blockIdx.x << 7;
  const int lane = t & 63, wid = t >> 6;
  const int wm = (wid >> 1) << 6, wn = (wid & 1) << 6;
  const int fr = lane & 15, kg = lane >> 4;

  f32x4 acc[4][4];
#pragma unroll
  for (int i=0;i<4;++i)
#pragma unroll
    for (int j=0;j<4;++j) acc[i][j] = (f32x4){0.f,0.f,0.f,0.f};

  const int rA0 = t >> 2,        qA0 = t & 3;
  const int rA1 = (t+256) >> 2;
  const size_t aOff0 = (size_t)(bm + rA0)*K + qA0*8;
  const size_t aOff1 = (size_t)(bm + rA1)*K + qA0*8;
  const size_t bOff0 = (size_t)(bn + rA0)*K + qA0*8;
  const size_t bOff1 = (size_t)(bn + rA1)*K + qA0*8;
  const int lA0 = (rA0<<5) + ((qA0 ^ ((rA0>>1)&3))<<3);
  const int lA1 = (rA1<<5) + ((qA0 ^ ((rA1>>1)&3))<<3);

  for (int k0=0; k0<K; k0+=32){
    ushort8 va0 = *(const ushort8*)(A  + aOff0 + k0);
    ushort8 va1 = *(const ushort8*)(A  + aOff1 + k0);
    ushort8 vb0 = *(const ushort8*)(Bt + bOff0 + k0);
    ushort8 vb1 = *(const ushort8*)(Bt + bOff1 + k0);
    *(ushort8*)&As[lA0] = va0;
    *(ushort8*)&As[lA1] = va1;
    *(ushort8*)&Bs[lA0] = vb0;
    *(ushort8*)&Bs[lA1] = vb1;
    __syncthreads();
    ushort8 af[4], bfr[4];
#pragma unroll
    for (int i=0;i<4;++i){
      int ra = wm + (i<<4) + fr;
      af[i]  = *(const ushort8*)&As[(ra<<5) + ((kg ^ ((ra>>1)&3))<<3)];
      int rb = wn + (i<<4) + fr;
      bfr[i] = *(const ushort8*)&Bs[(rb<<5) + ((kg ^ ((rb>>1)&3))<<3)];
    }
#pragma unroll
    for (int i=0;i<4;++i)
#pragma unroll
      for (int j=0;j<4;++j)
        asm("v_mfma_f32_16x16x32_bf16 %0, %1, %2, %0"
            : "+v"(acc[i][j]) : "v"(af[i]), "v"(bfr[j]));
    __syncthreads();
  }

  const int colBase = bn + wn + fr;
  const int rowBase = bm + wm + (kg << 2);
#pragma unroll
  for (int j=0;j<4;++j){
    int col = colBase + (j<<4);
    if (col >= N) continue;
    float bv = bias[col];
#pragma unroll
    for (int i=0;i<4;++i){
      int row0 = rowBase + (i<<4);
#pragma unroll
      for (int r=0;r<4;++r){
        float v = acc[i][j][r] + bv;
        if (flags & 1) v = fmaxf(v, 0.f);
        size_t idx = (size_t)(row0+r)*N + col;
        if (flags & 2) ((ushort*)Cout)[idx] = f2b(v);
        else {
          ((float*)Cout)[idx] = v;
          if (flags & 4) Cbf[idx] = f2b(v);
        }
      }
    }
  }
}

// ---------- fused sampled-QK + M score: one wave per (b,h,l), lane=sample ----------
__global__ __launch_bounds__(256) void msc_k(const float* __restrict__ qkv,
                                             const int* __restrict__ samp,
                                             float* __restrict__ Mb){
  __shared__ float sq[4][64];
  int wid = threadIdx.x >> 6, lane = threadIdx.x & 63;
  int gid = blockIdx.x*4 + wid;                 // (b*H+h)*L + l
  int l = gid % LL_; int bh = gid / LL_; int h = bh & 7; int b = bh >> 3;
  const float* qrow = qkv + (size_t)(b*LL_ + l)*1536 + h*64;
  sq[wid][lane] = qrow[lane];
  __syncthreads();
  float acc = 0.f;
  if (lane < UK){
    int j = samp[l*UK + lane];
    const float4* k4 = (const float4*)(qkv + (size_t)(b*LL_ + j)*1536 + 512 + h*64);
    const float* sqw = sq[wid];
#pragma unroll
    for (int d4=0; d4<16; ++d4){
      float4 kk = k4[d4];
      acc = fmaf(sqw[d4*4+0], kk.x, acc);
      acc = fmaf(sqw[d4*4+1], kk.y, acc);
      acc = fmaf(sqw[d4*4+2], kk.z, acc);
      acc = fmaf(sqw[d4*4+3], kk.w, acc);
    }
  }
  float mx = (lane < UK) ? acc : -INFINITY;
  float sm = (lane < UK) ? acc : 0.f;
  mx = wredmax(mx);
  sm = wredsum(sm);
  if (lane == 0) Mb[gid] = mx - sm*(1.f/LL_);
}

// ---------- top-U per (b,h) ----------
__global__ __launch_bounds__(256) void topk_k(const float* __restrict__ Mb,
                                              int* __restrict__ mtop){
  __shared__ float sv[LL_];
  __shared__ float bv[4]; __shared__ int bi[4];
  int bh = blockIdx.x;
  const float* mp = Mb + (size_t)bh*LL_;
  int t = threadIdx.x;
  for (int j=t;j<LL_;j+=256) sv[j]=mp[j];
  __syncthreads();
  for (int it=0; it<UK; ++it){
    float best=-INFINITY; int bidx=LL_;
    for (int j=t;j<LL_;j+=256){
      float v=sv[j];
      if (v>best){best=v;bidx=j;}
    }
#pragma unroll
    for(int o=32;o>0;o>>=1){
      float ov=__shfl_xor(best,o,64); int oi=__shfl_xor(bidx,o,64);
      if (ov>best || (ov==best && oi<bidx)){best=ov;bidx=oi;}
    }
    int lane=t&63, wid=t>>6;
    if(lane==0){bv[wid]=best;bi[wid]=bidx;}
    __syncthreads();
    if(t==0){
      float bb=bv[0]; int ii=bi[0];
      for(int w=1;w<4;w++){ if(bv[w]>bb || (bv[w]==bb && bi[w]<ii)){bb=bv[w];ii=bi[w];} }
      mtop[(size_t)bh*UK+it]=ii;
      sv[ii]=-INFINITY;
    }
    __syncthreads();
  }
}

// ---------- v mean over L, per (b,h) block ----------
__global__ __launch_bounds__(256) void vmean_k(const float* __restrict__ qkv,
                                               float* __restrict__ vmn){
  __shared__ float part[4][64];
  int bh = blockIdx.x; int b = bh >> 3, h = bh & 7;
  int t = threadIdx.x; int d = t & 63, jg = t >> 6;
  const float* vb = qkv + (size_t)b*LL_*1536 + 1024 + h*64 + d;
  float s = 0.f;
  for (int j=jg; j<LL_; j+=4) s += vb[(size_t)j*1536];
  part[jg][d] = s;
  __syncthreads();
  if (t < 64) vmn[bh*64+t] = (part[0][t]+part[1][t]+part[2][t]+part[3][t])*(1.f/LL_);
}

// ---------- ctx = broadcast v_mean (bf16) ----------
__global__ __launch_bounds__(256) void ctxfill_k(const float* __restrict__ vmn,
                                                 ushort* __restrict__ ctx){
  int idx = blockIdx.x*256 + threadIdx.x;   // < BL*DM
  int c = idx & 511; int bl = idx >> 9; int b = bl / LL_;
  ctx[idx] = f2b(vmn[(b*8 + (c>>6))*64 + (c&63)]);
}

// ---------- dense attention for 7-query chunks, scatter into ctx ----------
__global__ __launch_bounds__(256) void attn2_k(const float* __restrict__ qkv,
                                               const int* __restrict__ mtop,
                                               ushort* __restrict__ ctx){
  __shared__ float sq[7][64];
  __shared__ float sc[7][LL_];
  __shared__ float sden[8];
  __shared__ int rows[7];
  int blk = blockIdx.x;
  int uc = blk % 5; int bh = blk / 5; int h = bh & 7; int b = bh >> 3;
  int t = threadIdx.x;
  if (t < 7) rows[t] = mtop[bh*UK + uc*7 + t];
  __syncthreads();
  for (int idx=t; idx<7*64; idx+=256){          // FIXED: full 448-element load
    int u = idx >> 6, d = idx & 63;
    sq[u][d] = qkv[(size_t)(b*LL_ + rows[u])*1536 + h*64 + d];
  }
  __syncthreads();
  for (int idx=t; idx<7*LL_; idx+=256){
    int u = idx / LL_, j = idx - u*LL_;
    const float4* k4 = (const float4*)(qkv + (size_t)(b*LL_ + j)*1536 + 512 + h*64);
    float acc = 0.f;
#pragma unroll
    for (int d4=0; d4<16; ++d4){
      float4 kk = k4[d4];
      acc = fmaf(sq[u][d4*4+0], kk.x, acc);
      acc = fmaf(sq[u][d4*4+1], kk.y, acc);
      acc = fmaf(sq[u][d4*4+2], kk.z, acc);
      acc = fmaf(sq[u][d4*4+3], kk.w, acc);
    }
    sc[u][j] = acc * 0.125f;
  }
  __syncthreads();
  int wid = t >> 6, lane = t & 63;
  for (int u=wid; u<7; u+=4){
    float mx = -INFINITY;
    for (int j=lane; j<LL_; j+=64) mx = fmaxf(mx, sc[u][j]);
    mx = wredmax(mx);
    float s = 0.f;
    for (int j=lane; j<LL_; j+=64){ float e = __expf(sc[u][j]-mx); sc[u][j]=e; s+=e; }
    s = wredsum(s);
    if (lane==0) sden[u] = 1.f/s;
  }
  __syncthreads();
  int d = t & 63, ug = t >> 6;
  int u0 = ug, u1 = ug + 4;
  float a0 = 0.f, a1 = 0.f;
  const float* vbase = qkv + (size_t)b*LL_*1536 + 1024 + h*64 + d;
#pragma unroll 4
  for (int j=0; j<LL_; ++j){
    float vv = vbase[(size_t)j*1536];
    a0 = fmaf(sc[u0][j], vv, a0);
    if (u1 < 7) a1 = fmaf(sc[u1][j], vv, a1);
  }
  ctx[(size_t)(b*LL_ + rows[u0])*DM + h*64 + d] = f2b(a0*sden[u0]);
  if (u1 < 7)
    ctx[(size_t)(b*LL_ + rows[u1])*DM + h*64 + d] = f2b(a1*sden[u1]);
}

// ---------- LN(a - s): fp32 residual chain, dual output ----------
__global__ __launch_bounds__(256) void subln_k(const float* __restrict__ a,
                                               const float* __restrict__ s,
                                               const float* __restrict__ g,
                                               const float* __restrict__ be,
                                               float* __restrict__ of32,
                                               ushort* __restrict__ obf){
  __shared__ float red[4];
  int row = blockIdx.x;
  size_t base = (size_t)row * DM;
  int t = threadIdx.x;
  float e0 = a[base+t]     - s[base+t];
  float e1 = a[base+t+256] - s[base+t+256];
  float sum = bredsum(e0+e1, red);
  float mu = sum * (1.f/DM);
  float d0 = e0-mu, d1 = e1-mu;
  __syncthreads();
  float var = bredsum(d0*d0+d1*d1, red);
  float rs = rsqrtf(var*(1.f/DM) + EPSF);
  float o0 = d0*rs*g[t]     + be[t];
  float o1 = d1*rs*g[t+256] + be[t+256];
  of32[base+t]     = o0;
  of32[base+t+256] = o1;
  obf[base+t]      = f2b(o0);
  obf[base+t+256]  = f2b(o1);
}

// ---------- y (+)= t1 * sigmoid(t2) from fused og[M][672] ----------
__global__ __launch_bounds__(256) void yupd_k(const float* __restrict__ og,
                                              float* __restrict__ y, int accum){
  int idx = blockIdx.x*256 + threadIdx.x;
  if (idx >= BL*PRED) return;
  int m = idx / PRED, p = idx - m*PRED;
  float t1 = og[(size_t)m*672 + p];
  float t2 = og[(size_t)m*672 + 336 + p];
  float val = t1 * (1.f/(1.f+__expf(-t2)));
  y[idx] = accum ? (y[idx] + val) : val;
}

// ---------- final: out[b,p,n] = y[b,n,p]*std + mean ----------
__global__ __launch_bounds__(256) void final_k(const float* __restrict__ y,
                                               const float* __restrict__ stdv,
                                               const float* __restrict__ mean,
                                               float* __restrict__ out){
  int idx = blockIdx.x*256 + threadIdx.x;
  if (idx >= BB_*PRED*NF) return;
  int n = idx % NF;
  int r = idx / NF;
  int p = r % PRED;
  int b = r / PRED;
  out[idx] = y[((size_t)b*LL_ + n)*PRED + p] * stdv[b*NF+n] + mean[b*NF+n];
}

// ---------------- host ----------------
extern "C" void kernel_launch(void* const* d_in, const int* in_sizes, int n_in,
                              void* d_out, int out_size, void* d_ws, size_t ws_size,
                              hipStream_t stream){
  const float* x_enc = (const float*)d_in[0];
  const int*   samp  = (const int*)  d_in[1];
  const float* embw  = (const float*)d_in[2];
  const float* embb  = (const float*)d_in[3];
  const float* wq    = (const float*)d_in[4];
  const float* bq    = (const float*)d_in[5];
  const float* wk    = (const float*)d_in[6];
  const float* bk    = (const float*)d_in[7];
  const float* wv    = (const float*)d_in[8];
  const float* bv    = (const float*)d_in[9];
  const float* wo    = (const float*)d_in[10];
  const float* bo    = (const float*)d_in[11];
  const float* ln1g  = (const float*)d_in[12];
  const float* ln1b  = (const float*)d_in[13];
  const float* w1    = (const float*)d_in[14];
  const float* b1    = (const float*)d_in[15];
  const float* w2    = (const float*)d_in[16];
  const float* b2    = (const float*)d_in[17];
  const float* ln2g  = (const float*)d_in[18];
  const float* ln2b  = (const float*)d_in[19];
  const float* wout  = (const float*)d_in[20];
  const float* boutp = (const float*)d_in[21];
  const float* wg    = (const float*)d_in[22];
  const float* bg    = (const float*)d_in[23];
  float* out = (float*)d_out;

  char* wsb = (char*)d_ws;
  size_t off = 0;
  auto alloc = [&](size_t bytes)->void*{
    void* p = wsb + off; off += (bytes + 255) & ~(size_t)255; return p;
  };
  float* mean  = (float*)alloc((size_t)BB_*NF*4);
  float* stdv  = (float*)alloc((size_t)BB_*NF*4);
  float* rstd  = (float*)alloc((size_t)BB_*NF*4);
  float* bqkv  = (float*)alloc(2*1536*4);
  float* bog   = (float*)alloc(2*672*4);
  ushort* xn     = (ushort*)alloc((size_t)BL*KPE*2);
  ushort* we_t   = (ushort*)alloc((size_t)512*KPE*2);
  ushort* wqkv_t = (ushort*)alloc((size_t)2*1536*512*2);
  ushort* wo_t   = (ushort*)alloc((size_t)2*512*512*2);
  ushort* w1_t   = (ushort*)alloc((size_t)2*128*512*2);
  ushort* w2_t   = (ushort*)alloc((size_t)2*512*128*2);
  ushort* wog_t  = (ushort*)alloc((size_t)2*768*512*2);
  ushort* h_bf   = (ushort*)alloc((size_t)BL*DM*2);
  ushort* hx_bf  = (ushort*)alloc((size_t)BL*DM*2);
  ushort* ctx_bf = (ushort*)alloc((size_t)BL*DM*2);
  ushort* ff1_bf = (ushort*)alloc((size_t)BL*DFF*2);
  float* h_f32   = (float*)alloc((size_t)BL*DM*4);
  float* hx_f32  = (float*)alloc((size_t)BL*DM*4);
  float* qkv = (float*)alloc((size_t)BL*1536*4);   // reused as og [BL][672] later
  float* tmp = (float*)alloc((size_t)BL*DM*4);
  float* y   = (float*)alloc((size_t)BL*PRED*4);
  float* Mb  = (float*)alloc((size_t)BB_*HH_*LL_*4);
  int*  mtop = (int*)  alloc((size_t)BB_*HH_*UK*4);
  float* vmn = (float*)alloc((size_t)BB_*HH_*DH*4);
  if (off > ws_size) return;

  stats_k<<<BB_*NF, 256, 0, stream>>>(x_enc, mean, stdv, rstd);
  xnorm_k<<<(BL*KPE+255)/256, 256, 0, stream>>>(x_enc, mean, rstd, xn);

  TPack tp; int blk = 0; int di = 0;
  auto addT = [&](const float* in, ushort* o, int N, int K, int Npad, int Kpad){
    TDesc& d = tp.d[di++]; d.in=in; d.out=o; d.N=N; d.K=K; d.Npad=Npad; d.Kpad=Kpad;
    d.nbx = (Kpad+31)/32; d.blk0 = blk; blk += d.nbx * ((Npad+31)/32);
  };
  addT(embw, we_t, 512, NF, 512, KPE);
  for (int l=0;l<NLAY;++l){
    addT(wq + (size_t)l*262144, wqkv_t + (size_t)l*786432,            512,512,512,512);
    addT(wk + (size_t)l*262144, wqkv_t + (size_t)l*786432 + 262144,   512,512,512,512);
    addT(wv + (size_t)l*262144, wqkv_t + (size_t)l*786432 + 524288,   512,512,512,512);
    addT(wo + (size_t)l*262144, wo_t   + (size_t)l*262144,            512,512,512,512);
    addT(w1 + (size_t)l*65536,  w1_t   + (size_t)l*65536,             128,512,128,512);
    addT(w2 + (size_t)l*65536,  w2_t   + (size_t)l*65536,             512,128,512,128);
    addT(wout + (size_t)l*172032, wog_t + (size_t)l*393216,           336,512,336,512);
    addT(wg   + (size_t)l*172032, wog_t + (size_t)l*393216 + 172032,  336,512,432,512);
  }
  tp.n = di;
  transpose_k<<<blk, 256, 0, stream>>>(tp);
  pack_bias_k<<<12, 256, 0, stream>>>(bq, bk, bv, boutp, bg, bqkv, bog);

  // embed: h = xn @ embw + embb  (dual fp32 + bf16)
  gemm_k<<<dim3(4,45), 256, 0, stream>>>(xn, we_t, embb, h_f32, h_bf, 512, KPE, 4);

  for (int l=0;l<NLAY;++l){
    gemm_k<<<dim3(12,45), 256, 0, stream>>>(h_bf, wqkv_t + (size_t)l*786432,
                                            bqkv + l*1536, qkv, nullptr, 1536, 512, 0);
    msc_k<<<BB_*HH_*LL_/4, 256, 0, stream>>>(qkv, samp, Mb);
    topk_k<<<BB_*HH_, 256, 0, stream>>>(Mb, mtop);
    vmean_k<<<BB_*HH_, 256, 0, stream>>>(qkv, vmn);
    ctxfill_k<<<BL*DM/256, 256, 0, stream>>>(vmn, ctx_bf);
    attn2_k<<<BB_*HH_*5, 256, 0, stream>>>(qkv, mtop, ctx_bf);
    gemm_k<<<dim3(4,45), 256, 0, stream>>>(ctx_bf, wo_t + (size_t)l*262144,
                                           bo + l*512, tmp, nullptr, 512, 512, 0);
    subln_k<<<BL, 256, 0, stream>>>(h_f32, tmp, ln1g + l*512, ln1b + l*512,
                                    hx_f32, hx_bf);
    gemm_k<<<dim3(1,45), 256, 0, stream>>>(hx_bf, w1_t + (size_t)l*65536,
                                           b1 + l*128, ff1_bf, nullptr, 128, 512, 3);
    gemm_k<<<dim3(4,45), 256, 0, stream>>>(ff1_bf, w2_t + (size_t)l*65536,
                                           b2 + l*512, tmp, nullptr, 512, 128, 0);
    subln_k<<<BL, 256, 0, stream>>>(hx_f32, tmp, ln2g + l*512, ln2b + l*512,
                                    h_f32, h_bf);
    gemm_k<<<dim3(6,45), 256, 0, stream>>>(h_bf, wog_t + (size_t)l*393216,
                                           bog + l*672, qkv, nullptr, 672, 512, 0);
    yupd_k<<<(BL*PRED+255)/256, 256, 0, stream>>>(qkv, y, l==0?0:1);
  }
  final_k<<<(BB_*PRED*NF+255)/256, 256, 0, stream>>>(y, stdv, mean, out);
}

// Round 4
// 1099.292 us; speedup vs baseline: 1.6730x; 1.0465x over previous
//
#include <hip/hip_runtime.h>
#include <math.h>

#define BB_ 8
#define LL_ 720
#define NF 321
#define DM 512
#define HH_ 8
#define DH 64
#define DFF 128
#define PRED 336
#define UK 35
#define NLAY 2
#define EPSF 1e-5f
#define BL (BB_*LL_)
#define TJ 144

typedef unsigned short ushort;
typedef __attribute__((ext_vector_type(4))) float f32x4;
typedef __attribute__((ext_vector_type(8))) ushort ushort8;

// ---------- bf16 <-> f32 (raw ushort bits) ----------
__device__ __forceinline__ float b2f(ushort u){
  unsigned int x = ((unsigned int)u) << 16;
  return __builtin_bit_cast(float, x);
}
__device__ __forceinline__ ushort f2b(float f){
  unsigned int x = __builtin_bit_cast(unsigned int, f);
  unsigned int r = x + 0x7fff + ((x >> 16) & 1);   // RNE
  return (ushort)(r >> 16);
}

// ---------- reductions ----------
__device__ __forceinline__ float wredsum(float v){
#pragma unroll
  for (int o=32;o>0;o>>=1) v += __shfl_xor(v,o,64);
  return v;
}
__device__ __forceinline__ float wredmax(float v){
#pragma unroll
  for (int o=32;o>0;o>>=1) v = fmaxf(v,__shfl_xor(v,o,64));
  return v;
}
__device__ __forceinline__ float bredsum(float v, float* red){
  int lane = threadIdx.x & 63, wid = threadIdx.x >> 6;
  v = wredsum(v);
  __syncthreads();
  if (lane==0) red[wid]=v;
  __syncthreads();
  return red[0]+red[1]+red[2]+red[3];
}

// ---------- stats over L for x^T (B,N,L) ----------
__global__ __launch_bounds__(256) void stats_k(const float* __restrict__ x,
                                               float* __restrict__ mean,
                                               float* __restrict__ stdv,
                                               float* __restrict__ rstd){
  __shared__ float red[4];
  int bn = blockIdx.x;
  int b = bn / NF; int n = bn % NF;
  const float* xp = x + (size_t)b*LL_*NF + n;
  int t = threadIdx.x;
  float s = 0.f;
  for (int l=t;l<LL_;l+=256) s += xp[(size_t)l*NF];
  s = bredsum(s, red);
  float mu = s * (1.f/LL_);
  float s2 = 0.f;
  for (int l=t;l<LL_;l+=256){ float d = xp[(size_t)l*NF]-mu; s2 += d*d; }
  s2 = bredsum(s2, red);
  if (t==0){
    mean[bn]=mu;
    float sd = sqrtf(s2*(1.f/(LL_-1))) + EPSF;
    stdv[bn]=sd;
    rstd[bn]=1.f/sd;
  }
}

// ---------- normalized input -> bf16, K padded to 352 ----------
#define KPE 352
__global__ __launch_bounds__(256) void xnorm_k(const float* __restrict__ x,
                                               const float* __restrict__ mean,
                                               const float* __restrict__ rstd,
                                               ushort* __restrict__ xn){
  int idx = blockIdx.x*256 + threadIdx.x;
  if (idx >= BL*KPE) return;
  int c = idx % KPE; int bl = idx / KPE; int b = bl / LL_;
  float v = 0.f;
  if (c < NF) v = (x[(size_t)bl*NF + c] - mean[b*NF+c]) * rstd[b*NF+c];
  xn[idx] = f2b(v);
}

// ---------- weight transpose+convert mega-kernel ----------
struct TDesc { const float* in; ushort* out; int N, K, Npad, Kpad, nbx, blk0; };
struct TPack { TDesc d[17]; int n; };
__global__ __launch_bounds__(256) void transpose_k(TPack p){
  __shared__ float tile[32][33];
  int blk = blockIdx.x;
  int di = 0;
  while (di+1 < p.n && p.d[di+1].blk0 <= blk) ++di;
  TDesc D = p.d[di];
  int rel = blk - D.blk0;
  int bx = rel % D.nbx, by = rel / D.nbx;
  int k0 = bx*32, n0 = by*32;
  int t = threadIdx.x; int tx = t & 31, ty = t >> 5;
#pragma unroll
  for (int i=0;i<4;++i){
    int k = k0+ty+8*i, n = n0+tx;
    float v = (k < D.K && n < D.N) ? D.in[(size_t)k*D.N + n] : 0.f;
    tile[ty+8*i][tx] = v;
  }
  __syncthreads();
#pragma unroll
  for (int i=0;i<4;++i){
    int n = n0+ty+8*i, k = k0+tx;
    if (n < D.Npad && k < D.Kpad) D.out[(size_t)n*D.Kpad + k] = f2b(tile[tx][ty+8*i]);
  }
}

// ---------- fused bias packing (qkv + out/gate) ----------
__global__ __launch_bounds__(256) void pack_bias_k(const float* __restrict__ bq,
                                                   const float* __restrict__ bk,
                                                   const float* __restrict__ bv,
                                                   const float* __restrict__ bo2,
                                                   const float* __restrict__ bg,
                                                   float* __restrict__ bqkv,
                                                   float* __restrict__ bog){
  int t = blockIdx.x*256 + threadIdx.x;
  if (t < 2*1536){
    int l = t/1536, c = t%1536;
    float v = c<512 ? bq[l*512+c] : (c<1024 ? bk[l*512+c-512] : bv[l*512+c-1024]);
    bqkv[t] = v;
  }
  if (t < 2*672){
    int l = t/672, c = t%672;
    bog[t] = c<336 ? bo2[l*336+c] : bg[l*336+c-336];
  }
}

// ---------- bf16 MFMA GEMM: C[M,N] = A[M,K] @ Bt[N,K]^T + bias ----------
// flags: 1=relu, 2=bf16-only out (Cout is ushort*), 4=dual store (fp32 + bf16),
//        8=also pack cols [512,1536) as bf16 head-major K/V into kvp
__global__ __launch_bounds__(256) void gemm_k(
    const ushort* __restrict__ A, const ushort* __restrict__ Bt,
    const float* __restrict__ bias, void* __restrict__ Cout,
    ushort* __restrict__ Cbf, ushort* __restrict__ kvp,
    int N, int K, int flags)
{
  __shared__ ushort As[128*32];
  __shared__ ushort Bs[128*32];
  const int t = threadIdx.x;
  const int bm = blockIdx.y << 7, bn = blockIdx.x << 7;
  const int lane = t & 63, wid = t >> 6;
  const int wm = (wid >> 1) << 6, wn = (wid & 1) << 6;
  const int fr = lane & 15, kg = lane >> 4;

  f32x4 acc[4][4];
#pragma unroll
  for (int i=0;i<4;++i)
#pragma unroll
    for (int j=0;j<4;++j) acc[i][j] = (f32x4){0.f,0.f,0.f,0.f};

  const int rA0 = t >> 2,        qA0 = t & 3;
  const int rA1 = (t+256) >> 2;
  const size_t aOff0 = (size_t)(bm + rA0)*K + qA0*8;
  const size_t aOff1 = (size_t)(bm + rA1)*K + qA0*8;
  const size_t bOff0 = (size_t)(bn + rA0)*K + qA0*8;
  const size_t bOff1 = (size_t)(bn + rA1)*K + qA0*8;
  const int lA0 = (rA0<<5) + ((qA0 ^ ((rA0>>1)&3))<<3);
  const int lA1 = (rA1<<5) + ((qA0 ^ ((rA1>>1)&3))<<3);

  for (int k0=0; k0<K; k0+=32){
    ushort8 va0 = *(const ushort8*)(A  + aOff0 + k0);
    ushort8 va1 = *(const ushort8*)(A  + aOff1 + k0);
    ushort8 vb0 = *(const ushort8*)(Bt + bOff0 + k0);
    ushort8 vb1 = *(const ushort8*)(Bt + bOff1 + k0);
    *(ushort8*)&As[lA0] = va0;
    *(ushort8*)&As[lA1] = va1;
    *(ushort8*)&Bs[lA0] = vb0;
    *(ushort8*)&Bs[lA1] = vb1;
    __syncthreads();
    ushort8 af[4], bfr[4];
#pragma unroll
    for (int i=0;i<4;++i){
      int ra = wm + (i<<4) + fr;
      af[i]  = *(const ushort8*)&As[(ra<<5) + ((kg ^ ((ra>>1)&3))<<3)];
      int rb = wn + (i<<4) + fr;
      bfr[i] = *(const ushort8*)&Bs[(rb<<5) + ((kg ^ ((rb>>1)&3))<<3)];
    }
#pragma unroll
    for (int i=0;i<4;++i)
#pragma unroll
      for (int j=0;j<4;++j)
        asm("v_mfma_f32_16x16x32_bf16 %0, %1, %2, %0"
            : "+v"(acc[i][j]) : "v"(af[i]), "v"(bfr[j]));
    __syncthreads();
  }

  const int colBase = bn + wn + fr;
  const int rowBase = bm + wm + (kg << 2);
#pragma unroll
  for (int j=0;j<4;++j){
    int col = colBase + (j<<4);
    if (col >= N) continue;
    float bv = bias[col];
#pragma unroll
    for (int i=0;i<4;++i){
      int row0 = rowBase + (i<<4);
#pragma unroll
      for (int r=0;r<4;++r){
        float v = acc[i][j][r] + bv;
        if (flags & 1) v = fmaxf(v, 0.f);
        int row = row0 + r;
        size_t idx = (size_t)row*N + col;
        if (flags & 2) ((ushort*)Cout)[idx] = f2b(v);
        else {
          ((float*)Cout)[idx] = v;
          if (flags & 4) Cbf[idx] = f2b(v);
        }
        if ((flags & 8) && col >= 512){
          int part = col >> 9;            // 1=K, 2=V
          int hh = (col >> 6) & 7;
          int dd = col & 63;
          int bb = row / LL_; int jr = row - bb*LL_;
          ushort* dst = (part==1) ? kvp : kvp + (size_t)64*LL_*64;
          dst[(size_t)((bb*8+hh)*LL_ + jr)*64 + dd] = f2b(v);
        }
      }
    }
  }
}

// ---------- fused sampled-QK + M score: one wave per (b,h,l), lane=sample ----------
__global__ __launch_bounds__(256) void msc_k(const float* __restrict__ qkv,
                                             const int* __restrict__ samp,
                                             float* __restrict__ Mb){
  __shared__ float sq[4][64];
  int wid = threadIdx.x >> 6, lane = threadIdx.x & 63;
  int gid = blockIdx.x*4 + wid;                 // (b*H+h)*L + l
  int l = gid % LL_; int bh = gid / LL_; int h = bh & 7; int b = bh >> 3;
  const float* qrow = qkv + (size_t)(b*LL_ + l)*1536 + h*64;
  sq[wid][lane] = qrow[lane];
  __syncthreads();
  float acc = 0.f;
  if (lane < UK){
    int j = samp[l*UK + lane];
    const float4* k4 = (const float4*)(qkv + (size_t)(b*LL_ + j)*1536 + 512 + h*64);
    const float* sqw = sq[wid];
#pragma unroll
    for (int d4=0; d4<16; ++d4){
      float4 kk = k4[d4];
      acc = fmaf(sqw[d4*4+0], kk.x, acc);
      acc = fmaf(sqw[d4*4+1], kk.y, acc);
      acc = fmaf(sqw[d4*4+2], kk.z, acc);
      acc = fmaf(sqw[d4*4+3], kk.w, acc);
    }
  }
  float mx = (lane < UK) ? acc : -INFINITY;
  float sm = (lane < UK) ? acc : 0.f;
  mx = wredmax(mx);
  sm = wredsum(sm);
  if (lane == 0) Mb[gid] = mx - sm*(1.f/LL_);
}

// ---------- top-U per (b,h) ----------
__global__ __launch_bounds__(256) void topk_k(const float* __restrict__ Mb,
                                              int* __restrict__ mtop){
  __shared__ float sv[LL_];
  __shared__ float bv[4]; __shared__ int bi[4];
  int bh = blockIdx.x;
  const float* mp = Mb + (size_t)bh*LL_;
  int t = threadIdx.x;
  for (int j=t;j<LL_;j+=256) sv[j]=mp[j];
  __syncthreads();
  for (int it=0; it<UK; ++it){
    float best=-INFINITY; int bidx=LL_;
    for (int j=t;j<LL_;j+=256){
      float v=sv[j];
      if (v>best){best=v;bidx=j;}
    }
#pragma unroll
    for(int o=32;o>0;o>>=1){
      float ov=__shfl_xor(best,o,64); int oi=__shfl_xor(bidx,o,64);
      if (ov>best || (ov==best && oi<bidx)){best=ov;bidx=oi;}
    }
    int lane=t&63, wid=t>>6;
    if(lane==0){bv[wid]=best;bi[wid]=bidx;}
    __syncthreads();
    if(t==0){
      float bb=bv[0]; int ii=bi[0];
      for(int w=1;w<4;w++){ if(bv[w]>bb || (bv[w]==bb && bi[w]<ii)){bb=bv[w];ii=bi[w];} }
      mtop[(size_t)bh*UK+it]=ii;
      sv[ii]=-INFINITY;
    }
    __syncthreads();
  }
}

// ---------- v mean over L, per (b,h) block ----------
__global__ __launch_bounds__(256) void vmean_k(const float* __restrict__ qkv,
                                               float* __restrict__ vmn){
  __shared__ float part[4][64];
  int bh = blockIdx.x; int b = bh >> 3, h = bh & 7;
  int t = threadIdx.x; int d = t & 63, jg = t >> 6;
  const float* vb = qkv + (size_t)b*LL_*1536 + 1024 + h*64 + d;
  float s = 0.f;
  for (int j=jg; j<LL_; j+=4) s += vb[(size_t)j*1536];
  part[jg][d] = s;
  __syncthreads();
  if (t < 64) vmn[bh*64+t] = (part[0][t]+part[1][t]+part[2][t]+part[3][t])*(1.f/LL_);
}

// ---------- ctx = broadcast v_mean (bf16) ----------
__global__ __launch_bounds__(256) void ctxfill_k(const float* __restrict__ vmn,
                                                 ushort* __restrict__ ctx){
  int idx = blockIdx.x*256 + threadIdx.x;   // < BL*DM
  int c = idx & 511; int bl = idx >> 9; int b = bl / LL_;
  ctx[idx] = f2b(vmn[(b*8 + (c>>6))*64 + (c&63)]);
}

// ---------- flash-style attention: one block per (b,h), all 35 queries ----------
__global__ __launch_bounds__(512) void attn3_k(const float* __restrict__ qkv,
                                               const ushort* __restrict__ kpack,
                                               const ushort* __restrict__ vpack,
                                               const int* __restrict__ mtop,
                                               float* __restrict__ upd){
  __shared__ float sq[UK][64];
  __shared__ float sc[UK][TJ];
  __shared__ float m_s[40], l_s[40], r_s[40];
  int bh = blockIdx.x; int h = bh & 7; int b = bh >> 3;
  int t = threadIdx.x;
  int lane = t & 63, wid = t >> 6;
  for (int idx=t; idx<UK*64; idx+=512){
    int u = idx >> 6, d = idx & 63;
    int row = mtop[bh*UK + u];
    sq[u][d] = qkv[(size_t)(b*LL_ + row)*1536 + h*64 + d];
  }
  if (t < 40){ m_s[t] = -3.0e38f; l_s[t] = 0.f; r_s[t] = 0.f; }
  float acc0=0.f, acc1=0.f, acc2=0.f, acc3=0.f, acc4=0.f;
  const ushort* kb = kpack + (size_t)bh*LL_*64;
  const ushort* vb = vpack + (size_t)bh*LL_*64;
  for (int t0=0; t0<LL_; t0+=TJ){
    __syncthreads();                 // sc free (prev PV done), sq/m/l ready
    // scores: 35*TJ items
    for (int idx=t; idx<UK*TJ; idx+=512){
      int u = idx / TJ, jj = idx - u*TJ;
      const ushort8* kr = (const ushort8*)(kb + (size_t)(t0+jj)*64);
      const float* qu = sq[u];
      float dot = 0.f;
#pragma unroll
      for (int d8=0; d8<8; ++d8){
        ushort8 kk = kr[d8];
#pragma unroll
        for (int e=0;e<8;++e) dot = fmaf(qu[d8*8+e], b2f(kk[e]), dot);
      }
      sc[u][jj] = dot * 0.125f;
    }
    __syncthreads();
    // online softmax, wave w owns u = w, w+8, ...
    for (int u=wid; u<UK; u+=8){
      float v0 = sc[u][lane];
      float v1 = sc[u][lane+64];
      float v2 = (lane < TJ-128) ? sc[u][lane+128] : -3.0e38f;
      float tmax = wredmax(fmaxf(fmaxf(v0,v1),v2));
      float mold = m_s[u];
      float mnew = fmaxf(mold, tmax);
      float r = __expf(mold - mnew);
      float e0 = __expf(v0 - mnew);
      float e1 = __expf(v1 - mnew);
      float e2 = (lane < TJ-128) ? __expf(v2 - mnew) : 0.f;
      sc[u][lane] = e0; sc[u][lane+64] = e1;
      if (lane < TJ-128) sc[u][lane+128] = e2;
      float tsum = wredsum(e0+e1+e2);
      if (lane==0){ m_s[u] = mnew; l_s[u] = l_s[u]*r + tsum; r_s[u] = r; }
    }
    __syncthreads();
    // PV accumulate: thread owns (u = wid+8s, d = lane)
#pragma unroll
    for (int s=0; s<5; ++s){
      int u = wid + 8*s;
      if (u < UK){
        float r = r_s[u];
        const float* scu = sc[u];
        const ushort* vrow = vb + (size_t)t0*64 + lane;
        float sum = 0.f;
#pragma unroll 4
        for (int jj=0; jj<TJ; ++jj)
          sum = fmaf(scu[jj], b2f(vrow[(size_t)jj*64]), sum);
        float a = (s==0?acc0:s==1?acc1:s==2?acc2:s==3?acc3:acc4);
        a = a*r + sum;
        if(s==0)acc0=a; else if(s==1)acc1=a; else if(s==2)acc2=a;
        else if(s==3)acc3=a; else acc4=a;
      }
    }
  }
  __syncthreads();
#pragma unroll
  for (int s=0; s<5; ++s){
    int u = wid + 8*s;
    if (u < UK){
      float a = (s==0?acc0:s==1?acc1:s==2?acc2:s==3?acc3:acc4);
      upd[((size_t)bh*UK + u)*64 + lane] = a / l_s[u];
    }
  }
}

// ---------- scatter upd rows into ctx ----------
__global__ __launch_bounds__(256) void scatter2_k(const float* __restrict__ upd,
                                                  const int* __restrict__ mtop,
                                                  ushort* __restrict__ ctx){
  int idx = blockIdx.x*256 + threadIdx.x;   // < 64*UK*64
  if (idx >= 64*UK*64) return;
  int d = idx & 63; int r = idx >> 6; int u = r % UK; int bh = r / UK;
  int h = bh & 7, b = bh >> 3;
  int row = mtop[bh*UK + u];
  ctx[(size_t)(b*LL_ + row)*DM + h*64 + d] = f2b(upd[idx]);
}

// ---------- LN(a - s): fp32 residual chain, dual output ----------
__global__ __launch_bounds__(256) void subln_k(const float* __restrict__ a,
                                               const float* __restrict__ s,
                                               const float* __restrict__ g,
                                               const float* __restrict__ be,
                                               float* __restrict__ of32,
                                               ushort* __restrict__ obf){
  __shared__ float red[4];
  int row = blockIdx.x;
  size_t base = (size_t)row * DM;
  int t = threadIdx.x;
  float e0 = a[base+t]     - s[base+t];
  float e1 = a[base+t+256] - s[base+t+256];
  float sum = bredsum(e0+e1, red);
  float mu = sum * (1.f/DM);
  float d0 = e0-mu, d1 = e1-mu;
  __syncthreads();
  float var = bredsum(d0*d0+d1*d1, red);
  float rs = rsqrtf(var*(1.f/DM) + EPSF);
  float o0 = d0*rs*g[t]     + be[t];
  float o1 = d1*rs*g[t+256] + be[t+256];
  of32[base+t]     = o0;
  of32[base+t+256] = o1;
  obf[base+t]      = f2b(o0);
  obf[base+t+256]  = f2b(o1);
}

// ---------- y (+)= t1 * sigmoid(t2) from fused og[M][672] ----------
__global__ __launch_bounds__(256) void yupd_k(const float* __restrict__ og,
                                              float* __restrict__ y, int accum){
  int idx = blockIdx.x*256 + threadIdx.x;
  if (idx >= BL*PRED) return;
  int m = idx / PRED, p = idx - m*PRED;
  float t1 = og[(size_t)m*672 + p];
  float t2 = og[(size_t)m*672 + 336 + p];
  float val = t1 * (1.f/(1.f+__expf(-t2)));
  y[idx] = accum ? (y[idx] + val) : val;
}

// ---------- final: out[b,p,n] = y[b,n,p]*std + mean ----------
__global__ __launch_bounds__(256) void final_k(const float* __restrict__ y,
                                               const float* __restrict__ stdv,
                                               const float* __restrict__ mean,
                                               float* __restrict__ out){
  int idx = blockIdx.x*256 + threadIdx.x;
  if (idx >= BB_*PRED*NF) return;
  int n = idx % NF;
  int r = idx / NF;
  int p = r % PRED;
  int b = r / PRED;
  out[idx] = y[((size_t)b*LL_ + n)*PRED + p] * stdv[b*NF+n] + mean[b*NF+n];
}

// ---------------- host ----------------
extern "C" void kernel_launch(void* const* d_in, const int* in_sizes, int n_in,
                              void* d_out, int out_size, void* d_ws, size_t ws_size,
                              hipStream_t stream){
  const float* x_enc = (const float*)d_in[0];
  const int*   samp  = (const int*)  d_in[1];
  const float* embw  = (const float*)d_in[2];
  const float* embb  = (const float*)d_in[3];
  const float* wq    = (const float*)d_in[4];
  const float* bq    = (const float*)d_in[5];
  const float* wk    = (const float*)d_in[6];
  const float* bk    = (const float*)d_in[7];
  const float* wv    = (const float*)d_in[8];
  const float* bv    = (const float*)d_in[9];
  const float* wo    = (const float*)d_in[10];
  const float* bo    = (const float*)d_in[11];
  const float* ln1g  = (const float*)d_in[12];
  const float* ln1b  = (const float*)d_in[13];
  const float* w1    = (const float*)d_in[14];
  const float* b1    = (const float*)d_in[15];
  const float* w2    = (const float*)d_in[16];
  const float* b2    = (const float*)d_in[17];
  const float* ln2g  = (const float*)d_in[18];
  const float* ln2b  = (const float*)d_in[19];
  const float* wout  = (const float*)d_in[20];
  const float* boutp = (const float*)d_in[21];
  const float* wg    = (const float*)d_in[22];
  const float* bg    = (const float*)d_in[23];
  float* out = (float*)d_out;

  char* wsb = (char*)d_ws;
  size_t off = 0;
  auto alloc = [&](size_t bytes)->void*{
    void* p = wsb + off; off += (bytes + 255) & ~(size_t)255; return p;
  };
  float* mean  = (float*)alloc((size_t)BB_*NF*4);
  float* stdv  = (float*)alloc((size_t)BB_*NF*4);
  float* rstd  = (float*)alloc((size_t)BB_*NF*4);
  float* bqkv  = (float*)alloc(2*1536*4);
  float* bog   = (float*)alloc(2*672*4);
  ushort* xn     = (ushort*)alloc((size_t)BL*KPE*2);
  ushort* we_t   = (ushort*)alloc((size_t)512*KPE*2);
  ushort* wqkv_t = (ushort*)alloc((size_t)2*1536*512*2);
  ushort* wo_t   = (ushort*)alloc((size_t)2*512*512*2);
  ushort* w1_t   = (ushort*)alloc((size_t)2*128*512*2);
  ushort* w2_t   = (ushort*)alloc((size_t)2*512*128*2);
  ushort* wog_t  = (ushort*)alloc((size_t)2*768*512*2);
  ushort* h_bf   = (ushort*)alloc((size_t)BL*DM*2);
  ushort* hx_bf  = (ushort*)alloc((size_t)BL*DM*2);
  ushort* ctx_bf = (ushort*)alloc((size_t)BL*DM*2);
  ushort* ff1_bf = (ushort*)alloc((size_t)BL*DFF*2);
  ushort* kvpack = (ushort*)alloc((size_t)2*64*LL_*64*2);
  float* h_f32   = (float*)alloc((size_t)BL*DM*4);
  float* hx_f32  = (float*)alloc((size_t)BL*DM*4);
  float* qkv = (float*)alloc((size_t)BL*1536*4);   // reused as og [BL][672] later
  float* tmp = (float*)alloc((size_t)BL*DM*4);
  float* y   = (float*)alloc((size_t)BL*PRED*4);
  float* Mb  = (float*)alloc((size_t)BB_*HH_*LL_*4);
  int*  mtop = (int*)  alloc((size_t)BB_*HH_*UK*4);
  float* vmn = (float*)alloc((size_t)BB_*HH_*DH*4);
  float* upd = (float*)alloc((size_t)BB_*HH_*UK*DH*4);
  if (off > ws_size) return;
  ushort* kpack = kvpack;
  ushort* vpack = kvpack + (size_t)64*LL_*64;

  stats_k<<<BB_*NF, 256, 0, stream>>>(x_enc, mean, stdv, rstd);
  xnorm_k<<<(BL*KPE+255)/256, 256, 0, stream>>>(x_enc, mean, rstd, xn);

  TPack tp; int blk = 0; int di = 0;
  auto addT = [&](const float* in, ushort* o, int N, int K, int Npad, int Kpad){
    TDesc& d = tp.d[di++]; d.in=in; d.out=o; d.N=N; d.K=K; d.Npad=Npad; d.Kpad=Kpad;
    d.nbx = (Kpad+31)/32; d.blk0 = blk; blk += d.nbx * ((Npad+31)/32);
  };
  addT(embw, we_t, 512, NF, 512, KPE);
  for (int l=0;l<NLAY;++l){
    addT(wq + (size_t)l*262144, wqkv_t + (size_t)l*786432,            512,512,512,512);
    addT(wk + (size_t)l*262144, wqkv_t + (size_t)l*786432 + 262144,   512,512,512,512);
    addT(wv + (size_t)l*262144, wqkv_t + (size_t)l*786432 + 524288,   512,512,512,512);
    addT(wo + (size_t)l*262144, wo_t   + (size_t)l*262144,            512,512,512,512);
    addT(w1 + (size_t)l*65536,  w1_t   + (size_t)l*65536,             128,512,128,512);
    addT(w2 + (size_t)l*65536,  w2_t   + (size_t)l*65536,             512,128,512,128);
    addT(wout + (size_t)l*172032, wog_t + (size_t)l*393216,           336,512,336,512);
    addT(wg   + (size_t)l*172032, wog_t + (size_t)l*393216 + 172032,  336,512,432,512);
  }
  tp.n = di;
  transpose_k<<<blk, 256, 0, stream>>>(tp);
  pack_bias_k<<<12, 256, 0, stream>>>(bq, bk, bv, boutp, bg, bqkv, bog);

  // embed: h = xn @ embw + embb  (dual fp32 + bf16)
  gemm_k<<<dim3(4,45), 256, 0, stream>>>(xn, we_t, embb, h_f32, h_bf, nullptr,
                                         512, KPE, 4);

  for (int l=0;l<NLAY;++l){
    gemm_k<<<dim3(12,45), 256, 0, stream>>>(h_bf, wqkv_t + (size_t)l*786432,
                                            bqkv + l*1536, qkv, nullptr, kvpack,
                                            1536, 512, 8);
    msc_k<<<BB_*HH_*LL_/4, 256, 0, stream>>>(qkv, samp, Mb);
    topk_k<<<BB_*HH_, 256, 0, stream>>>(Mb, mtop);
    vmean_k<<<BB_*HH_, 256, 0, stream>>>(qkv, vmn);
    ctxfill_k<<<BL*DM/256, 256, 0, stream>>>(vmn, ctx_bf);
    attn3_k<<<BB_*HH_, 512, 0, stream>>>(qkv, kpack, vpack, mtop, upd);
    scatter2_k<<<(64*UK*64+255)/256, 256, 0, stream>>>(upd, mtop, ctx_bf);
    gemm_k<<<dim3(4,45), 256, 0, stream>>>(ctx_bf, wo_t + (size_t)l*262144,
                                           bo + l*512, tmp, nullptr, nullptr,
                                           512, 512, 0);
    subln_k<<<BL, 256, 0, stream>>>(h_f32, tmp, ln1g + l*512, ln1b + l*512,
                                    hx_f32, hx_bf);
    gemm_k<<<dim3(1,45), 256, 0, stream>>>(hx_bf, w1_t + (size_t)l*65536,
                                           b1 + l*128, ff1_bf, nullptr, nullptr,
                                           128, 512, 3);
    gemm_k<<<dim3(4,45), 256, 0, stream>>>(ff1_bf, w2_t + (size_t)l*65536,
                                           b2 + l*512, tmp, nullptr, nullptr,
                                           512, 128, 0);
    subln_k<<<BL, 256, 0, stream>>>(hx_f32, tmp, ln2g + l*512, ln2b + l*512,
                                    h_f32, h_bf);
    gemm_k<<<dim3(6,45), 256, 0, stream>>>(h_bf, wog_t + (size_t)l*393216,
                                           bog + l*672, qkv, nullptr, nullptr,
                                           672, 512, 0);
    yupd_k<<<(BL*PRED+255)/256, 256, 0, stream>>>(qkv, y, l==0?0:1);
  }
  final_k<<<(BB_*PRED*NF+255)/256, 256, 0, stream>>>(y, stdv, mean, out);
}

// Round 5
// 778.689 us; speedup vs baseline: 2.3618x; 1.4117x over previous
//
#include <hip/hip_runtime.h>
#include <math.h>

#define BB_ 8
#define LL_ 720
#define NF 321
#define DM 512
#define HH_ 8
#define DH 64
#define DFF 128
#define PRED 336
#define UK 35
#define NLAY 2
#define EPSF 1e-5f
#define BL (BB_*LL_)
#define TJC 72
#define NCH (LL_/TJC)

typedef unsigned short ushort;
typedef __attribute__((ext_vector_type(4))) float f32x4;
typedef __attribute__((ext_vector_type(8))) ushort ushort8;

// ---------- bf16 <-> f32 (raw ushort bits) ----------
__device__ __forceinline__ float b2f(ushort u){
  unsigned int x = ((unsigned int)u) << 16;
  return __builtin_bit_cast(float, x);
}
__device__ __forceinline__ ushort f2b(float f){
  unsigned int x = __builtin_bit_cast(unsigned int, f);
  unsigned int r = x + 0x7fff + ((x >> 16) & 1);   // RNE
  return (ushort)(r >> 16);
}

// ---------- reductions ----------
__device__ __forceinline__ float wredsum(float v){
#pragma unroll
  for (int o=32;o>0;o>>=1) v += __shfl_xor(v,o,64);
  return v;
}
__device__ __forceinline__ float wredmax(float v){
#pragma unroll
  for (int o=32;o>0;o>>=1) v = fmaxf(v,__shfl_xor(v,o,64));
  return v;
}
__device__ __forceinline__ float bredsum(float v, float* red){
  int lane = threadIdx.x & 63, wid = threadIdx.x >> 6;
  v = wredsum(v);
  __syncthreads();
  if (lane==0) red[wid]=v;
  __syncthreads();
  return red[0]+red[1]+red[2]+red[3];
}

// ---------- stats over L for x^T (B,N,L) ----------
__global__ __launch_bounds__(256) void stats_k(const float* __restrict__ x,
                                               float* __restrict__ mean,
                                               float* __restrict__ stdv,
                                               float* __restrict__ rstd){
  __shared__ float red[4];
  int bn = blockIdx.x;
  int b = bn / NF; int n = bn % NF;
  const float* xp = x + (size_t)b*LL_*NF + n;
  int t = threadIdx.x;
  float s = 0.f;
  for (int l=t;l<LL_;l+=256) s += xp[(size_t)l*NF];
  s = bredsum(s, red);
  float mu = s * (1.f/LL_);
  float s2 = 0.f;
  for (int l=t;l<LL_;l+=256){ float d = xp[(size_t)l*NF]-mu; s2 += d*d; }
  s2 = bredsum(s2, red);
  if (t==0){
    mean[bn]=mu;
    float sd = sqrtf(s2*(1.f/(LL_-1))) + EPSF;
    stdv[bn]=sd;
    rstd[bn]=1.f/sd;
  }
}

// ---------- normalized input -> bf16, K padded to 352 ----------
#define KPE 352
__global__ __launch_bounds__(256) void xnorm_k(const float* __restrict__ x,
                                               const float* __restrict__ mean,
                                               const float* __restrict__ rstd,
                                               ushort* __restrict__ xn){
  int idx = blockIdx.x*256 + threadIdx.x;
  if (idx >= BL*KPE) return;
  int c = idx % KPE; int bl = idx / KPE; int b = bl / LL_;
  float v = 0.f;
  if (c < NF) v = (x[(size_t)bl*NF + c] - mean[b*NF+c]) * rstd[b*NF+c];
  xn[idx] = f2b(v);
}

// ---------- weight transpose+convert mega-kernel ----------
struct TDesc { const float* in; ushort* out; int N, K, Npad, Kpad, nbx, blk0; };
struct TPack { TDesc d[17]; int n; };
__global__ __launch_bounds__(256) void transpose_k(TPack p){
  __shared__ float tile[32][33];
  int blk = blockIdx.x;
  int di = 0;
  while (di+1 < p.n && p.d[di+1].blk0 <= blk) ++di;
  TDesc D = p.d[di];
  int rel = blk - D.blk0;
  int bx = rel % D.nbx, by = rel / D.nbx;
  int k0 = bx*32, n0 = by*32;
  int t = threadIdx.x; int tx = t & 31, ty = t >> 5;
#pragma unroll
  for (int i=0;i<4;++i){
    int k = k0+ty+8*i, n = n0+tx;
    float v = (k < D.K && n < D.N) ? D.in[(size_t)k*D.N + n] : 0.f;
    tile[ty+8*i][tx] = v;
  }
  __syncthreads();
#pragma unroll
  for (int i=0;i<4;++i){
    int n = n0+ty+8*i, k = k0+tx;
    if (n < D.Npad && k < D.Kpad) D.out[(size_t)n*D.Kpad + k] = f2b(tile[tx][ty+8*i]);
  }
}

// ---------- fused bias packing (qkv + out/gate) ----------
__global__ __launch_bounds__(256) void pack_bias_k(const float* __restrict__ bq,
                                                   const float* __restrict__ bk,
                                                   const float* __restrict__ bv,
                                                   const float* __restrict__ bo2,
                                                   const float* __restrict__ bg,
                                                   float* __restrict__ bqkv,
                                                   float* __restrict__ bog){
  int t = blockIdx.x*256 + threadIdx.x;
  if (t < 2*1536){
    int l = t/1536, c = t%1536;
    float v = c<512 ? bq[l*512+c] : (c<1024 ? bk[l*512+c-512] : bv[l*512+c-1024]);
    bqkv[t] = v;
  }
  if (t < 2*672){
    int l = t/672, c = t%672;
    bog[t] = c<336 ? bo2[l*336+c] : bg[l*336+c-336];
  }
}

// ---------- bf16 MFMA GEMM: C[M,N] = A[M,K] @ Bt[N,K]^T + bias ----------
// flags: 1=relu, 2=bf16-only out (Cout is ushort*), 4=dual store (fp32 + bf16),
//        8=pack cols [512,1024) as K^T [bh][d][L] and [1024,1536) as V [bh][L][d] (bf16)
__global__ __launch_bounds__(256) void gemm_k(
    const ushort* __restrict__ A, const ushort* __restrict__ Bt,
    const float* __restrict__ bias, void* __restrict__ Cout,
    ushort* __restrict__ Cbf, ushort* __restrict__ kvp,
    int N, int K, int flags)
{
  __shared__ ushort As[128*32];
  __shared__ ushort Bs[128*32];
  const int t = threadIdx.x;
  const int bm = blockIdx.y << 7, bn = blockIdx.x << 7;
  const int lane = t & 63, wid = t >> 6;
  const int wm = (wid >> 1) << 6, wn = (wid & 1) << 6;
  const int fr = lane & 15, kg = lane >> 4;

  f32x4 acc[4][4];
#pragma unroll
  for (int i=0;i<4;++i)
#pragma unroll
    for (int j=0;j<4;++j) acc[i][j] = (f32x4){0.f,0.f,0.f,0.f};

  const int rA0 = t >> 2,        qA0 = t & 3;
  const int rA1 = (t+256) >> 2;
  const size_t aOff0 = (size_t)(bm + rA0)*K + qA0*8;
  const size_t aOff1 = (size_t)(bm + rA1)*K + qA0*8;
  const size_t bOff0 = (size_t)(bn + rA0)*K + qA0*8;
  const size_t bOff1 = (size_t)(bn + rA1)*K + qA0*8;
  const int lA0 = (rA0<<5) + ((qA0 ^ ((rA0>>1)&3))<<3);
  const int lA1 = (rA1<<5) + ((qA0 ^ ((rA1>>1)&3))<<3);

  for (int k0=0; k0<K; k0+=32){
    ushort8 va0 = *(const ushort8*)(A  + aOff0 + k0);
    ushort8 va1 = *(const ushort8*)(A  + aOff1 + k0);
    ushort8 vb0 = *(const ushort8*)(Bt + bOff0 + k0);
    ushort8 vb1 = *(const ushort8*)(Bt + bOff1 + k0);
    *(ushort8*)&As[lA0] = va0;
    *(ushort8*)&As[lA1] = va1;
    *(ushort8*)&Bs[lA0] = vb0;
    *(ushort8*)&Bs[lA1] = vb1;
    __syncthreads();
    ushort8 af[4], bfr[4];
#pragma unroll
    for (int i=0;i<4;++i){
      int ra = wm + (i<<4) + fr;
      af[i]  = *(const ushort8*)&As[(ra<<5) + ((kg ^ ((ra>>1)&3))<<3)];
      int rb = wn + (i<<4) + fr;
      bfr[i] = *(const ushort8*)&Bs[(rb<<5) + ((kg ^ ((rb>>1)&3))<<3)];
    }
#pragma unroll
    for (int i=0;i<4;++i)
#pragma unroll
      for (int j=0;j<4;++j)
        asm("v_mfma_f32_16x16x32_bf16 %0, %1, %2, %0"
            : "+v"(acc[i][j]) : "v"(af[i]), "v"(bfr[j]));
    __syncthreads();
  }

  const int colBase = bn + wn + fr;
  const int rowBase = bm + wm + (kg << 2);
#pragma unroll
  for (int j=0;j<4;++j){
    int col = colBase + (j<<4);
    if (col >= N) continue;
    float bv = bias[col];
#pragma unroll
    for (int i=0;i<4;++i){
      int row0 = rowBase + (i<<4);
#pragma unroll
      for (int r=0;r<4;++r){
        float v = acc[i][j][r] + bv;
        if (flags & 1) v = fmaxf(v, 0.f);
        int row = row0 + r;
        size_t idx = (size_t)row*N + col;
        if (flags & 2) ((ushort*)Cout)[idx] = f2b(v);
        else {
          ((float*)Cout)[idx] = v;
          if (flags & 4) Cbf[idx] = f2b(v);
        }
        if ((flags & 8) && col >= 512){
          int hh = (col >> 6) & 7;
          int dd = col & 63;
          int bb = row / LL_; int jr = row - bb*LL_;
          if (col < 1024)   // K transposed: [bh][d][L]
            kvp[((size_t)(bb*8+hh)*64 + dd)*LL_ + jr] = f2b(v);
          else              // V: [bh][L][d]
            kvp[(size_t)64*64*LL_ + ((size_t)(bb*8+hh)*LL_ + jr)*64 + dd] = f2b(v);
        }
      }
    }
  }
}

// ---------- fused sampled-QK + M score: one wave per (b,h,l), lane=sample ----------
__global__ __launch_bounds__(256) void msc_k(const float* __restrict__ qkv,
                                             const int* __restrict__ samp,
                                             float* __restrict__ Mb){
  __shared__ float sq[4][64];
  int wid = threadIdx.x >> 6, lane = threadIdx.x & 63;
  int gid = blockIdx.x*4 + wid;                 // (b*H+h)*L + l
  int l = gid % LL_; int bh = gid / LL_; int h = bh & 7; int b = bh >> 3;
  const float* qrow = qkv + (size_t)(b*LL_ + l)*1536 + h*64;
  sq[wid][lane] = qrow[lane];
  __syncthreads();
  float acc = 0.f;
  if (lane < UK){
    int j = samp[l*UK + lane];
    const float4* k4 = (const float4*)(qkv + (size_t)(b*LL_ + j)*1536 + 512 + h*64);
    const float* sqw = sq[wid];
#pragma unroll
    for (int d4=0; d4<16; ++d4){
      float4 kk = k4[d4];
      acc = fmaf(sqw[d4*4+0], kk.x, acc);
      acc = fmaf(sqw[d4*4+1], kk.y, acc);
      acc = fmaf(sqw[d4*4+2], kk.z, acc);
      acc = fmaf(sqw[d4*4+3], kk.w, acc);
    }
  }
  float mx = (lane < UK) ? acc : -INFINITY;
  float sm = (lane < UK) ? acc : 0.f;
  mx = wredmax(mx);
  sm = wredsum(sm);
  if (lane == 0) Mb[gid] = mx - sm*(1.f/LL_);
}

// ---------- top-U per (b,h) ----------
__global__ __launch_bounds__(256) void topk_k(const float* __restrict__ Mb,
                                              int* __restrict__ mtop){
  __shared__ float sv[LL_];
  __shared__ float bv[4]; __shared__ int bi[4];
  int bh = blockIdx.x;
  const float* mp = Mb + (size_t)bh*LL_;
  int t = threadIdx.x;
  for (int j=t;j<LL_;j+=256) sv[j]=mp[j];
  __syncthreads();
  for (int it=0; it<UK; ++it){
    float best=-INFINITY; int bidx=LL_;
    for (int j=t;j<LL_;j+=256){
      float v=sv[j];
      if (v>best){best=v;bidx=j;}
    }
#pragma unroll
    for(int o=32;o>0;o>>=1){
      float ov=__shfl_xor(best,o,64); int oi=__shfl_xor(bidx,o,64);
      if (ov>best || (ov==best && oi<bidx)){best=ov;bidx=oi;}
    }
    int lane=t&63, wid=t>>6;
    if(lane==0){bv[wid]=best;bi[wid]=bidx;}
    __syncthreads();
    if(t==0){
      float bb=bv[0]; int ii=bi[0];
      for(int w=1;w<4;w++){ if(bv[w]>bb || (bv[w]==bb && bi[w]<ii)){bb=bv[w];ii=bi[w];} }
      mtop[(size_t)bh*UK+it]=ii;
      sv[ii]=-INFINITY;
    }
    __syncthreads();
  }
}

// ---------- v mean over L, per (b,h) block ----------
__global__ __launch_bounds__(256) void vmean_k(const float* __restrict__ qkv,
                                               float* __restrict__ vmn){
  __shared__ float part[4][64];
  int bh = blockIdx.x; int b = bh >> 3, h = bh & 7;
  int t = threadIdx.x; int d = t & 63, jg = t >> 6;
  const float* vb = qkv + (size_t)b*LL_*1536 + 1024 + h*64 + d;
  float s = 0.f;
  for (int j=jg; j<LL_; j+=4) s += vb[(size_t)j*1536];
  part[jg][d] = s;
  __syncthreads();
  if (t < 64) vmn[bh*64+t] = (part[0][t]+part[1][t]+part[2][t]+part[3][t])*(1.f/LL_);
}

// ---------- ctx = broadcast v_mean (bf16) ----------
__global__ __launch_bounds__(256) void ctxfill_k(const float* __restrict__ vmn,
                                                 ushort* __restrict__ ctx){
  int idx = blockIdx.x*256 + threadIdx.x;   // < BL*DM
  int c = idx & 511; int bl = idx >> 9; int b = bl / LL_;
  ctx[idx] = f2b(vmn[(b*8 + (c>>6))*64 + (c&63)]);
}

// ---------- chunked attention partials: one block per (b,h,chunk) ----------
__global__ __launch_bounds__(256) void attn4_k(const float* __restrict__ qkv,
                                               const ushort* __restrict__ kT,
                                               const ushort* __restrict__ vp,
                                               const int* __restrict__ mtop,
                                               float* __restrict__ pacc,
                                               float* __restrict__ pm,
                                               float* __restrict__ pl){
  __shared__ ushort skT[64][TJC];    // K^T chunk
  __shared__ ushort sv[TJC][64];     // V chunk
  __shared__ float  sq[UK][64];
  __shared__ float  sc[UK][TJC];
  int blk = blockIdx.x;
  int ch = blk % NCH; int bh = blk / NCH;
  int b = bh >> 3, h = bh & 7; int t0 = ch*TJC;
  int t = threadIdx.x, lane = t & 63, wid = t >> 6;
  for (int idx=t; idx<64*(TJC/8); idx+=256){
    int d = idx/(TJC/8), c8 = idx%(TJC/8);
    *(ushort8*)&skT[d][c8*8] =
      *(const ushort8*)(kT + ((size_t)bh*64 + d)*LL_ + t0 + c8*8);
  }
  for (int idx=t; idx<TJC*8; idx+=256){
    int jj = idx>>3, c8 = idx&7;
    *(ushort8*)&sv[jj][c8*8] =
      *(const ushort8*)(vp + ((size_t)bh*LL_ + t0+jj)*64 + c8*8);
  }
  for (int idx=t; idx<UK*64; idx+=256){
    int u = idx>>6, d = idx&63;
    int row = mtop[bh*UK + u];
    sq[u][d] = qkv[(size_t)(b*LL_ + row)*1536 + h*64 + d];
  }
  __syncthreads();
  // scores: items (u, jb) = 35 x 9, each computes 8 consecutive j
  for (int idx=t; idx<UK*(TJC/8); idx+=256){
    int u = idx/(TJC/8), jb = idx%(TJC/8);
    float dot[8] = {0.f,0.f,0.f,0.f,0.f,0.f,0.f,0.f};
    const float* qu = sq[u];
#pragma unroll
    for (int d=0; d<64; ++d){
      ushort8 kk = *(const ushort8*)&skT[d][jb*8];
      float qv = qu[d];
#pragma unroll
      for (int e=0;e<8;++e) dot[e] = fmaf(qv, b2f(kk[e]), dot[e]);
    }
#pragma unroll
    for (int e=0;e<8;++e) sc[u][jb*8+e] = dot[e]*0.125f;
  }
  __syncthreads();
  // chunk-local softmax: wave w owns u = w, w+4, ...
  for (int u=wid; u<UK; u+=4){
    float v0 = sc[u][lane];
    float v1 = (lane < TJC-64) ? sc[u][64+lane] : -3.0e38f;
    float mx = wredmax(fmaxf(v0,v1));
    float e0 = __expf(v0-mx);
    float e1 = (lane < TJC-64) ? __expf(v1-mx) : 0.f;
    sc[u][lane] = e0;
    if (lane < TJC-64) sc[u][64+lane] = e1;
    float s = wredsum(e0+e1);
    if (lane==0){
      pm[((size_t)bh*NCH+ch)*UK + u] = mx;
      pl[((size_t)bh*NCH+ch)*UK + u] = s;
    }
  }
  __syncthreads();
  // partial PV: (u,d) outputs
  for (int idx=t; idx<UK*64; idx+=256){
    int u = idx>>6, d = idx&63;
    const float* scu = sc[u];
    float a = 0.f;
#pragma unroll 8
    for (int jj=0; jj<TJC; ++jj) a = fmaf(scu[jj], b2f(sv[jj][d]), a);
    pacc[(((size_t)bh*NCH+ch)*UK + u)*64 + d] = a;
  }
}

// ---------- combine partials + scatter into ctx ----------
__global__ __launch_bounds__(256) void attn5_k(const float* __restrict__ pacc,
                                               const float* __restrict__ pm,
                                               const float* __restrict__ pl,
                                               const int* __restrict__ mtop,
                                               ushort* __restrict__ ctx){
  int bh = blockIdx.x; int b = bh >> 3, h = bh & 7;
  int t = threadIdx.x;
  for (int idx=t; idx<UK*64; idx+=256){
    int u = idx>>6, d = idx&63;
    float M = -3.0e38f;
#pragma unroll
    for (int ch=0; ch<NCH; ++ch)
      M = fmaxf(M, pm[((size_t)bh*NCH+ch)*UK + u]);
    float L = 0.f, A = 0.f;
#pragma unroll
    for (int ch=0; ch<NCH; ++ch){
      float w = __expf(pm[((size_t)bh*NCH+ch)*UK + u] - M);
      L += w * pl[((size_t)bh*NCH+ch)*UK + u];
      A += w * pacc[(((size_t)bh*NCH+ch)*UK + u)*64 + d];
    }
    int row = mtop[bh*UK + u];
    ctx[(size_t)(b*LL_ + row)*DM + h*64 + d] = f2b(A / L);
  }
}

// ---------- LN(a - s): fp32 residual chain, dual output ----------
__global__ __launch_bounds__(256) void subln_k(const float* __restrict__ a,
                                               const float* __restrict__ s,
                                               const float* __restrict__ g,
                                               const float* __restrict__ be,
                                               float* __restrict__ of32,
                                               ushort* __restrict__ obf){
  __shared__ float red[4];
  int row = blockIdx.x;
  size_t base = (size_t)row * DM;
  int t = threadIdx.x;
  float e0 = a[base+t]     - s[base+t];
  float e1 = a[base+t+256] - s[base+t+256];
  float sum = bredsum(e0+e1, red);
  float mu = sum * (1.f/DM);
  float d0 = e0-mu, d1 = e1-mu;
  __syncthreads();
  float var = bredsum(d0*d0+d1*d1, red);
  float rs = rsqrtf(var*(1.f/DM) + EPSF);
  float o0 = d0*rs*g[t]     + be[t];
  float o1 = d1*rs*g[t+256] + be[t+256];
  of32[base+t]     = o0;
  of32[base+t+256] = o1;
  obf[base+t]      = f2b(o0);
  obf[base+t+256]  = f2b(o1);
}

// ---------- y (+)= t1 * sigmoid(t2) from fused og[M][672] ----------
__global__ __launch_bounds__(256) void yupd_k(const float* __restrict__ og,
                                              float* __restrict__ y, int accum){
  int idx = blockIdx.x*256 + threadIdx.x;
  if (idx >= BL*PRED) return;
  int m = idx / PRED, p = idx - m*PRED;
  float t1 = og[(size_t)m*672 + p];
  float t2 = og[(size_t)m*672 + 336 + p];
  float val = t1 * (1.f/(1.f+__expf(-t2)));
  y[idx] = accum ? (y[idx] + val) : val;
}

// ---------- final: out[b,p,n] = y[b,n,p]*std + mean ----------
__global__ __launch_bounds__(256) void final_k(const float* __restrict__ y,
                                               const float* __restrict__ stdv,
                                               const float* __restrict__ mean,
                                               float* __restrict__ out){
  int idx = blockIdx.x*256 + threadIdx.x;
  if (idx >= BB_*PRED*NF) return;
  int n = idx % NF;
  int r = idx / NF;
  int p = r % PRED;
  int b = r / PRED;
  out[idx] = y[((size_t)b*LL_ + n)*PRED + p] * stdv[b*NF+n] + mean[b*NF+n];
}

// ---------------- host ----------------
extern "C" void kernel_launch(void* const* d_in, const int* in_sizes, int n_in,
                              void* d_out, int out_size, void* d_ws, size_t ws_size,
                              hipStream_t stream){
  const float* x_enc = (const float*)d_in[0];
  const int*   samp  = (const int*)  d_in[1];
  const float* embw  = (const float*)d_in[2];
  const float* embb  = (const float*)d_in[3];
  const float* wq    = (const float*)d_in[4];
  const float* bq    = (const float*)d_in[5];
  const float* wk    = (const float*)d_in[6];
  const float* bk    = (const float*)d_in[7];
  const float* wv    = (const float*)d_in[8];
  const float* bv    = (const float*)d_in[9];
  const float* wo    = (const float*)d_in[10];
  const float* bo    = (const float*)d_in[11];
  const float* ln1g  = (const float*)d_in[12];
  const float* ln1b  = (const float*)d_in[13];
  const float* w1    = (const float*)d_in[14];
  const float* b1    = (const float*)d_in[15];
  const float* w2    = (const float*)d_in[16];
  const float* b2    = (const float*)d_in[17];
  const float* ln2g  = (const float*)d_in[18];
  const float* ln2b  = (const float*)d_in[19];
  const float* wout  = (const float*)d_in[20];
  const float* boutp = (const float*)d_in[21];
  const float* wg    = (const float*)d_in[22];
  const float* bg    = (const float*)d_in[23];
  float* out = (float*)d_out;

  char* wsb = (char*)d_ws;
  size_t off = 0;
  auto alloc = [&](size_t bytes)->void*{
    void* p = wsb + off; off += (bytes + 255) & ~(size_t)255; return p;
  };
  float* mean  = (float*)alloc((size_t)BB_*NF*4);
  float* stdv  = (float*)alloc((size_t)BB_*NF*4);
  float* rstd  = (float*)alloc((size_t)BB_*NF*4);
  float* bqkv  = (float*)alloc(2*1536*4);
  float* bog   = (float*)alloc(2*672*4);
  ushort* xn     = (ushort*)alloc((size_t)BL*KPE*2);
  ushort* we_t   = (ushort*)alloc((size_t)512*KPE*2);
  ushort* wqkv_t = (ushort*)alloc((size_t)2*1536*512*2);
  ushort* wo_t   = (ushort*)alloc((size_t)2*512*512*2);
  ushort* w1_t   = (ushort*)alloc((size_t)2*128*512*2);
  ushort* w2_t   = (ushort*)alloc((size_t)2*512*128*2);
  ushort* wog_t  = (ushort*)alloc((size_t)2*768*512*2);
  ushort* h_bf   = (ushort*)alloc((size_t)BL*DM*2);
  ushort* hx_bf  = (ushort*)alloc((size_t)BL*DM*2);
  ushort* ctx_bf = (ushort*)alloc((size_t)BL*DM*2);
  ushort* ff1_bf = (ushort*)alloc((size_t)BL*DFF*2);
  ushort* kvpack = (ushort*)alloc((size_t)2*64*LL_*64*2);
  float* h_f32   = (float*)alloc((size_t)BL*DM*4);
  float* hx_f32  = (float*)alloc((size_t)BL*DM*4);
  float* qkv = (float*)alloc((size_t)BL*1536*4);   // reused as og [BL][672] later
  float* tmp = (float*)alloc((size_t)BL*DM*4);
  float* y   = (float*)alloc((size_t)BL*PRED*4);
  float* Mb  = (float*)alloc((size_t)BB_*HH_*LL_*4);
  int*  mtop = (int*)  alloc((size_t)BB_*HH_*UK*4);
  float* vmn = (float*)alloc((size_t)BB_*HH_*DH*4);
  float* pacc = (float*)alloc((size_t)64*NCH*UK*64*4);
  float* pm   = (float*)alloc((size_t)64*NCH*UK*4);
  float* pl   = (float*)alloc((size_t)64*NCH*UK*4);
  if (off > ws_size) return;
  ushort* kTp   = kvpack;
  ushort* vpack = kvpack + (size_t)64*64*LL_;

  stats_k<<<BB_*NF, 256, 0, stream>>>(x_enc, mean, stdv, rstd);
  xnorm_k<<<(BL*KPE+255)/256, 256, 0, stream>>>(x_enc, mean, rstd, xn);

  TPack tp; int blk = 0; int di = 0;
  auto addT = [&](const float* in, ushort* o, int N, int K, int Npad, int Kpad){
    TDesc& d = tp.d[di++]; d.in=in; d.out=o; d.N=N; d.K=K; d.Npad=Npad; d.Kpad=Kpad;
    d.nbx = (Kpad+31)/32; d.blk0 = blk; blk += d.nbx * ((Npad+31)/32);
  };
  addT(embw, we_t, 512, NF, 512, KPE);
  for (int l=0;l<NLAY;++l){
    addT(wq + (size_t)l*262144, wqkv_t + (size_t)l*786432,            512,512,512,512);
    addT(wk + (size_t)l*262144, wqkv_t + (size_t)l*786432 + 262144,   512,512,512,512);
    addT(wv + (size_t)l*262144, wqkv_t + (size_t)l*786432 + 524288,   512,512,512,512);
    addT(wo + (size_t)l*262144, wo_t   + (size_t)l*262144,            512,512,512,512);
    addT(w1 + (size_t)l*65536,  w1_t   + (size_t)l*65536,             128,512,128,512);
    addT(w2 + (size_t)l*65536,  w2_t   + (size_t)l*65536,             512,128,512,128);
    addT(wout + (size_t)l*172032, wog_t + (size_t)l*393216,           336,512,336,512);
    addT(wg   + (size_t)l*172032, wog_t + (size_t)l*393216 + 172032,  336,512,432,512);
  }
  tp.n = di;
  transpose_k<<<blk, 256, 0, stream>>>(tp);
  pack_bias_k<<<12, 256, 0, stream>>>(bq, bk, bv, boutp, bg, bqkv, bog);

  // embed: h = xn @ embw + embb  (dual fp32 + bf16)
  gemm_k<<<dim3(4,45), 256, 0, stream>>>(xn, we_t, embb, h_f32, h_bf, nullptr,
                                         512, KPE, 4);

  for (int l=0;l<NLAY;++l){
    gemm_k<<<dim3(12,45), 256, 0, stream>>>(h_bf, wqkv_t + (size_t)l*786432,
                                            bqkv + l*1536, qkv, nullptr, kvpack,
                                            1536, 512, 8);
    msc_k<<<BB_*HH_*LL_/4, 256, 0, stream>>>(qkv, samp, Mb);
    topk_k<<<BB_*HH_, 256, 0, stream>>>(Mb, mtop);
    vmean_k<<<BB_*HH_, 256, 0, stream>>>(qkv, vmn);
    ctxfill_k<<<BL*DM/256, 256, 0, stream>>>(vmn, ctx_bf);
    attn4_k<<<64*NCH, 256, 0, stream>>>(qkv, kTp, vpack, mtop, pacc, pm, pl);
    attn5_k<<<64, 256, 0, stream>>>(pacc, pm, pl, mtop, ctx_bf);
    gemm_k<<<dim3(4,45), 256, 0, stream>>>(ctx_bf, wo_t + (size_t)l*262144,
                                           bo + l*512, tmp, nullptr, nullptr,
                                           512, 512, 0);
    subln_k<<<BL, 256, 0, stream>>>(h_f32, tmp, ln1g + l*512, ln1b + l*512,
                                    hx_f32, hx_bf);
    gemm_k<<<dim3(1,45), 256, 0, stream>>>(hx_bf, w1_t + (size_t)l*65536,
                                           b1 + l*128, ff1_bf, nullptr, nullptr,
                                           128, 512, 3);
    gemm_k<<<dim3(4,45), 256, 0, stream>>>(ff1_bf, w2_t + (size_t)l*65536,
                                           b2 + l*512, tmp, nullptr, nullptr,
                                           512, 128, 0);
    subln_k<<<BL, 256, 0, stream>>>(hx_f32, tmp, ln2g + l*512, ln2b + l*512,
                                    h_f32, h_bf);
    gemm_k<<<dim3(6,45), 256, 0, stream>>>(h_bf, wog_t + (size_t)l*393216,
                                           bog + l*672, qkv, nullptr, nullptr,
                                           672, 512, 0);
    yupd_k<<<(BL*PRED+255)/256, 256, 0, stream>>>(qkv, y, l==0?0:1);
  }
  final_k<<<(BB_*PRED*NF+255)/256, 256, 0, stream>>>(y, stdv, mean, out);
}

// Round 7
// 774.544 us; speedup vs baseline: 2.3744x; 1.0054x over previous
//
#include <hip/hip_runtime.h>
#include <math.h>

#define BB_ 8
#define LL_ 720
#define NF 321
#define DM 512
#define HH_ 8
#define DH 64
#define DFF 128
#define PRED 336
#define UK 35
#define NLAY 2
#define EPSF 1e-5f
#define BL (BB_*LL_)
#define TJC 72
#define NCH (LL_/TJC)

typedef unsigned short ushort;
typedef __attribute__((ext_vector_type(4))) float f32x4;
typedef __attribute__((ext_vector_type(8))) ushort ushort8;

#define KVSEG ((size_t)64*LL_*64)   // one K-or-V pack segment (bh=64 heads)

// ---------- bf16 <-> f32 (raw ushort bits) ----------
__device__ __forceinline__ float b2f(ushort u){
  unsigned int x = ((unsigned int)u) << 16;
  return __builtin_bit_cast(float, x);
}
__device__ __forceinline__ ushort f2b(float f){
  unsigned int x = __builtin_bit_cast(unsigned int, f);
  unsigned int r = x + 0x7fff + ((x >> 16) & 1);   // RNE
  return (ushort)(r >> 16);
}

// ---------- reductions ----------
__device__ __forceinline__ float wredsum(float v){
#pragma unroll
  for (int o=32;o>0;o>>=1) v += __shfl_xor(v,o,64);
  return v;
}
__device__ __forceinline__ float wredmax(float v){
#pragma unroll
  for (int o=32;o>0;o>>=1) v = fmaxf(v,__shfl_xor(v,o,64));
  return v;
}
__device__ __forceinline__ float bredsum(float v, float* red){
  int lane = threadIdx.x & 63, wid = threadIdx.x >> 6;
  v = wredsum(v);
  __syncthreads();
  if (lane==0) red[wid]=v;
  __syncthreads();
  return red[0]+red[1]+red[2]+red[3];
}

// ---------- stats over L: coalesced single-pass ----------
__global__ __launch_bounds__(256) void stats2_k(const float* __restrict__ x,
                                                float* __restrict__ mean,
                                                float* __restrict__ stdv,
                                                float* __restrict__ rstd){
  __shared__ float s1[4][64], s2[4][64];
  int b = blockIdx.x / 6, nt = blockIdx.x % 6;
  int nl = threadIdx.x & 63, lg = threadIdx.x >> 6;
  int n = nt*64 + nl;
  float sum=0.f, ss=0.f;
  if (n < NF){
    const float* xp = x + (size_t)b*LL_*NF + n;
    for (int l=lg; l<LL_; l+=4){ float v = xp[(size_t)l*NF]; sum += v; ss = fmaf(v,v,ss); }
  }
  s1[lg][nl]=sum; s2[lg][nl]=ss;
  __syncthreads();
  if (lg==0 && n<NF){
    float S = s1[0][nl]+s1[1][nl]+s1[2][nl]+s1[3][nl];
    float Q = s2[0][nl]+s2[1][nl]+s2[2][nl]+s2[3][nl];
    float mu = S*(1.f/LL_);
    float var = fmaxf((Q - S*mu)*(1.f/(LL_-1)), 0.f);
    float sd = sqrtf(var) + EPSF;
    int bn = b*NF+n;
    mean[bn]=mu; stdv[bn]=sd; rstd[bn]=1.f/sd;
  }
}

// ---------- normalized input -> bf16, K padded to 352 ----------
#define KPE 352
__global__ __launch_bounds__(256) void xnorm_k(const float* __restrict__ x,
                                               const float* __restrict__ mean,
                                               const float* __restrict__ rstd,
                                               ushort* __restrict__ xn){
  int idx = blockIdx.x*256 + threadIdx.x;
  if (idx >= BL*KPE) return;
  int c = idx % KPE; int bl = idx / KPE; int b = bl / LL_;
  float v = 0.f;
  if (c < NF) v = (x[(size_t)bl*NF + c] - mean[b*NF+c]) * rstd[b*NF+c];
  xn[idx] = f2b(v);
}

// ---------- weight transpose+convert mega-kernel ----------
struct TDesc { const float* in; ushort* out; int N, K, Npad, Kpad, nbx, blk0, ilv; };
struct TPack { TDesc d[17]; int n; };
__global__ __launch_bounds__(256) void transpose_k(TPack p){
  __shared__ float tile[32][33];
  int blk = blockIdx.x;
  int di = 0;
  while (di+1 < p.n && p.d[di+1].blk0 <= blk) ++di;
  TDesc D = p.d[di];
  int rel = blk - D.blk0;
  int bx = rel % D.nbx, by = rel / D.nbx;
  int k0 = bx*32, n0 = by*32;
  int t = threadIdx.x; int tx = t & 31, ty = t >> 5;
#pragma unroll
  for (int i=0;i<4;++i){
    int k = k0+ty+8*i, n = n0+tx;
    float v = (k < D.K && n < D.N) ? D.in[(size_t)k*D.N + n] : 0.f;
    tile[ty+8*i][tx] = v;
  }
  __syncthreads();
#pragma unroll
  for (int i=0;i<4;++i){
    int n = n0+ty+8*i, k = k0+tx;
    if (n < D.Npad && k < D.Kpad){
      int outn = D.ilv ? (2*n + (D.ilv-1)) : n;
      D.out[(size_t)outn*D.Kpad + k] = f2b(tile[tx][ty+8*i]);
    }
  }
}

// ---------- fused bias packing (qkv + interleaved out/gate) ----------
__global__ __launch_bounds__(256) void pack_bias_k(const float* __restrict__ bq,
                                                   const float* __restrict__ bk,
                                                   const float* __restrict__ bv,
                                                   const float* __restrict__ bo2,
                                                   const float* __restrict__ bg,
                                                   float* __restrict__ bqkv,
                                                   float* __restrict__ bog){
  int t = blockIdx.x*256 + threadIdx.x;
  if (t < 2*1536){
    int l = t/1536, c = t%1536;
    float v = c<512 ? bq[l*512+c] : (c<1024 ? bk[l*512+c-512] : bv[l*512+c-1024]);
    bqkv[t] = v;
  }
  if (t < 2*672){
    int l = t/672, c = t%672;
    int p = c>>1;
    bog[t] = (c&1) ? bg[l*336+p] : bo2[l*336+p];
  }
}

// ---------- bf16 MFMA GEMM: C[M,N] = A[M,K] @ Bt[N,K]^T + bias ----------
// flags: 1=relu, 2=bf16-only out, 4=dual store (fp32+bf16),
//        8=qkv mode (q fp32; K->kT+kR, V->vp bf16 packs),
//        16=gate epilogue y[row][col/2] (+)= t1*sigmoid(t2), 32=gate accumulate
__global__ __launch_bounds__(256) void gemm_k(
    const ushort* __restrict__ A, const ushort* __restrict__ Bt,
    const float* __restrict__ bias, void* __restrict__ Cout,
    ushort* __restrict__ Cbf, ushort* __restrict__ kvp,
    int N, int K, int flags)
{
  __shared__ ushort As[128*32];
  __shared__ ushort Bs[128*32];
  const int t = threadIdx.x;
  const int bm = blockIdx.y << 7, bn = blockIdx.x << 7;
  const int lane = t & 63, wid = t >> 6;
  const int wm = (wid >> 1) << 6, wn = (wid & 1) << 6;
  const int fr = lane & 15, kg = lane >> 4;

  f32x4 acc[4][4];
#pragma unroll
  for (int i=0;i<4;++i)
#pragma unroll
    for (int j=0;j<4;++j) acc[i][j] = (f32x4){0.f,0.f,0.f,0.f};

  const int rA0 = t >> 2,        qA0 = t & 3;
  const int rA1 = (t+256) >> 2;
  const size_t aOff0 = (size_t)(bm + rA0)*K + qA0*8;
  const size_t aOff1 = (size_t)(bm + rA1)*K + qA0*8;
  const size_t bOff0 = (size_t)(bn + rA0)*K + qA0*8;
  const size_t bOff1 = (size_t)(bn + rA1)*K + qA0*8;
  const int lA0 = (rA0<<5) + ((qA0 ^ ((rA0>>1)&3))<<3);
  const int lA1 = (rA1<<5) + ((qA0 ^ ((rA1>>1)&3))<<3);

  for (int k0=0; k0<K; k0+=32){
    ushort8 va0 = *(const ushort8*)(A  + aOff0 + k0);
    ushort8 va1 = *(const ushort8*)(A  + aOff1 + k0);
    ushort8 vb0 = *(const ushort8*)(Bt + bOff0 + k0);
    ushort8 vb1 = *(const ushort8*)(Bt + bOff1 + k0);
    *(ushort8*)&As[lA0] = va0;
    *(ushort8*)&As[lA1] = va1;
    *(ushort8*)&Bs[lA0] = vb0;
    *(ushort8*)&Bs[lA1] = vb1;
    __syncthreads();
    ushort8 af[4], bfr[4];
#pragma unroll
    for (int i=0;i<4;++i){
      int ra = wm + (i<<4) + fr;
      af[i]  = *(const ushort8*)&As[(ra<<5) + ((kg ^ ((ra>>1)&3))<<3)];
      int rb = wn + (i<<4) + fr;
      bfr[i] = *(const ushort8*)&Bs[(rb<<5) + ((kg ^ ((rb>>1)&3))<<3)];
    }
#pragma unroll
    for (int i=0;i<4;++i)
#pragma unroll
      for (int j=0;j<4;++j)
        asm("v_mfma_f32_16x16x32_bf16 %0, %1, %2, %0"
            : "+v"(acc[i][j]) : "v"(af[i]), "v"(bfr[j]));
    __syncthreads();
  }

  const int colBase = bn + wn + fr;
  const int rowBase = bm + wm + (kg << 2);

  if (flags & 16){
    // interleaved out/gate: even col = t1, odd col = t2
#pragma unroll
    for (int j=0;j<4;++j){
      int col = colBase + (j<<4);
      if (col >= N) continue;               // 672 is 16-aligned: wave-uniform
      float bv = bias[col];
#pragma unroll
      for (int i=0;i<4;++i){
        int row0 = rowBase + (i<<4);
#pragma unroll
        for (int r=0;r<4;++r){
          float v = acc[i][j][r] + bv;
          float o = __shfl_xor(v, 1, 64);   // partner (t2 for even lanes)
          if ((lane & 1) == 0){
            float val = v * (1.f/(1.f+__expf(-o)));
            size_t yi = (size_t)(row0+r)*PRED + (col>>1);
            float* yp = (float*)Cout;
            yp[yi] = (flags & 32) ? (yp[yi] + val) : val;
          }
        }
      }
    }
    return;
  }

#pragma unroll
  for (int j=0;j<4;++j){
    int col = colBase + (j<<4);
    if (col >= N) continue;
    float bv = bias[col];
#pragma unroll
    for (int i=0;i<4;++i){
      int row0 = rowBase + (i<<4);
#pragma unroll
      for (int r=0;r<4;++r){
        float v = acc[i][j][r] + bv;
        if (flags & 1) v = fmaxf(v, 0.f);
        int row = row0 + r;
        size_t idx = (size_t)row*N + col;
        if (flags & 2) ((ushort*)Cout)[idx] = f2b(v);
        else if (flags & 8){
          if (col < 512) ((float*)Cout)[idx] = v;
          else {
            int hh = (col >> 6) & 7;
            int dd = col & 63;
            int bb = row / LL_; int jr = row - bb*LL_;
            ushort bfv = f2b(v);
            if (col < 1024){
              kvp[((size_t)(bb*8+hh)*64 + dd)*LL_ + jr] = bfv;            // kT [bh][d][L]
              kvp[2*KVSEG + ((size_t)(bb*8+hh)*LL_ + jr)*64 + dd] = bfv;  // kR [bh][L][d]
            } else {
              kvp[KVSEG + ((size_t)(bb*8+hh)*LL_ + jr)*64 + dd] = bfv;    // V  [bh][L][d]
            }
          }
        } else {
          ((float*)Cout)[idx] = v;
          if (flags & 4) Cbf[idx] = f2b(v);
        }
      }
    }
  }
}

// ---------- fused sampled-QK + M score: one wave per (b,h,l), lane=sample ----------
__global__ __launch_bounds__(256) void msc_k(const float* __restrict__ qkv,
                                             const ushort* __restrict__ kR,
                                             const int* __restrict__ samp,
                                             float* __restrict__ Mb){
  __shared__ float sq[4][64];
  int wid = threadIdx.x >> 6, lane = threadIdx.x & 63;
  int gid = blockIdx.x*4 + wid;                 // (b*H+h)*L + l
  int l = gid % LL_; int bh = gid / LL_; int h = bh & 7; int b = bh >> 3;
  sq[wid][lane] = qkv[(size_t)(b*LL_ + l)*1536 + h*64 + lane];
  __syncthreads();
  float acc = 0.f;
  if (lane < UK){
    int j = samp[l*UK + lane];
    const ushort8* kr = (const ushort8*)(kR + ((size_t)bh*LL_ + j)*64);
    const float* sqw = sq[wid];
#pragma unroll
    for (int d8=0; d8<8; ++d8){
      ushort8 kk = kr[d8];
#pragma unroll
      for (int e=0;e<8;++e) acc = fmaf(sqw[d8*8+e], b2f(kk[e]), acc);
    }
  }
  float mx = (lane < UK) ? acc : -INFINITY;
  float sm = (lane < UK) ? acc : 0.f;
  mx = wredmax(mx);
  sm = wredsum(sm);
  if (lane == 0) Mb[gid] = mx - sm*(1.f/LL_);
}

// ---------- top-U per (b,h): one wave, shuffle-only ----------
__global__ __launch_bounds__(64) void topk2_k(const float* __restrict__ Mb,
                                              int* __restrict__ mtop){
  int bh = blockIdx.x; int lane = threadIdx.x;
  const float* mp = Mb + (size_t)bh*LL_;
  float v[12]; int vi[12];
#pragma unroll
  for (int i=0;i<12;++i){
    int j = lane + i*64;
    bool ok = j < LL_;
    v[i] = ok ? mp[j] : -INFINITY;
    vi[i] = ok ? j : (LL_ + i);
  }
  for (int it=0; it<UK; ++it){
    float best = v[0]; int bi = vi[0]; int bslot = 0;
#pragma unroll
    for (int i=1;i<12;++i){
      if (v[i] > best || (v[i]==best && vi[i] < bi)){ best=v[i]; bi=vi[i]; bslot=i; }
    }
    float gb = best; int gi = bi;
#pragma unroll
    for (int o=32;o>0;o>>=1){
      float ov = __shfl_xor(gb,o,64); int oi = __shfl_xor(gi,o,64);
      if (ov > gb || (ov==gb && oi < gi)){ gb=ov; gi=oi; }
    }
    if (lane==0) mtop[(size_t)bh*UK + it] = gi;
    if (bi == gi){
#pragma unroll
      for (int i=0;i<12;++i) if (i==bslot) v[i] = -INFINITY;
    }
  }
}

// ---------- v mean over L from bf16 V pack ----------
__global__ __launch_bounds__(256) void vmean_k(const ushort* __restrict__ vp,
                                               float* __restrict__ vmn){
  __shared__ float part[4][64];
  int bh = blockIdx.x;
  int t = threadIdx.x; int d = t & 63, jg = t >> 6;
  const ushort* vb = vp + (size_t)bh*LL_*64 + d;
  float s = 0.f;
  for (int j=jg; j<LL_; j+=4) s += b2f(vb[(size_t)j*64]);
  part[jg][d] = s;
  __syncthreads();
  if (t < 64) vmn[bh*64+t] = (part[0][t]+part[1][t]+part[2][t]+part[3][t])*(1.f/LL_);
}

// ---------- ctx = broadcast v_mean (bf16) ----------
__global__ __launch_bounds__(256) void ctxfill_k(const float* __restrict__ vmn,
                                                 ushort* __restrict__ ctx){
  int idx = blockIdx.x*256 + threadIdx.x;   // < BL*DM
  int c = idx & 511; int bl = idx >> 9; int b = bl / LL_;
  ctx[idx] = f2b(vmn[(b*8 + (c>>6))*64 + (c&63)]);
}

// ---------- chunked attention partials: one block per (b,h,chunk) ----------
__global__ __launch_bounds__(256) void attn4_k(const float* __restrict__ qkv,
                                               const ushort* __restrict__ kT,
                                               const ushort* __restrict__ vp,
                                               const int* __restrict__ mtop,
                                               float* __restrict__ pacc,
                                               float* __restrict__ pm,
                                               float* __restrict__ pl){
  __shared__ ushort skT[64][TJC];    // K^T chunk
  __shared__ ushort sv[TJC][64];     // V chunk
  __shared__ float  sq[UK][64];
  __shared__ float  sc[UK][TJC];
  int blk = blockIdx.x;
  int ch = blk % NCH; int bh = blk / NCH;
  int b = bh >> 3, h = bh & 7; int t0 = ch*TJC;
  int t = threadIdx.x, lane = t & 63, wid = t >> 6;
  for (int idx=t; idx<64*(TJC/8); idx+=256){
    int d = idx/(TJC/8), c8 = idx%(TJC/8);
    *(ushort8*)&skT[d][c8*8] =
      *(const ushort8*)(kT + ((size_t)bh*64 + d)*LL_ + t0 + c8*8);
  }
  for (int idx=t; idx<TJC*8; idx+=256){
    int jj = idx>>3, c8 = idx&7;
    *(ushort8*)&sv[jj][c8*8] =
      *(const ushort8*)(vp + ((size_t)bh*LL_ + t0+jj)*64 + c8*8);
  }
  for (int idx=t; idx<UK*64; idx+=256){
    int u = idx>>6, d = idx&63;
    int row = mtop[bh*UK + u];
    sq[u][d] = qkv[(size_t)(b*LL_ + row)*1536 + h*64 + d];
  }
  __syncthreads();
  for (int idx=t; idx<UK*(TJC/8); idx+=256){
    int u = idx/(TJC/8), jb = idx%(TJC/8);
    float dot[8] = {0.f,0.f,0.f,0.f,0.f,0.f,0.f,0.f};
    const float* qu = sq[u];
#pragma unroll
    for (int d=0; d<64; ++d){
      ushort8 kk = *(const ushort8*)&skT[d][jb*8];
      float qv = qu[d];
#pragma unroll
      for (int e=0;e<8;++e) dot[e] = fmaf(qv, b2f(kk[e]), dot[e]);
    }
#pragma unroll
    for (int e=0;e<8;++e) sc[u][jb*8+e] = dot[e]*0.125f;
  }
  __syncthreads();
  for (int u=wid; u<UK; u+=4){
    float v0 = sc[u][lane];
    float v1 = (lane < TJC-64) ? sc[u][64+lane] : -3.0e38f;
    float mx = wredmax(fmaxf(v0,v1));
    float e0 = __expf(v0-mx);
    float e1 = (lane < TJC-64) ? __expf(v1-mx) : 0.f;
    sc[u][lane] = e0;
    if (lane < TJC-64) sc[u][64+lane] = e1;
    float s = wredsum(e0+e1);
    if (lane==0){
      pm[((size_t)bh*NCH+ch)*UK + u] = mx;
      pl[((size_t)bh*NCH+ch)*UK + u] = s;
    }
  }
  __syncthreads();
  for (int idx=t; idx<UK*64; idx+=256){
    int u = idx>>6, d = idx&63;
    const float* scu = sc[u];
    float a = 0.f;
#pragma unroll 8
    for (int jj=0; jj<TJC; ++jj) a = fmaf(scu[jj], b2f(sv[jj][d]), a);
    pacc[(((size_t)bh*NCH+ch)*UK + u)*64 + d] = a;
  }
}

// ---------- combine partials + scatter into ctx ----------
__global__ __launch_bounds__(256) void attn5_k(const float* __restrict__ pacc,
                                               const float* __restrict__ pm,
                                               const float* __restrict__ pl,
                                               const int* __restrict__ mtop,
                                               ushort* __restrict__ ctx){
  int bh = blockIdx.x; int b = bh >> 3, h = bh & 7;
  int t = threadIdx.x;
  for (int idx=t; idx<UK*64; idx+=256){
    int u = idx>>6, d = idx&63;
    float M = -3.0e38f;
#pragma unroll
    for (int ch=0; ch<NCH; ++ch)
      M = fmaxf(M, pm[((size_t)bh*NCH+ch)*UK + u]);
    float L = 0.f, A = 0.f;
#pragma unroll
    for (int ch=0; ch<NCH; ++ch){
      float w = __expf(pm[((size_t)bh*NCH+ch)*UK + u] - M);
      L += w * pl[((size_t)bh*NCH+ch)*UK + u];
      A += w * pacc[(((size_t)bh*NCH+ch)*UK + u)*64 + d];
    }
    int row = mtop[bh*UK + u];
    ctx[(size_t)(b*LL_ + row)*DM + h*64 + d] = f2b(A / L);
  }
}

// ---------- LN(a - s): fp32 residual chain, dual output ----------
__global__ __launch_bounds__(256) void subln_k(const float* __restrict__ a,
                                               const float* __restrict__ s,
                                               const float* __restrict__ g,
                                               const float* __restrict__ be,
                                               float* __restrict__ of32,
                                               ushort* __restrict__ obf){
  __shared__ float red[4];
  int row = blockIdx.x;
  size_t base = (size_t)row * DM;
  int t = threadIdx.x;
  float e0 = a[base+t]     - s[base+t];
  float e1 = a[base+t+256] - s[base+t+256];
  float sum = bredsum(e0+e1, red);
  float mu = sum * (1.f/DM);
  float d0 = e0-mu, d1 = e1-mu;
  __syncthreads();
  float var = bredsum(d0*d0+d1*d1, red);
  float rs = rsqrtf(var*(1.f/DM) + EPSF);
  float o0 = d0*rs*g[t]     + be[t];
  float o1 = d1*rs*g[t+256] + be[t+256];
  of32[base+t]     = o0;
  of32[base+t+256] = o1;
  obf[base+t]      = f2b(o0);
  obf[base+t+256]  = f2b(o1);
}

// ---------- final: LDS-tiled transpose, out[b,p,n] = y[b,n,p]*std + mean ----------
__global__ __launch_bounds__(256) void final2_k(const float* __restrict__ y,
                                                const float* __restrict__ stdv,
                                                const float* __restrict__ mean,
                                                float* __restrict__ out){
  __shared__ float tile[32][33];
  int n0 = blockIdx.x*32, p0 = blockIdx.y*32, b = blockIdx.z;
  int tx = threadIdx.x & 31, ty = threadIdx.x >> 5;
  for (int i=ty; i<32; i+=8){
    int n = n0+i, p = p0+tx;
    tile[i][tx] = (n<NF && p<PRED) ? y[((size_t)b*LL_+n)*PRED + p] : 0.f;
  }
  __syncthreads();
  for (int i=ty; i<32; i+=8){
    int p = p0+i, n = n0+tx;
    if (p<PRED && n<NF)
      out[((size_t)b*PRED + p)*NF + n] = tile[tx][i]*stdv[b*NF+n] + mean[b*NF+n];
  }
}

// ---------------- host ----------------
extern "C" void kernel_launch(void* const* d_in, const int* in_sizes, int n_in,
                              void* d_out, int out_size, void* d_ws, size_t ws_size,
                              hipStream_t stream){
  const float* x_enc = (const float*)d_in[0];
  const int*   samp  = (const int*)  d_in[1];
  const float* embw  = (const float*)d_in[2];
  const float* embb  = (const float*)d_in[3];
  const float* wq    = (const float*)d_in[4];
  const float* bq    = (const float*)d_in[5];
  const float* wk    = (const float*)d_in[6];
  const float* bk    = (const float*)d_in[7];
  const float* wv    = (const float*)d_in[8];
  const float* bv    = (const float*)d_in[9];
  const float* wo    = (const float*)d_in[10];
  const float* bo    = (const float*)d_in[11];
  const float* ln1g  = (const float*)d_in[12];
  const float* ln1b  = (const float*)d_in[13];
  const float* w1    = (const float*)d_in[14];
  const float* b1    = (const float*)d_in[15];
  const float* w2    = (const float*)d_in[16];
  const float* b2    = (const float*)d_in[17];
  const float* ln2g  = (const float*)d_in[18];
  const float* ln2b  = (const float*)d_in[19];
  const float* wout  = (const float*)d_in[20];
  const float* boutp = (const float*)d_in[21];
  const float* wg    = (const float*)d_in[22];
  const float* bg    = (const float*)d_in[23];
  float* out = (float*)d_out;

  char* wsb = (char*)d_ws;
  size_t off = 0;
  auto alloc = [&](size_t bytes)->void*{
    void* p = wsb + off; off += (bytes + 255) & ~(size_t)255; return p;
  };
  float* mean  = (float*)alloc((size_t)BB_*NF*4);
  float* stdv  = (float*)alloc((size_t)BB_*NF*4);
  float* rstd  = (float*)alloc((size_t)BB_*NF*4);
  float* bqkv  = (float*)alloc(2*1536*4);
  float* bog   = (float*)alloc(2*672*4);
  ushort* xn     = (ushort*)alloc((size_t)BL*KPE*2);
  ushort* we_t   = (ushort*)alloc((size_t)512*KPE*2);
  ushort* wqkv_t = (ushort*)alloc((size_t)2*1536*512*2);
  ushort* wo_t   = (ushort*)alloc((size_t)2*512*512*2);
  ushort* w1_t   = (ushort*)alloc((size_t)2*128*512*2);
  ushort* w2_t   = (ushort*)alloc((size_t)2*512*128*2);
  ushort* wog_t  = (ushort*)alloc((size_t)2*768*512*2);
  ushort* h_bf   = (ushort*)alloc((size_t)BL*DM*2);
  ushort* hx_bf  = (ushort*)alloc((size_t)BL*DM*2);
  ushort* ctx_bf = (ushort*)alloc((size_t)BL*DM*2);
  ushort* ff1_bf = (ushort*)alloc((size_t)BL*DFF*2);
  ushort* kvpack = (ushort*)alloc(3*KVSEG*2);
  float* h_f32   = (float*)alloc((size_t)BL*DM*4);
  float* hx_f32  = (float*)alloc((size_t)BL*DM*4);
  float* qkv = (float*)alloc((size_t)BL*1536*4);
  float* tmp = (float*)alloc((size_t)BL*DM*4);
  float* y   = (float*)alloc((size_t)BL*PRED*4);
  float* Mb  = (float*)alloc((size_t)BB_*HH_*LL_*4);
  int*  mtop = (int*)  alloc((size_t)BB_*HH_*UK*4);
  float* vmn = (float*)alloc((size_t)BB_*HH_*DH*4);
  float* pacc = (float*)alloc((size_t)64*NCH*UK*64*4);
  float* pm   = (float*)alloc((size_t)64*NCH*UK*4);
  float* pl   = (float*)alloc((size_t)64*NCH*UK*4);
  if (off > ws_size) return;
  ushort* kTp   = kvpack;
  ushort* vpack = kvpack + KVSEG;
  ushort* kRp   = kvpack + 2*KVSEG;

  stats2_k<<<BB_*6, 256, 0, stream>>>(x_enc, mean, stdv, rstd);
  xnorm_k<<<(BL*KPE+255)/256, 256, 0, stream>>>(x_enc, mean, rstd, xn);

  TPack tp; int blk = 0; int di = 0;
  auto addT = [&](const float* in, ushort* o, int N, int K, int Npad, int Kpad, int ilv){
    TDesc& d = tp.d[di++]; d.in=in; d.out=o; d.N=N; d.K=K; d.Npad=Npad; d.Kpad=Kpad; d.ilv=ilv;
    d.nbx = (Kpad+31)/32; d.blk0 = blk; blk += d.nbx * ((Npad+31)/32);
  };
  addT(embw, we_t, 512, NF, 512, KPE, 0);
  for (int l=0;l<NLAY;++l){
    addT(wq + (size_t)l*262144, wqkv_t + (size_t)l*786432,            512,512,512,512,0);
    addT(wk + (size_t)l*262144, wqkv_t + (size_t)l*786432 + 262144,   512,512,512,512,0);
    addT(wv + (size_t)l*262144, wqkv_t + (size_t)l*786432 + 524288,   512,512,512,512,0);
    addT(wo + (size_t)l*262144, wo_t   + (size_t)l*262144,            512,512,512,512,0);
    addT(w1 + (size_t)l*65536,  w1_t   + (size_t)l*65536,             128,512,128,512,0);
    addT(w2 + (size_t)l*65536,  w2_t   + (size_t)l*65536,             512,128,512,128,0);
    addT(wout + (size_t)l*172032, wog_t + (size_t)l*393216,           336,512,384,512,1);
    addT(wg   + (size_t)l*172032, wog_t + (size_t)l*393216,           336,512,384,512,2);
  }
  tp.n = di;
  transpose_k<<<blk, 256, 0, stream>>>(tp);
  pack_bias_k<<<12, 256, 0, stream>>>(bq, bk, bv, boutp, bg, bqkv, bog);

  // embed: h = xn @ embw + embb  (dual fp32 + bf16)
  gemm_k<<<dim3(4,45), 256, 0, stream>>>(xn, we_t, embb, h_f32, h_bf, nullptr,
                                         512, KPE, 4);

  for (int l=0;l<NLAY;++l){
    gemm_k<<<dim3(12,45), 256, 0, stream>>>(h_bf, wqkv_t + (size_t)l*786432,
                                            bqkv + l*1536, qkv, nullptr, kvpack,
                                            1536, 512, 8);
    msc_k<<<BB_*HH_*LL_/4, 256, 0, stream>>>(qkv, kRp, samp, Mb);
    topk2_k<<<BB_*HH_, 64, 0, stream>>>(Mb, mtop);
    vmean_k<<<BB_*HH_, 256, 0, stream>>>(vpack, vmn);
    ctxfill_k<<<BL*DM/256, 256, 0, stream>>>(vmn, ctx_bf);
    attn4_k<<<64*NCH, 256, 0, stream>>>(qkv, kTp, vpack, mtop, pacc, pm, pl);
    attn5_k<<<64, 256, 0, stream>>>(pacc, pm, pl, mtop, ctx_bf);
    gemm_k<<<dim3(4,45), 256, 0, stream>>>(ctx_bf, wo_t + (size_t)l*262144,
                                           bo + l*512, tmp, nullptr, nullptr,
                                           512, 512, 0);
    subln_k<<<BL, 256, 0, stream>>>(h_f32, tmp, ln1g + l*512, ln1b + l*512,
                                    hx_f32, hx_bf);
    gemm_k<<<dim3(1,45), 256, 0, stream>>>(hx_bf, w1_t + (size_t)l*65536,
                                           b1 + l*128, ff1_bf, nullptr, nullptr,
                                           128, 512, 3);
    gemm_k<<<dim3(4,45), 256, 0, stream>>>(ff1_bf, w2_t + (size_t)l*65536,
                                           b2 + l*512, tmp, nullptr, nullptr,
                                           512, 128, 0);
    subln_k<<<BL, 256, 0, stream>>>(hx_f32, tmp, ln2g + l*512, ln2b + l*512,
                                    h_f32, h_bf);
    gemm_k<<<dim3(6,45), 256, 0, stream>>>(h_bf, wog_t + (size_t)l*393216,
                                           bog + l*672, y, nullptr, nullptr,
                                           672, 512, 16 | (l ? 32 : 0));
  }
  final2_k<<<dim3((NF+31)/32,(PRED+31)/32,BB_), 256, 0, stream>>>(y, stdv, mean, out);
}

// Round 9
// 717.933 us; speedup vs baseline: 2.5617x; 1.0789x over previous
//
#include <hip/hip_runtime.h>
#include <math.h>

#define BB_ 8
#define LL_ 720
#define NF 321
#define DM 512
#define HH_ 8
#define DH 64
#define DFF 128
#define PRED 336
#define UK 35
#define NLAY 2
#define EPSF 1e-5f
#define BL (BB_*LL_)
#define TJC 72
#define NCH (LL_/TJC)
#define LCH 48
#define NLC (LL_/LCH)

typedef unsigned short ushort;
typedef __attribute__((ext_vector_type(4))) float f32x4;
typedef __attribute__((ext_vector_type(8))) ushort ushort8;
typedef __attribute__((ext_vector_type(4))) ushort ushortx4;

#define KVSEG ((size_t)64*LL_*64)   // one K-or-V pack segment (bh=64 heads)

// ---------- bf16 <-> f32 (raw ushort bits) ----------
__device__ __forceinline__ float b2f(ushort u){
  unsigned int x = ((unsigned int)u) << 16;
  return __builtin_bit_cast(float, x);
}
__device__ __forceinline__ ushort f2b(float f){
  unsigned int x = __builtin_bit_cast(unsigned int, f);
  unsigned int r = x + 0x7fff + ((x >> 16) & 1);   // RNE
  return (ushort)(r >> 16);
}

// ---------- reductions ----------
__device__ __forceinline__ float wredsum(float v){
#pragma unroll
  for (int o=32;o>0;o>>=1) v += __shfl_xor(v,o,64);
  return v;
}
__device__ __forceinline__ float wredmax(float v){
#pragma unroll
  for (int o=32;o>0;o>>=1) v = fmaxf(v,__shfl_xor(v,o,64));
  return v;
}
__device__ __forceinline__ float bredsum(float v, float* red){
  int lane = threadIdx.x & 63, wid = threadIdx.x >> 6;
  v = wredsum(v);
  __syncthreads();
  if (lane==0) red[wid]=v;
  __syncthreads();
  return red[0]+red[1]+red[2]+red[3];
}

// ---------- stats partials: one block per (b, n-tile, L-chunk) ----------
__global__ __launch_bounds__(256) void stats3_k(const float* __restrict__ x,
                                                float* __restrict__ pp){
  __shared__ float s1[4][64], s2[4][64];
  int blk = blockIdx.x;                  // b*6*NLC + nt*NLC + lc
  int lc = blk % NLC; int r = blk / NLC;
  int nt = r % 6; int b = r / 6;
  int nl = threadIdx.x & 63, lg = threadIdx.x >> 6;
  int n = nt*64 + nl;
  float sum=0.f, ss=0.f;
  if (n < NF){
    const float* xp = x + ((size_t)b*LL_ + lc*LCH)*NF + n;
    for (int l=lg; l<LCH; l+=4){ float v = xp[(size_t)l*NF]; sum += v; ss = fmaf(v,v,ss); }
  }
  s1[lg][nl]=sum; s2[lg][nl]=ss;
  __syncthreads();
  if (lg==0){
    float S = s1[0][nl]+s1[1][nl]+s1[2][nl]+s1[3][nl];
    float Q = s2[0][nl]+s2[1][nl]+s2[2][nl]+s2[3][nl];
    pp[(size_t)blk*128 + nl]      = S;
    pp[(size_t)blk*128 + 64 + nl] = Q;
  }
}

// ---------- stats combine: one block per (b, n-tile) ----------
__global__ __launch_bounds__(64) void statsc_k(const float* __restrict__ pp,
                                               float* __restrict__ mean,
                                               float* __restrict__ stdv,
                                               float* __restrict__ rstd){
  int bn6 = blockIdx.x;                  // b*6 + nt
  int nl = threadIdx.x;
  int nt = bn6 % 6, b = bn6 / 6;
  int n = nt*64 + nl;
  if (n >= NF) return;
  float S=0.f, Q=0.f;
#pragma unroll
  for (int lc=0; lc<NLC; ++lc){
    size_t base = ((size_t)(b*6+nt)*NLC + lc)*128;
    S += pp[base + nl];
    Q += pp[base + 64 + nl];
  }
  float mu = S*(1.f/LL_);
  float var = fmaxf((Q - S*mu)*(1.f/(LL_-1)), 0.f);
  float sd = sqrtf(var) + EPSF;
  int bn = b*NF+n;
  mean[bn]=mu; stdv[bn]=sd; rstd[bn]=1.f/sd;
}

// ---------- normalized input -> bf16, K padded to 352 ----------
#define KPE 352
__global__ __launch_bounds__(256) void xnorm_k(const float* __restrict__ x,
                                               const float* __restrict__ mean,
                                               const float* __restrict__ rstd,
                                               ushort* __restrict__ xn){
  int idx = blockIdx.x*256 + threadIdx.x;
  if (idx >= BL*KPE) return;
  int c = idx % KPE; int bl = idx / KPE; int b = bl / LL_;
  float v = 0.f;
  if (c < NF) v = (x[(size_t)bl*NF + c] - mean[b*NF+c]) * rstd[b*NF+c];
  xn[idx] = f2b(v);
}

// ---------- weight transpose+convert mega-kernel ----------
struct TDesc { const float* in; ushort* out; int N, K, Npad, Kpad, nbx, blk0, ilv; };
struct TPack { TDesc d[17]; int n; };
__global__ __launch_bounds__(256) void transpose_k(TPack p){
  __shared__ float tile[32][33];
  int blk = blockIdx.x;
  int di = 0;
  while (di+1 < p.n && p.d[di+1].blk0 <= blk) ++di;
  TDesc D = p.d[di];
  int rel = blk - D.blk0;
  int bx = rel % D.nbx, by = rel / D.nbx;
  int k0 = bx*32, n0 = by*32;
  int t = threadIdx.x; int tx = t & 31, ty = t >> 5;
#pragma unroll
  for (int i=0;i<4;++i){
    int k = k0+ty+8*i, n = n0+tx;
    float v = (k < D.K && n < D.N) ? D.in[(size_t)k*D.N + n] : 0.f;
    tile[ty+8*i][tx] = v;
  }
  __syncthreads();
#pragma unroll
  for (int i=0;i<4;++i){
    int n = n0+ty+8*i, k = k0+tx;
    if (n < D.Npad && k < D.Kpad){
      int outn = D.ilv ? (2*n + (D.ilv-1)) : n;
      D.out[(size_t)outn*D.Kpad + k] = f2b(tile[tx][ty+8*i]);
    }
  }
}

// ---------- fused bias packing (qkv + interleaved out/gate) ----------
__global__ __launch_bounds__(256) void pack_bias_k(const float* __restrict__ bq,
                                                   const float* __restrict__ bk,
                                                   const float* __restrict__ bv,
                                                   const float* __restrict__ bo2,
                                                   const float* __restrict__ bg,
                                                   float* __restrict__ bqkv,
                                                   float* __restrict__ bog){
  int t = blockIdx.x*256 + threadIdx.x;
  if (t < 2*1536){
    int l = t/1536, c = t%1536;
    float v = c<512 ? bq[l*512+c] : (c<1024 ? bk[l*512+c-512] : bv[l*512+c-1024]);
    bqkv[t] = v;
  }
  if (t < 2*672){
    int l = t/672, c = t%672;
    int p = c>>1;
    bog[t] = (c&1) ? bg[l*336+p] : bo2[l*336+p];
  }
}

// ---------- bf16 MFMA GEMM: C[M,N] = A[M,K] @ Bt[N,K]^T + bias ----------
// flags: 1=relu, 2=bf16-only out, 4=dual store (fp32+bf16),
//        8=qkv mode (q fp32; K->kT+kR, V->vp bf16 packs),
//        16=gate epilogue y[row][col/2] (+)= t1*sigmoid(t2), 32=gate accumulate
__global__ __launch_bounds__(256) void gemm_k(
    const ushort* __restrict__ A, const ushort* __restrict__ Bt,
    const float* __restrict__ bias, void* __restrict__ Cout,
    ushort* __restrict__ Cbf, ushort* __restrict__ kvp,
    int N, int K, int flags)
{
  __shared__ ushort As[128*32];
  __shared__ ushort Bs[128*32];
  const int t = threadIdx.x;
  const int bm = blockIdx.y << 7, bn = blockIdx.x << 7;
  const int lane = t & 63, wid = t >> 6;
  const int wm = (wid >> 1) << 6, wn = (wid & 1) << 6;
  const int fr = lane & 15, kg = lane >> 4;

  f32x4 acc[4][4];
#pragma unroll
  for (int i=0;i<4;++i)
#pragma unroll
    for (int j=0;j<4;++j) acc[i][j] = (f32x4){0.f,0.f,0.f,0.f};

  const int rA0 = t >> 2,        qA0 = t & 3;
  const int rA1 = (t+256) >> 2;
  const size_t aOff0 = (size_t)(bm + rA0)*K + qA0*8;
  const size_t aOff1 = (size_t)(bm + rA1)*K + qA0*8;
  const size_t bOff0 = (size_t)(bn + rA0)*K + qA0*8;
  const size_t bOff1 = (size_t)(bn + rA1)*K + qA0*8;
  const int lA0 = (rA0<<5) + ((qA0 ^ ((rA0>>1)&3))<<3);
  const int lA1 = (rA1<<5) + ((qA0 ^ ((rA1>>1)&3))<<3);

  for (int k0=0; k0<K; k0+=32){
    ushort8 va0 = *(const ushort8*)(A  + aOff0 + k0);
    ushort8 va1 = *(const ushort8*)(A  + aOff1 + k0);
    ushort8 vb0 = *(const ushort8*)(Bt + bOff0 + k0);
    ushort8 vb1 = *(const ushort8*)(Bt + bOff1 + k0);
    *(ushort8*)&As[lA0] = va0;
    *(ushort8*)&As[lA1] = va1;
    *(ushort8*)&Bs[lA0] = vb0;
    *(ushort8*)&Bs[lA1] = vb1;
    __syncthreads();
    ushort8 af[4], bfr[4];
#pragma unroll
    for (int i=0;i<4;++i){
      int ra = wm + (i<<4) + fr;
      af[i]  = *(const ushort8*)&As[(ra<<5) + ((kg ^ ((ra>>1)&3))<<3)];
      int rb = wn + (i<<4) + fr;
      bfr[i] = *(const ushort8*)&Bs[(rb<<5) + ((kg ^ ((rb>>1)&3))<<3)];
    }
#pragma unroll
    for (int i=0;i<4;++i)
#pragma unroll
      for (int j=0;j<4;++j)
        asm("v_mfma_f32_16x16x32_bf16 %0, %1, %2, %0"
            : "+v"(acc[i][j]) : "v"(af[i]), "v"(bfr[j]));
    __syncthreads();
  }

  const int colBase = bn + wn + fr;
  const int rowBase = bm + wm + (kg << 2);

  if (flags & 16){
    // interleaved out/gate: even col = t1, odd col = t2
#pragma unroll
    for (int j=0;j<4;++j){
      int col = colBase + (j<<4);
      if (col >= N) continue;               // 672 is 16-aligned: wave-uniform
      float bv = bias[col];
#pragma unroll
      for (int i=0;i<4;++i){
        int row0 = rowBase + (i<<4);
#pragma unroll
        for (int r=0;r<4;++r){
          float v = acc[i][j][r] + bv;
          float o = __shfl_xor(v, 1, 64);   // partner (t2 for even lanes)
          if ((lane & 1) == 0){
            float val = v * (1.f/(1.f+__expf(-o)));
            size_t yi = (size_t)(row0+r)*PRED + (col>>1);
            float* yp = (float*)Cout;
            yp[yi] = (flags & 32) ? (yp[yi] + val) : val;
          }
        }
      }
    }
    return;
  }

#pragma unroll
  for (int j=0;j<4;++j){
    int col = colBase + (j<<4);
    if (col >= N) continue;
    float bv = bias[col];
#pragma unroll
    for (int i=0;i<4;++i){
      int row0 = rowBase + (i<<4);
#pragma unroll
      for (int r=0;r<4;++r){
        float v = acc[i][j][r] + bv;
        if (flags & 1) v = fmaxf(v, 0.f);
        int row = row0 + r;
        size_t idx = (size_t)row*N + col;
        if (flags & 2) ((ushort*)Cout)[idx] = f2b(v);
        else if (flags & 8){
          if (col < 512) ((float*)Cout)[idx] = v;
          else {
            int hh = (col >> 6) & 7;
            int dd = col & 63;
            int bb = row / LL_; int jr = row - bb*LL_;
            ushort bfv = f2b(v);
            if (col < 1024){
              kvp[((size_t)(bb*8+hh)*64 + dd)*LL_ + jr] = bfv;            // kT [bh][d][L]
              kvp[2*KVSEG + ((size_t)(bb*8+hh)*LL_ + jr)*64 + dd] = bfv;  // kR [bh][L][d]
            } else {
              kvp[KVSEG + ((size_t)(bb*8+hh)*LL_ + jr)*64 + dd] = bfv;    // V  [bh][L][d]
            }
          }
        } else {
          ((float*)Cout)[idx] = v;
          if (flags & 4) Cbf[idx] = f2b(v);
        }
      }
    }
  }
}

// ---------- fused sampled-QK + M score: one wave per (b,h,l), lane=sample ----------
__global__ __launch_bounds__(256) void msc_k(const float* __restrict__ qkv,
                                             const ushort* __restrict__ kR,
                                             const int* __restrict__ samp,
                                             float* __restrict__ Mb){
  __shared__ float sq[4][64];
  int wid = threadIdx.x >> 6, lane = threadIdx.x & 63;
  int gid = blockIdx.x*4 + wid;                 // (b*H+h)*L + l
  int l = gid % LL_; int bh = gid / LL_; int h = bh & 7; int b = bh >> 3;
  sq[wid][lane] = qkv[(size_t)(b*LL_ + l)*1536 + h*64 + lane];
  __syncthreads();
  float acc = 0.f;
  if (lane < UK){
    int j = samp[l*UK + lane];
    const ushort8* kr = (const ushort8*)(kR + ((size_t)bh*LL_ + j)*64);
    const float* sqw = sq[wid];
#pragma unroll
    for (int d8=0; d8<8; ++d8){
      ushort8 kk = kr[d8];
#pragma unroll
      for (int e=0;e<8;++e) acc = fmaf(sqw[d8*8+e], b2f(kk[e]), acc);
    }
  }
  float mx = (lane < UK) ? acc : -INFINITY;
  float sm = (lane < UK) ? acc : 0.f;
  mx = wredmax(mx);
  sm = wredsum(sm);
  if (lane == 0) Mb[gid] = mx - sm*(1.f/LL_);
}

// ---------- top-U per (b,h): one wave, shuffle-only ----------
__global__ __launch_bounds__(64) void topk2_k(const float* __restrict__ Mb,
                                              int* __restrict__ mtop){
  int bh = blockIdx.x; int lane = threadIdx.x;
  const float* mp = Mb + (size_t)bh*LL_;
  float v[12]; int vi[12];
#pragma unroll
  for (int i=0;i<12;++i){
    int j = lane + i*64;
    bool ok = j < LL_;
    v[i] = ok ? mp[j] : -INFINITY;
    vi[i] = ok ? j : (LL_ + i);
  }
  for (int it=0; it<UK; ++it){
    float best = v[0]; int bi = vi[0]; int bslot = 0;
#pragma unroll
    for (int i=1;i<12;++i){
      if (v[i] > best || (v[i]==best && vi[i] < bi)){ best=v[i]; bi=vi[i]; bslot=i; }
    }
    float gb = best; int gi = bi;
#pragma unroll
    for (int o=32;o>0;o>>=1){
      float ov = __shfl_xor(gb,o,64); int oi = __shfl_xor(gi,o,64);
      if (ov > gb || (ov==gb && oi < gi)){ gb=ov; gi=oi; }
    }
    if (lane==0) mtop[(size_t)bh*UK + it] = gi;
    if (bi == gi){
#pragma unroll
      for (int i=0;i<12;++i) if (i==bslot) v[i] = -INFINITY;
    }
  }
}

// ---------- v mean over L from bf16 V pack ----------
__global__ __launch_bounds__(256) void vmean_k(const ushort* __restrict__ vp,
                                               float* __restrict__ vmn){
  __shared__ float part[4][64];
  int bh = blockIdx.x;
  int t = threadIdx.x; int d = t & 63, jg = t >> 6;
  const ushort* vb = vp + (size_t)bh*LL_*64 + d;
  float s = 0.f;
  for (int j=jg; j<LL_; j+=4) s += b2f(vb[(size_t)j*64]);
  part[jg][d] = s;
  __syncthreads();
  if (t < 64) vmn[bh*64+t] = (part[0][t]+part[1][t]+part[2][t]+part[3][t])*(1.f/LL_);
}

// ---------- ctx = broadcast v_mean (bf16, ushortx4 stores) ----------
__global__ __launch_bounds__(256) void ctxfill_k(const float* __restrict__ vmn,
                                                 ushort* __restrict__ ctx){
  int idx = blockIdx.x*256 + threadIdx.x;   // < BL*DM/4
  int c4 = idx & 127; int bl = idx >> 7; int b = bl / LL_;
  int c = c4*4;
  const float* vm = vmn + (b*8 + (c>>6))*64 + (c&63);
  ushortx4 o = { f2b(vm[0]), f2b(vm[1]), f2b(vm[2]), f2b(vm[3]) };
  *(ushortx4*)&ctx[(size_t)bl*DM + c] = o;
}

// ---------- chunked attention partials: one block per (b,h,chunk) ----------
__global__ __launch_bounds__(256) void attn4_k(const float* __restrict__ qkv,
                                               const ushort* __restrict__ kT,
                                               const ushort* __restrict__ vp,
                                               const int* __restrict__ mtop,
                                               float* __restrict__ pacc,
                                               float* __restrict__ pm,
                                               float* __restrict__ pl){
  __shared__ ushort skT[64][TJC];    // K^T chunk
  __shared__ ushort sv[TJC][64];     // V chunk
  __shared__ float  sq[UK][64];
  __shared__ float  sc[UK][TJC];
  int blk = blockIdx.x;
  int ch = blk % NCH; int bh = blk / NCH;
  int b = bh >> 3, h = bh & 7; int t0 = ch*TJC;
  int t = threadIdx.x, lane = t & 63, wid = t >> 6;
  for (int idx=t; idx<64*(TJC/8); idx+=256){
    int d = idx/(TJC/8), c8 = idx%(TJC/8);
    *(ushort8*)&skT[d][c8*8] =
      *(const ushort8*)(kT + ((size_t)bh*64 + d)*LL_ + t0 + c8*8);
  }
  for (int idx=t; idx<TJC*8; idx+=256){
    int jj = idx>>3, c8 = idx&7;
    *(ushort8*)&sv[jj][c8*8] =
      *(const ushort8*)(vp + ((size_t)bh*LL_ + t0+jj)*64 + c8*8);
  }
  for (int idx=t; idx<UK*64; idx+=256){
    int u = idx>>6, d = idx&63;
    int row = mtop[bh*UK + u];
    sq[u][d] = qkv[(size_t)(b*LL_ + row)*1536 + h*64 + d];
  }
  __syncthreads();
  for (int idx=t; idx<UK*(TJC/8); idx+=256){
    int u = idx/(TJC/8), jb = idx%(TJC/8);
    float dot[8] = {0.f,0.f,0.f,0.f,0.f,0.f,0.f,0.f};
    const float* qu = sq[u];
#pragma unroll
    for (int d=0; d<64; ++d){
      ushort8 kk = *(const ushort8*)&skT[d][jb*8];
      float qv = qu[d];
#pragma unroll
      for (int e=0;e<8;++e) dot[e] = fmaf(qv, b2f(kk[e]), dot[e]);
    }
#pragma unroll
    for (int e=0;e<8;++e) sc[u][jb*8+e] = dot[e]*0.125f;
  }
  __syncthreads();
  for (int u=wid; u<UK; u+=4){
    float v0 = sc[u][lane];
    float v1 = (lane < TJC-64) ? sc[u][64+lane] : -3.0e38f;
    float mx = wredmax(fmaxf(v0,v1));
    float e0 = __expf(v0-mx);
    float e1 = (lane < TJC-64) ? __expf(v1-mx) : 0.f;
    sc[u][lane] = e0;
    if (lane < TJC-64) sc[u][64+lane] = e1;
    float s = wredsum(e0+e1);
    if (lane==0){
      pm[((size_t)bh*NCH+ch)*UK + u] = mx;
      pl[((size_t)bh*NCH+ch)*UK + u] = s;
    }
  }
  __syncthreads();
  for (int idx=t; idx<UK*64; idx+=256){
    int u = idx>>6, d = idx&63;
    const float* scu = sc[u];
    float a = 0.f;
#pragma unroll 8
    for (int jj=0; jj<TJC; ++jj) a = fmaf(scu[jj], b2f(sv[jj][d]), a);
    pacc[(((size_t)bh*NCH+ch)*UK + u)*64 + d] = a;
  }
}

// ---------- combine partials + scatter into ctx ----------
__global__ __launch_bounds__(256) void attn5_k(const float* __restrict__ pacc,
                                               const float* __restrict__ pm,
                                               const float* __restrict__ pl,
                                               const int* __restrict__ mtop,
                                               ushort* __restrict__ ctx){
  int bh = blockIdx.x; int b = bh >> 3, h = bh & 7;
  int t = threadIdx.x;
  for (int idx=t; idx<UK*64; idx+=256){
    int u = idx>>6, d = idx&63;
    float M = -3.0e38f;
#pragma unroll
    for (int ch=0; ch<NCH; ++ch)
      M = fmaxf(M, pm[((size_t)bh*NCH+ch)*UK + u]);
    float L = 0.f, A = 0.f;
#pragma unroll
    for (int ch=0; ch<NCH; ++ch){
      float w = __expf(pm[((size_t)bh*NCH+ch)*UK + u] - M);
      L += w * pl[((size_t)bh*NCH+ch)*UK + u];
      A += w * pacc[(((size_t)bh*NCH+ch)*UK + u)*64 + d];
    }
    int row = mtop[bh*UK + u];
    ctx[(size_t)(b*LL_ + row)*DM + h*64 + d] = f2b(A / L);
  }
}

// ---------- LN(a - s): fp32 residual chain, dual output ----------
__global__ __launch_bounds__(256) void subln_k(const float* __restrict__ a,
                                               const float* __restrict__ s,
                                               const float* __restrict__ g,
                                               const float* __restrict__ be,
                                               float* __restrict__ of32,
                                               ushort* __restrict__ obf){
  __shared__ float red[4];
  int row = blockIdx.x;
  size_t base = (size_t)row * DM;
  int t = threadIdx.x;
  float e0 = a[base+t]     - s[base+t];
  float e1 = a[base+t+256] - s[base+t+256];
  float sum = bredsum(e0+e1, red);
  float mu = sum * (1.f/DM);
  float d0 = e0-mu, d1 = e1-mu;
  __syncthreads();
  float var = bredsum(d0*d0+d1*d1, red);
  float rs = rsqrtf(var*(1.f/DM) + EPSF);
  float o0 = d0*rs*g[t]     + be[t];
  float o1 = d1*rs*g[t+256] + be[t+256];
  of32[base+t]     = o0;
  of32[base+t+256] = o1;
  obf[base+t]      = f2b(o0);
  obf[base+t+256]  = f2b(o1);
}

// ---------- final: LDS-tiled transpose, out[b,p,n] = y[b,n,p]*std + mean ----------
__global__ __launch_bounds__(256) void final2_k(const float* __restrict__ y,
                                                const float* __restrict__ stdv,
                                                const float* __restrict__ mean,
                                                float* __restrict__ out){
  __shared__ float tile[32][33];
  int n0 = blockIdx.x*32, p0 = blockIdx.y*32, b = blockIdx.z;
  int tx = threadIdx.x & 31, ty = threadIdx.x >> 5;
  for (int i=ty; i<32; i+=8){
    int n = n0+i, p = p0+tx;
    tile[i][tx] = (n<NF && p<PRED) ? y[((size_t)b*LL_+n)*PRED + p] : 0.f;
  }
  __syncthreads();
  for (int i=ty; i<32; i+=8){
    int p = p0+i, n = n0+tx;
    if (p<PRED && n<NF)
      out[((size_t)b*PRED + p)*NF + n] = tile[tx][i]*stdv[b*NF+n] + mean[b*NF+n];
  }
}

// ---------------- host ----------------
extern "C" void kernel_launch(void* const* d_in, const int* in_sizes, int n_in,
                              void* d_out, int out_size, void* d_ws, size_t ws_size,
                              hipStream_t stream){
  const float* x_enc = (const float*)d_in[0];
  const int*   samp  = (const int*)  d_in[1];
  const float* embw  = (const float*)d_in[2];
  const float* embb  = (const float*)d_in[3];
  const float* wq    = (const float*)d_in[4];
  const float* bq    = (const float*)d_in[5];
  const float* wk    = (const float*)d_in[6];
  const float* bk    = (const float*)d_in[7];
  const float* wv    = (const float*)d_in[8];
  const float* bv    = (const float*)d_in[9];
  const float* wo    = (const float*)d_in[10];
  const float* bo    = (const float*)d_in[11];
  const float* ln1g  = (const float*)d_in[12];
  const float* ln1b  = (const float*)d_in[13];
  const float* w1    = (const float*)d_in[14];
  const float* b1    = (const float*)d_in[15];
  const float* w2    = (const float*)d_in[16];
  const float* b2    = (const float*)d_in[17];
  const float* ln2g  = (const float*)d_in[18];
  const float* ln2b  = (const float*)d_in[19];
  const float* wout  = (const float*)d_in[20];
  const float* boutp = (const float*)d_in[21];
  const float* wg    = (const float*)d_in[22];
  const float* bg    = (const float*)d_in[23];
  float* out = (float*)d_out;

  char* wsb = (char*)d_ws;
  size_t off = 0;
  auto alloc = [&](size_t bytes)->void*{
    void* p = wsb + off; off += (bytes + 255) & ~(size_t)255; return p;
  };
  float* mean  = (float*)alloc((size_t)BB_*NF*4);
  float* stdv  = (float*)alloc((size_t)BB_*NF*4);
  float* rstd  = (float*)alloc((size_t)BB_*NF*4);
  float* pp    = (float*)alloc((size_t)BB_*6*NLC*128*4);
  float* bqkv  = (float*)alloc(2*1536*4);
  float* bog   = (float*)alloc(2*672*4);
  ushort* xn     = (ushort*)alloc((size_t)BL*KPE*2);
  ushort* we_t   = (ushort*)alloc((size_t)512*KPE*2);
  ushort* wqkv_t = (ushort*)alloc((size_t)2*1536*512*2);
  ushort* wo_t   = (ushort*)alloc((size_t)2*512*512*2);
  ushort* w1_t   = (ushort*)alloc((size_t)2*128*512*2);
  ushort* w2_t   = (ushort*)alloc((size_t)2*512*128*2);
  ushort* wog_t  = (ushort*)alloc((size_t)2*768*512*2);
  ushort* h_bf   = (ushort*)alloc((size_t)BL*DM*2);
  ushort* hx_bf  = (ushort*)alloc((size_t)BL*DM*2);
  ushort* ctx_bf = (ushort*)alloc((size_t)BL*DM*2);
  ushort* ff1_bf = (ushort*)alloc((size_t)BL*DFF*2);
  ushort* kvpack = (ushort*)alloc(3*KVSEG*2);
  float* h_f32   = (float*)alloc((size_t)BL*DM*4);
  float* hx_f32  = (float*)alloc((size_t)BL*DM*4);
  float* qkv = (float*)alloc((size_t)BL*1536*4);
  float* tmp = (float*)alloc((size_t)BL*DM*4);
  float* y   = (float*)alloc((size_t)BL*PRED*4);
  float* Mb  = (float*)alloc((size_t)BB_*HH_*LL_*4);
  int*  mtop = (int*)  alloc((size_t)BB_*HH_*UK*4);
  float* vmn = (float*)alloc((size_t)BB_*HH_*DH*4);
  float* pacc = (float*)alloc((size_t)64*NCH*UK*64*4);
  float* pm   = (float*)alloc((size_t)64*NCH*UK*4);
  float* pl   = (float*)alloc((size_t)64*NCH*UK*4);
  if (off > ws_size) return;
  ushort* kTp   = kvpack;
  ushort* vpack = kvpack + KVSEG;
  ushort* kRp   = kvpack + 2*KVSEG;

  stats3_k<<<BB_*6*NLC, 256, 0, stream>>>(x_enc, pp);
  statsc_k<<<BB_*6, 64, 0, stream>>>(pp, mean, stdv, rstd);
  xnorm_k<<<(BL*KPE+255)/256, 256, 0, stream>>>(x_enc, mean, rstd, xn);

  TPack tp; int blk = 0; int di = 0;
  auto addT = [&](const float* in, ushort* o, int N, int K, int Npad, int Kpad, int ilv){
    TDesc& d = tp.d[di++]; d.in=in; d.out=o; d.N=N; d.K=K; d.Npad=Npad; d.Kpad=Kpad; d.ilv=ilv;
    d.nbx = (Kpad+31)/32; d.blk0 = blk; blk += d.nbx * ((Npad+31)/32);
  };
  addT(embw, we_t, 512, NF, 512, KPE, 0);
  for (int l=0;l<NLAY;++l){
    addT(wq + (size_t)l*262144, wqkv_t + (size_t)l*786432,            512,512,512,512,0);
    addT(wk + (size_t)l*262144, wqkv_t + (size_t)l*786432 + 262144,   512,512,512,512,0);
    addT(wv + (size_t)l*262144, wqkv_t + (size_t)l*786432 + 524288,   512,512,512,512,0);
    addT(wo + (size_t)l*262144, wo_t   + (size_t)l*262144,            512,512,512,512,0);
    addT(w1 + (size_t)l*65536,  w1_t   + (size_t)l*65536,             128,512,128,512,0);
    addT(w2 + (size_t)l*65536,  w2_t   + (size_t)l*65536,             512,128,512,128,0);
    addT(wout + (size_t)l*172032, wog_t + (size_t)l*393216,           336,512,384,512,1);
    addT(wg   + (size_t)l*172032, wog_t + (size_t)l*393216,           336,512,384,512,2);
  }
  tp.n = di;
  transpose_k<<<blk, 256, 0, stream>>>(tp);
  pack_bias_k<<<12, 256, 0, stream>>>(bq, bk, bv, boutp, bg, bqkv, bog);

  // embed: h = xn @ embw + embb  (dual fp32 + bf16)
  gemm_k<<<dim3(4,45), 256, 0, stream>>>(xn, we_t, embb, h_f32, h_bf, nullptr,
                                         512, KPE, 4);

  for (int l=0;l<NLAY;++l){
    gemm_k<<<dim3(12,45), 256, 0, stream>>>(h_bf, wqkv_t + (size_t)l*786432,
                                            bqkv + l*1536, qkv, nullptr, kvpack,
                                            1536, 512, 8);
    msc_k<<<BB_*HH_*LL_/4, 256, 0, stream>>>(qkv, kRp, samp, Mb);
    topk2_k<<<BB_*HH_, 64, 0, stream>>>(Mb, mtop);
    vmean_k<<<BB_*HH_, 256, 0, stream>>>(vpack, vmn);
    ctxfill_k<<<BL*DM/1024, 256, 0, stream>>>(vmn, ctx_bf);
    attn4_k<<<64*NCH, 256, 0, stream>>>(qkv, kTp, vpack, mtop, pacc, pm, pl);
    attn5_k<<<64, 256, 0, stream>>>(pacc, pm, pl, mtop, ctx_bf);
    gemm_k<<<dim3(4,45), 256, 0, stream>>>(ctx_bf, wo_t + (size_t)l*262144,
                                           bo + l*512, tmp, nullptr, nullptr,
                                           512, 512, 0);
    subln_k<<<BL, 256, 0, stream>>>(h_f32, tmp, ln1g + l*512, ln1b + l*512,
                                    hx_f32, hx_bf);
    gemm_k<<<dim3(1,45), 256, 0, stream>>>(hx_bf, w1_t + (size_t)l*65536,
                                           b1 + l*128, ff1_bf, nullptr, nullptr,
                                           128, 512, 3);
    gemm_k<<<dim3(4,45), 256, 0, stream>>>(ff1_bf, w2_t + (size_t)l*65536,
                                           b2 + l*512, tmp, nullptr, nullptr,
                                           512, 128, 0);
    subln_k<<<BL, 256, 0, stream>>>(hx_f32, tmp, ln2g + l*512, ln2b + l*512,
                                    h_f32, h_bf);
    gemm_k<<<dim3(6,45), 256, 0, stream>>>(h_bf, wog_t + (size_t)l*393216,
                                           bog + l*672, y, nullptr, nullptr,
                                           672, 512, 16 | (l ? 32 : 0));
  }
  final2_k<<<dim3((NF+31)/32,(PRED+31)/32,BB_), 256, 0, stream>>>(y, stdv, mean, out);
}

// Round 10
// 623.307 us; speedup vs baseline: 2.9506x; 1.1518x over previous
//
#include <hip/hip_runtime.h>
#include <math.h>

#define BB_ 8
#define LL_ 720
#define NF 321
#define DM 512
#define HH_ 8
#define DH 64
#define DFF 128
#define PRED 336
#define UK 35
#define NLAY 2
#define EPSF 1e-5f
#define BL (BB_*LL_)
#define TJC 72
#define NCH (LL_/TJC)
#define LCH 48
#define NLC (LL_/LCH)

typedef unsigned short ushort;
typedef __attribute__((ext_vector_type(4))) float f32x4;
typedef __attribute__((ext_vector_type(8))) ushort ushort8;
typedef __attribute__((ext_vector_type(4))) ushort ushortx4;

#define KVSEG ((size_t)64*LL_*64)   // one K-or-V pack segment (bh=64 heads)

// ---------- bf16 <-> f32 (raw ushort bits) ----------
__device__ __forceinline__ float b2f(ushort u){
  unsigned int x = ((unsigned int)u) << 16;
  return __builtin_bit_cast(float, x);
}
__device__ __forceinline__ ushort f2b(float f){
  unsigned int x = __builtin_bit_cast(unsigned int, f);
  unsigned int r = x + 0x7fff + ((x >> 16) & 1);   // RNE
  return (ushort)(r >> 16);
}

// ---------- reductions ----------
__device__ __forceinline__ float wredsum(float v){
#pragma unroll
  for (int o=32;o>0;o>>=1) v += __shfl_xor(v,o,64);
  return v;
}
__device__ __forceinline__ float wredmax(float v){
#pragma unroll
  for (int o=32;o>0;o>>=1) v = fmaxf(v,__shfl_xor(v,o,64));
  return v;
}
__device__ __forceinline__ float bredsum(float v, float* red){
  int lane = threadIdx.x & 63, wid = threadIdx.x >> 6;
  v = wredsum(v);
  __syncthreads();
  if (lane==0) red[wid]=v;
  __syncthreads();
  return red[0]+red[1]+red[2]+red[3];
}

// ---------- stats partials: one block per (b, n-tile, L-chunk) ----------
__global__ __launch_bounds__(256) void stats3_k(const float* __restrict__ x,
                                                float* __restrict__ pp){
  __shared__ float s1[4][64], s2[4][64];
  int blk = blockIdx.x;                  // b*6*NLC + nt*NLC + lc
  int lc = blk % NLC; int r = blk / NLC;
  int nt = r % 6; int b = r / 6;
  int nl = threadIdx.x & 63, lg = threadIdx.x >> 6;
  int n = nt*64 + nl;
  float sum=0.f, ss=0.f;
  if (n < NF){
    const float* xp = x + ((size_t)b*LL_ + lc*LCH)*NF + n;
    for (int l=lg; l<LCH; l+=4){ float v = xp[(size_t)l*NF]; sum += v; ss = fmaf(v,v,ss); }
  }
  s1[lg][nl]=sum; s2[lg][nl]=ss;
  __syncthreads();
  if (lg==0){
    float S = s1[0][nl]+s1[1][nl]+s1[2][nl]+s1[3][nl];
    float Q = s2[0][nl]+s2[1][nl]+s2[2][nl]+s2[3][nl];
    pp[(size_t)blk*128 + nl]      = S;
    pp[(size_t)blk*128 + 64 + nl] = Q;
  }
}

// ---------- stats combine: one block per (b, n-tile) ----------
__global__ __launch_bounds__(64) void statsc_k(const float* __restrict__ pp,
                                               float* __restrict__ mean,
                                               float* __restrict__ stdv,
                                               float* __restrict__ rstd){
  int bn6 = blockIdx.x;                  // b*6 + nt
  int nl = threadIdx.x;
  int nt = bn6 % 6, b = bn6 / 6;
  int n = nt*64 + nl;
  if (n >= NF) return;
  float S=0.f, Q=0.f;
#pragma unroll
  for (int lc=0; lc<NLC; ++lc){
    size_t base = ((size_t)(b*6+nt)*NLC + lc)*128;
    S += pp[base + nl];
    Q += pp[base + 64 + nl];
  }
  float mu = S*(1.f/LL_);
  float var = fmaxf((Q - S*mu)*(1.f/(LL_-1)), 0.f);
  float sd = sqrtf(var) + EPSF;
  int bn = b*NF+n;
  mean[bn]=mu; stdv[bn]=sd; rstd[bn]=1.f/sd;
}

// ---------- normalized input -> bf16, K padded to 352 ----------
#define KPE 352
__global__ __launch_bounds__(256) void xnorm_k(const float* __restrict__ x,
                                               const float* __restrict__ mean,
                                               const float* __restrict__ rstd,
                                               ushort* __restrict__ xn){
  int idx = blockIdx.x*256 + threadIdx.x;
  if (idx >= BL*KPE) return;
  int c = idx % KPE; int bl = idx / KPE; int b = bl / LL_;
  float v = 0.f;
  if (c < NF) v = (x[(size_t)bl*NF + c] - mean[b*NF+c]) * rstd[b*NF+c];
  xn[idx] = f2b(v);
}

// ---------- weight transpose+convert mega-kernel ----------
struct TDesc { const float* in; ushort* out; int N, K, Npad, Kpad, nbx, blk0, ilv; };
struct TPack { TDesc d[17]; int n; };
__global__ __launch_bounds__(256) void transpose_k(TPack p){
  __shared__ float tile[32][33];
  int blk = blockIdx.x;
  int di = 0;
  while (di+1 < p.n && p.d[di+1].blk0 <= blk) ++di;
  TDesc D = p.d[di];
  int rel = blk - D.blk0;
  int bx = rel % D.nbx, by = rel / D.nbx;
  int k0 = bx*32, n0 = by*32;
  int t = threadIdx.x; int tx = t & 31, ty = t >> 5;
#pragma unroll
  for (int i=0;i<4;++i){
    int k = k0+ty+8*i, n = n0+tx;
    float v = (k < D.K && n < D.N) ? D.in[(size_t)k*D.N + n] : 0.f;
    tile[ty+8*i][tx] = v;
  }
  __syncthreads();
#pragma unroll
  for (int i=0;i<4;++i){
    int n = n0+ty+8*i, k = k0+tx;
    if (n < D.Npad && k < D.Kpad){
      int outn = D.ilv ? (2*n + (D.ilv-1)) : n;
      D.out[(size_t)outn*D.Kpad + k] = f2b(tile[tx][ty+8*i]);
    }
  }
}

// ---------- fused bias packing (qkv + interleaved out/gate) ----------
__global__ __launch_bounds__(256) void pack_bias_k(const float* __restrict__ bq,
                                                   const float* __restrict__ bk,
                                                   const float* __restrict__ bv,
                                                   const float* __restrict__ bo2,
                                                   const float* __restrict__ bg,
                                                   float* __restrict__ bqkv,
                                                   float* __restrict__ bog){
  int t = blockIdx.x*256 + threadIdx.x;
  if (t < 2*1536){
    int l = t/1536, c = t%1536;
    float v = c<512 ? bq[l*512+c] : (c<1024 ? bk[l*512+c-512] : bv[l*512+c-1024]);
    bqkv[t] = v;
  }
  if (t < 2*672){
    int l = t/672, c = t%672;
    int p = c>>1;
    bog[t] = (c&1) ? bg[l*336+p] : bo2[l*336+p];
  }
}

// ---------- bf16 MFMA GEMM: C[M,N] = A[M,K] @ Bt[N,K]^T + bias ----------
// flags: 1=relu, 2=bf16-only out, 4=dual store (fp32+bf16),
//        8=qkv mode (q fp32; K->kR, V->vp bf16 row packs),
//        16=gate epilogue y[row][col/2] (+)= t1*sigmoid(t2), 32=gate accumulate
__global__ __launch_bounds__(256) void gemm_k(
    const ushort* __restrict__ A, const ushort* __restrict__ Bt,
    const float* __restrict__ bias, void* __restrict__ Cout,
    ushort* __restrict__ Cbf, ushort* __restrict__ kvp,
    int N, int K, int flags)
{
  __shared__ ushort As[128*32];
  __shared__ ushort Bs[128*32];
  const int t = threadIdx.x;
  const int bm = blockIdx.y << 7, bn = blockIdx.x << 7;
  const int lane = t & 63, wid = t >> 6;
  const int wm = (wid >> 1) << 6, wn = (wid & 1) << 6;
  const int fr = lane & 15, kg = lane >> 4;

  f32x4 acc[4][4];
#pragma unroll
  for (int i=0;i<4;++i)
#pragma unroll
    for (int j=0;j<4;++j) acc[i][j] = (f32x4){0.f,0.f,0.f,0.f};

  const int rA0 = t >> 2,        qA0 = t & 3;
  const int rA1 = (t+256) >> 2;
  const size_t aOff0 = (size_t)(bm + rA0)*K + qA0*8;
  const size_t aOff1 = (size_t)(bm + rA1)*K + qA0*8;
  const size_t bOff0 = (size_t)(bn + rA0)*K + qA0*8;
  const size_t bOff1 = (size_t)(bn + rA1)*K + qA0*8;
  const int lA0 = (rA0<<5) + ((qA0 ^ ((rA0>>1)&3))<<3);
  const int lA1 = (rA1<<5) + ((qA0 ^ ((rA1>>1)&3))<<3);

  for (int k0=0; k0<K; k0+=32){
    ushort8 va0 = *(const ushort8*)(A  + aOff0 + k0);
    ushort8 va1 = *(const ushort8*)(A  + aOff1 + k0);
    ushort8 vb0 = *(const ushort8*)(Bt + bOff0 + k0);
    ushort8 vb1 = *(const ushort8*)(Bt + bOff1 + k0);
    *(ushort8*)&As[lA0] = va0;
    *(ushort8*)&As[lA1] = va1;
    *(ushort8*)&Bs[lA0] = vb0;
    *(ushort8*)&Bs[lA1] = vb1;
    __syncthreads();
    ushort8 af[4], bfr[4];
#pragma unroll
    for (int i=0;i<4;++i){
      int ra = wm + (i<<4) + fr;
      af[i]  = *(const ushort8*)&As[(ra<<5) + ((kg ^ ((ra>>1)&3))<<3)];
      int rb = wn + (i<<4) + fr;
      bfr[i] = *(const ushort8*)&Bs[(rb<<5) + ((kg ^ ((rb>>1)&3))<<3)];
    }
#pragma unroll
    for (int i=0;i<4;++i)
#pragma unroll
      for (int j=0;j<4;++j)
        asm("v_mfma_f32_16x16x32_bf16 %0, %1, %2, %0"
            : "+v"(acc[i][j]) : "v"(af[i]), "v"(bfr[j]));
    __syncthreads();
  }

  const int colBase = bn + wn + fr;
  const int rowBase = bm + wm + (kg << 2);

  if (flags & 16){
    // interleaved out/gate: even col = t1, odd col = t2
#pragma unroll
    for (int j=0;j<4;++j){
      int col = colBase + (j<<4);
      if (col >= N) continue;               // 672 is 16-aligned: wave-uniform
      float bv = bias[col];
#pragma unroll
      for (int i=0;i<4;++i){
        int row0 = rowBase + (i<<4);
#pragma unroll
        for (int r=0;r<4;++r){
          float v = acc[i][j][r] + bv;
          float o = __shfl_xor(v, 1, 64);   // partner (t2 for even lanes)
          if ((lane & 1) == 0){
            float val = v * (1.f/(1.f+__expf(-o)));
            size_t yi = (size_t)(row0+r)*PRED + (col>>1);
            float* yp = (float*)Cout;
            yp[yi] = (flags & 32) ? (yp[yi] + val) : val;
          }
        }
      }
    }
    return;
  }

#pragma unroll
  for (int j=0;j<4;++j){
    int col = colBase + (j<<4);
    if (col >= N) continue;
    float bv = bias[col];
#pragma unroll
    for (int i=0;i<4;++i){
      int row0 = rowBase + (i<<4);
#pragma unroll
      for (int r=0;r<4;++r){
        float v = acc[i][j][r] + bv;
        if (flags & 1) v = fmaxf(v, 0.f);
        int row = row0 + r;
        size_t idx = (size_t)row*N + col;
        if (flags & 2) ((ushort*)Cout)[idx] = f2b(v);
        else if (flags & 8){
          if (col < 512) ((float*)Cout)[idx] = v;
          else {
            int hh = (col >> 6) & 7;
            int dd = col & 63;
            int bb = row / LL_; int jr = row - bb*LL_;
            ushort bfv = f2b(v);
            if (col < 1024)   // K rows: kR [bh][L][d]
              kvp[((size_t)(bb*8+hh)*LL_ + jr)*64 + dd] = bfv;
            else              // V rows: [bh][L][d]
              kvp[KVSEG + ((size_t)(bb*8+hh)*LL_ + jr)*64 + dd] = bfv;
          }
        } else {
          ((float*)Cout)[idx] = v;
          if (flags & 4) Cbf[idx] = f2b(v);
        }
      }
    }
  }
}

// ---------- fused sampled-QK + M score: one wave per (b,h,l), lane=sample ----------
__global__ __launch_bounds__(256) void msc_k(const float* __restrict__ qkv,
                                             const ushort* __restrict__ kR,
                                             const int* __restrict__ samp,
                                             float* __restrict__ Mb){
  __shared__ float sq[4][64];
  int wid = threadIdx.x >> 6, lane = threadIdx.x & 63;
  int gid = blockIdx.x*4 + wid;                 // (b*H+h)*L + l
  int l = gid % LL_; int bh = gid / LL_; int h = bh & 7; int b = bh >> 3;
  sq[wid][lane] = qkv[(size_t)(b*LL_ + l)*1536 + h*64 + lane];
  __syncthreads();
  float acc = 0.f;
  if (lane < UK){
    int j = samp[l*UK + lane];
    const ushort8* kr = (const ushort8*)(kR + ((size_t)bh*LL_ + j)*64);
    const float* sqw = sq[wid];
#pragma unroll
    for (int d8=0; d8<8; ++d8){
      ushort8 kk = kr[d8];
#pragma unroll
      for (int e=0;e<8;++e) acc = fmaf(sqw[d8*8+e], b2f(kk[e]), acc);
    }
  }
  float mx = (lane < UK) ? acc : -INFINITY;
  float sm = (lane < UK) ? acc : 0.f;
  mx = wredmax(mx);
  sm = wredsum(sm);
  if (lane == 0) Mb[gid] = mx - sm*(1.f/LL_);
}

// ---------- top-U per (b,h): one wave, shuffle-only ----------
__global__ __launch_bounds__(64) void topk2_k(const float* __restrict__ Mb,
                                              int* __restrict__ mtop){
  int bh = blockIdx.x; int lane = threadIdx.x;
  const float* mp = Mb + (size_t)bh*LL_;
  float v[12]; int vi[12];
#pragma unroll
  for (int i=0;i<12;++i){
    int j = lane + i*64;
    bool ok = j < LL_;
    v[i] = ok ? mp[j] : -INFINITY;
    vi[i] = ok ? j : (LL_ + i);
  }
  for (int it=0; it<UK; ++it){
    float best = v[0]; int bi = vi[0]; int bslot = 0;
#pragma unroll
    for (int i=1;i<12;++i){
      if (v[i] > best || (v[i]==best && vi[i] < bi)){ best=v[i]; bi=vi[i]; bslot=i; }
    }
    float gb = best; int gi = bi;
#pragma unroll
    for (int o=32;o>0;o>>=1){
      float ov = __shfl_xor(gb,o,64); int oi = __shfl_xor(gi,o,64);
      if (ov > gb || (ov==gb && oi < gi)){ gb=ov; gi=oi; }
    }
    if (lane==0) mtop[(size_t)bh*UK + it] = gi;
    if (bi == gi){
#pragma unroll
      for (int i=0;i<12;++i) if (i==bslot) v[i] = -INFINITY;
    }
  }
}

// ---------- combine per-chunk V sums -> v mean ----------
__global__ __launch_bounds__(256) void vmnc_k(const float* __restrict__ pvs,
                                              float* __restrict__ vmn){
  int idx = blockIdx.x*256 + threadIdx.x;   // < 64*64
  if (idx >= 64*64) return;
  int bh = idx >> 6, d = idx & 63;
  float s = 0.f;
#pragma unroll
  for (int ch=0; ch<NCH; ++ch) s += pvs[((size_t)bh*NCH + ch)*64 + d];
  vmn[idx] = s*(1.f/LL_);
}

// ---------- ctx = broadcast v_mean (bf16, ushortx4 stores) ----------
__global__ __launch_bounds__(256) void ctxfill_k(const float* __restrict__ vmn,
                                                 ushort* __restrict__ ctx){
  int idx = blockIdx.x*256 + threadIdx.x;   // < BL*DM/4
  int c4 = idx & 127; int bl = idx >> 7; int b = bl / LL_;
  int c = c4*4;
  const float* vm = vmn + (b*8 + (c>>6))*64 + (c&63);
  ushortx4 o = { f2b(vm[0]), f2b(vm[1]), f2b(vm[2]), f2b(vm[3]) };
  *(ushortx4*)&ctx[(size_t)bl*DM + c] = o;
}

// ---------- chunked attention partials: one block per (b,h,chunk) ----------
// K staged from coalesced kR rows, transposed through LDS; also emits V-chunk sums.
__global__ __launch_bounds__(256) void attn4_k(const float* __restrict__ qkv,
                                               const ushort* __restrict__ kR,
                                               const ushort* __restrict__ vp,
                                               const int* __restrict__ mtop,
                                               float* __restrict__ pacc,
                                               float* __restrict__ pm,
                                               float* __restrict__ pl,
                                               float* __restrict__ pvs){
  __shared__ ushort skT[64][TJC];    // K^T chunk
  __shared__ ushort sv[TJC][64];     // V chunk
  __shared__ float  sq[UK][64];
  __shared__ float  sc[UK][TJC];
  __shared__ float  part[4][64];
  int blk = blockIdx.x;
  int ch = blk % NCH; int bh = blk / NCH;
  int b = bh >> 3, h = bh & 7; int t0 = ch*TJC;
  int t = threadIdx.x, lane = t & 63, wid = t >> 6;
  // K rows: coalesced load + LDS transpose
  for (int idx=t; idx<TJC*8; idx+=256){
    int jj = idx>>3, c8 = idx&7;
    ushort8 kk = *(const ushort8*)(kR + ((size_t)bh*LL_ + t0+jj)*64 + c8*8);
#pragma unroll
    for (int e=0;e<8;++e) skT[c8*8+e][jj] = kk[e];
  }
  // V rows
  for (int idx=t; idx<TJC*8; idx+=256){
    int jj = idx>>3, c8 = idx&7;
    *(ushort8*)&sv[jj][c8*8] =
      *(const ushort8*)(vp + ((size_t)bh*LL_ + t0+jj)*64 + c8*8);
  }
  for (int idx=t; idx<UK*64; idx+=256){
    int u = idx>>6, d = idx&63;
    int row = mtop[bh*UK + u];
    sq[u][d] = qkv[(size_t)(b*LL_ + row)*1536 + h*64 + d];
  }
  __syncthreads();
  // V partial sums (for v-mean)
  {
    int d = t & 63, q = t >> 6;
    float s = 0.f;
    for (int jj=q; jj<TJC; jj+=4) s += b2f(sv[jj][d]);
    part[q][d] = s;
  }
  // scores
  for (int idx=t; idx<UK*(TJC/8); idx+=256){
    int u = idx/(TJC/8), jb = idx%(TJC/8);
    float dot[8] = {0.f,0.f,0.f,0.f,0.f,0.f,0.f,0.f};
    const float* qu = sq[u];
#pragma unroll
    for (int d=0; d<64; ++d){
      ushort8 kk = *(const ushort8*)&skT[d][jb*8];
      float qv = qu[d];
#pragma unroll
      for (int e=0;e<8;++e) dot[e] = fmaf(qv, b2f(kk[e]), dot[e]);
    }
#pragma unroll
    for (int e=0;e<8;++e) sc[u][jb*8+e] = dot[e]*0.125f;
  }
  __syncthreads();
  if (t < 64)
    pvs[((size_t)bh*NCH + ch)*64 + t] = part[0][t]+part[1][t]+part[2][t]+part[3][t];
  for (int u=wid; u<UK; u+=4){
    float v0 = sc[u][lane];
    float v1 = (lane < TJC-64) ? sc[u][64+lane] : -3.0e38f;
    float mx = wredmax(fmaxf(v0,v1));
    float e0 = __expf(v0-mx);
    float e1 = (lane < TJC-64) ? __expf(v1-mx) : 0.f;
    sc[u][lane] = e0;
    if (lane < TJC-64) sc[u][64+lane] = e1;
    float s = wredsum(e0+e1);
    if (lane==0){
      pm[((size_t)bh*NCH+ch)*UK + u] = mx;
      pl[((size_t)bh*NCH+ch)*UK + u] = s;
    }
  }
  __syncthreads();
  for (int idx=t; idx<UK*64; idx+=256){
    int u = idx>>6, d = idx&63;
    const float* scu = sc[u];
    float a = 0.f;
#pragma unroll 8
    for (int jj=0; jj<TJC; ++jj) a = fmaf(scu[jj], b2f(sv[jj][d]), a);
    pacc[(((size_t)bh*NCH+ch)*UK + u)*64 + d] = a;
  }
}

// ---------- combine partials + scatter into ctx ----------
__global__ __launch_bounds__(256) void attn5_k(const float* __restrict__ pacc,
                                               const float* __restrict__ pm,
                                               const float* __restrict__ pl,
                                               const int* __restrict__ mtop,
                                               ushort* __restrict__ ctx){
  int bh = blockIdx.x; int b = bh >> 3, h = bh & 7;
  int t = threadIdx.x;
  for (int idx=t; idx<UK*64; idx+=256){
    int u = idx>>6, d = idx&63;
    float M = -3.0e38f;
#pragma unroll
    for (int ch=0; ch<NCH; ++ch)
      M = fmaxf(M, pm[((size_t)bh*NCH+ch)*UK + u]);
    float L = 0.f, A = 0.f;
#pragma unroll
    for (int ch=0; ch<NCH; ++ch){
      float w = __expf(pm[((size_t)bh*NCH+ch)*UK + u] - M);
      L += w * pl[((size_t)bh*NCH+ch)*UK + u];
      A += w * pacc[(((size_t)bh*NCH+ch)*UK + u)*64 + d];
    }
    int row = mtop[bh*UK + u];
    ctx[(size_t)(b*LL_ + row)*DM + h*64 + d] = f2b(A / L);
  }
}

// ---------- LN(a - s): fp32 residual chain, dual output ----------
__global__ __launch_bounds__(256) void subln_k(const float* __restrict__ a,
                                               const float* __restrict__ s,
                                               const float* __restrict__ g,
                                               const float* __restrict__ be,
                                               float* __restrict__ of32,
                                               ushort* __restrict__ obf){
  __shared__ float red[4];
  int row = blockIdx.x;
  size_t base = (size_t)row * DM;
  int t = threadIdx.x;
  float e0 = a[base+t]     - s[base+t];
  float e1 = a[base+t+256] - s[base+t+256];
  float sum = bredsum(e0+e1, red);
  float mu = sum * (1.f/DM);
  float d0 = e0-mu, d1 = e1-mu;
  __syncthreads();
  float var = bredsum(d0*d0+d1*d1, red);
  float rs = rsqrtf(var*(1.f/DM) + EPSF);
  float o0 = d0*rs*g[t]     + be[t];
  float o1 = d1*rs*g[t+256] + be[t+256];
  of32[base+t]     = o0;
  of32[base+t+256] = o1;
  obf[base+t]      = f2b(o0);
  obf[base+t+256]  = f2b(o1);
}

// ---------- final: LDS-tiled transpose, out[b,p,n] = y[b,n,p]*std + mean ----------
__global__ __launch_bounds__(256) void final2_k(const float* __restrict__ y,
                                                const float* __restrict__ stdv,
                                                const float* __restrict__ mean,
                                                float* __restrict__ out){
  __shared__ float tile[32][33];
  int n0 = blockIdx.x*32, p0 = blockIdx.y*32, b = blockIdx.z;
  int tx = threadIdx.x & 31, ty = threadIdx.x >> 5;
  for (int i=ty; i<32; i+=8){
    int n = n0+i, p = p0+tx;
    tile[i][tx] = (n<NF && p<PRED) ? y[((size_t)b*LL_+n)*PRED + p] : 0.f;
  }
  __syncthreads();
  for (int i=ty; i<32; i+=8){
    int p = p0+i, n = n0+tx;
    if (p<PRED && n<NF)
      out[((size_t)b*PRED + p)*NF + n] = tile[tx][i]*stdv[b*NF+n] + mean[b*NF+n];
  }
}

// ---------------- host ----------------
extern "C" void kernel_launch(void* const* d_in, const int* in_sizes, int n_in,
                              void* d_out, int out_size, void* d_ws, size_t ws_size,
                              hipStream_t stream){
  const float* x_enc = (const float*)d_in[0];
  const int*   samp  = (const int*)  d_in[1];
  const float* embw  = (const float*)d_in[2];
  const float* embb  = (const float*)d_in[3];
  const float* wq    = (const float*)d_in[4];
  const float* bq    = (const float*)d_in[5];
  const float* wk    = (const float*)d_in[6];
  const float* bk    = (const float*)d_in[7];
  const float* wv    = (const float*)d_in[8];
  const float* bv    = (const float*)d_in[9];
  const float* wo    = (const float*)d_in[10];
  const float* bo    = (const float*)d_in[11];
  const float* ln1g  = (const float*)d_in[12];
  const float* ln1b  = (const float*)d_in[13];
  const float* w1    = (const float*)d_in[14];
  const float* b1    = (const float*)d_in[15];
  const float* w2    = (const float*)d_in[16];
  const float* b2    = (const float*)d_in[17];
  const float* ln2g  = (const float*)d_in[18];
  const float* ln2b  = (const float*)d_in[19];
  const float* wout  = (const float*)d_in[20];
  const float* boutp = (const float*)d_in[21];
  const float* wg    = (const float*)d_in[22];
  const float* bg    = (const float*)d_in[23];
  float* out = (float*)d_out;

  char* wsb = (char*)d_ws;
  size_t off = 0;
  auto alloc = [&](size_t bytes)->void*{
    void* p = wsb + off; off += (bytes + 255) & ~(size_t)255; return p;
  };
  float* mean  = (float*)alloc((size_t)BB_*NF*4);
  float* stdv  = (float*)alloc((size_t)BB_*NF*4);
  float* rstd  = (float*)alloc((size_t)BB_*NF*4);
  float* pp    = (float*)alloc((size_t)BB_*6*NLC*128*4);
  float* bqkv  = (float*)alloc(2*1536*4);
  float* bog   = (float*)alloc(2*672*4);
  ushort* xn     = (ushort*)alloc((size_t)BL*KPE*2);
  ushort* we_t   = (ushort*)alloc((size_t)512*KPE*2);
  ushort* wqkv_t = (ushort*)alloc((size_t)2*1536*512*2);
  ushort* wo_t   = (ushort*)alloc((size_t)2*512*512*2);
  ushort* w1_t   = (ushort*)alloc((size_t)2*128*512*2);
  ushort* w2_t   = (ushort*)alloc((size_t)2*512*128*2);
  ushort* wog_t  = (ushort*)alloc((size_t)2*768*512*2);
  ushort* h_bf   = (ushort*)alloc((size_t)BL*DM*2);
  ushort* hx_bf  = (ushort*)alloc((size_t)BL*DM*2);
  ushort* ctx_bf = (ushort*)alloc((size_t)BL*DM*2);
  ushort* ff1_bf = (ushort*)alloc((size_t)BL*DFF*2);
  ushort* kvpack = (ushort*)alloc(2*KVSEG*2);
  float* h_f32   = (float*)alloc((size_t)BL*DM*4);
  float* hx_f32  = (float*)alloc((size_t)BL*DM*4);
  float* qkv = (float*)alloc((size_t)BL*1536*4);
  float* tmp = (float*)alloc((size_t)BL*DM*4);
  float* y   = (float*)alloc((size_t)BL*PRED*4);
  float* Mb  = (float*)alloc((size_t)BB_*HH_*LL_*4);
  int*  mtop = (int*)  alloc((size_t)BB_*HH_*UK*4);
  float* vmn = (float*)alloc((size_t)BB_*HH_*DH*4);
  float* pacc = (float*)alloc((size_t)64*NCH*UK*64*4);
  float* pm   = (float*)alloc((size_t)64*NCH*UK*4);
  float* pl   = (float*)alloc((size_t)64*NCH*UK*4);
  float* pvs  = (float*)alloc((size_t)64*NCH*64*4);
  if (off > ws_size) return;
  ushort* kRp   = kvpack;
  ushort* vpack = kvpack + KVSEG;

  stats3_k<<<BB_*6*NLC, 256, 0, stream>>>(x_enc, pp);
  statsc_k<<<BB_*6, 64, 0, stream>>>(pp, mean, stdv, rstd);
  xnorm_k<<<(BL*KPE+255)/256, 256, 0, stream>>>(x_enc, mean, rstd, xn);

  TPack tp; int blk = 0; int di = 0;
  auto addT = [&](const float* in, ushort* o, int N, int K, int Npad, int Kpad, int ilv){
    TDesc& d = tp.d[di++]; d.in=in; d.out=o; d.N=N; d.K=K; d.Npad=Npad; d.Kpad=Kpad; d.ilv=ilv;
    d.nbx = (Kpad+31)/32; d.blk0 = blk; blk += d.nbx * ((Npad+31)/32);
  };
  addT(embw, we_t, 512, NF, 512, KPE, 0);
  for (int l=0;l<NLAY;++l){
    addT(wq + (size_t)l*262144, wqkv_t + (size_t)l*786432,            512,512,512,512,0);
    addT(wk + (size_t)l*262144, wqkv_t + (size_t)l*786432 + 262144,   512,512,512,512,0);
    addT(wv + (size_t)l*262144, wqkv_t + (size_t)l*786432 + 524288,   512,512,512,512,0);
    addT(wo + (size_t)l*262144, wo_t   + (size_t)l*262144,            512,512,512,512,0);
    addT(w1 + (size_t)l*65536,  w1_t   + (size_t)l*65536,             128,512,128,512,0);
    addT(w2 + (size_t)l*65536,  w2_t   + (size_t)l*65536,             512,128,512,128,0);
    addT(wout + (size_t)l*172032, wog_t + (size_t)l*393216,           336,512,384,512,1);
    addT(wg   + (size_t)l*172032, wog_t + (size_t)l*393216,           336,512,384,512,2);
  }
  tp.n = di;
  transpose_k<<<blk, 256, 0, stream>>>(tp);
  pack_bias_k<<<12, 256, 0, stream>>>(bq, bk, bv, boutp, bg, bqkv, bog);

  // embed: h = xn @ embw + embb  (dual fp32 + bf16)
  gemm_k<<<dim3(4,45), 256, 0, stream>>>(xn, we_t, embb, h_f32, h_bf, nullptr,
                                         512, KPE, 4);

  for (int l=0;l<NLAY;++l){
    gemm_k<<<dim3(12,45), 256, 0, stream>>>(h_bf, wqkv_t + (size_t)l*786432,
                                            bqkv + l*1536, qkv, nullptr, kvpack,
                                            1536, 512, 8);
    msc_k<<<BB_*HH_*LL_/4, 256, 0, stream>>>(qkv, kRp, samp, Mb);
    topk2_k<<<BB_*HH_, 64, 0, stream>>>(Mb, mtop);
    attn4_k<<<64*NCH, 256, 0, stream>>>(qkv, kRp, vpack, mtop, pacc, pm, pl, pvs);
    vmnc_k<<<16, 256, 0, stream>>>(pvs, vmn);
    ctxfill_k<<<BL*DM/1024, 256, 0, stream>>>(vmn, ctx_bf);
    attn5_k<<<64, 256, 0, stream>>>(pacc, pm, pl, mtop, ctx_bf);
    gemm_k<<<dim3(4,45), 256, 0, stream>>>(ctx_bf, wo_t + (size_t)l*262144,
                                           bo + l*512, tmp, nullptr, nullptr,
                                           512, 512, 0);
    subln_k<<<BL, 256, 0, stream>>>(h_f32, tmp, ln1g + l*512, ln1b + l*512,
                                    hx_f32, hx_bf);
    gemm_k<<<dim3(1,45), 256, 0, stream>>>(hx_bf, w1_t + (size_t)l*65536,
                                           b1 + l*128, ff1_bf, nullptr, nullptr,
                                           128, 512, 3);
    gemm_k<<<dim3(4,45), 256, 0, stream>>>(ff1_bf, w2_t + (size_t)l*65536,
                                           b2 + l*512, tmp, nullptr, nullptr,
                                           512, 128, 0);
    subln_k<<<BL, 256, 0, stream>>>(hx_f32, tmp, ln2g + l*512, ln2b + l*512,
                                    h_f32, h_bf);
    gemm_k<<<dim3(6,45), 256, 0, stream>>>(h_bf, wog_t + (size_t)l*393216,
                                           bog + l*672, y, nullptr, nullptr,
                                           672, 512, 16 | (l ? 32 : 0));
  }
  final2_k<<<dim3((NF+31)/32,(PRED+31)/32,BB_), 256, 0, stream>>>(y, stdv, mean, out);
}